// Round 1
// baseline (7309.454 us; speedup 1.0000x reference)
//
#include <hip/hip_runtime.h>

#define NNODE 100000
#define NEDGE 1600000

// ---------------- degree counting ----------------
__global__ __launch_bounds__(256) void count_kernel(const int* __restrict__ dst,
                                                    float* __restrict__ cnt, int E) {
    int e = blockIdx.x * 256 + threadIdx.x;
    if (e < E) unsafeAtomicAdd(&cnt[dst[e]], 1.0f);
}

__global__ __launch_bounds__(256) void inv_kernel(float* __restrict__ c, int n) {
    int i = blockIdx.x * 256 + threadIdx.x;
    if (i < n) c[i] = 1.0f / fmaxf(c[i], 1.0f);
}

// ---------------- input projection: relu(concat(xd,xc) @ W + b) ----------------
// block = 256 threads = 16 nodes x 16 threads; each thread computes 4 outputs.
__global__ __launch_bounds__(256) void proj_kernel(const float* __restrict__ xd,
                                                   const float* __restrict__ xc,
                                                   const float* __restrict__ W,
                                                   const float* __restrict__ b,
                                                   float* __restrict__ out) {
    __shared__ float sW[64 * 64];
    __shared__ float sX[16 * 64];
    for (int i = threadIdx.x; i < 4096; i += 256) sW[i] = W[i];
    int base = blockIdx.x * 16;
    for (int i = threadIdx.x; i < 1024; i += 256) {
        int node = base + (i >> 6);
        int k = i & 63;
        sX[i] = (k < 32) ? xd[(size_t)node * 32 + k] : xc[(size_t)node * 32 + k - 32];
    }
    __syncthreads();
    int t = threadIdx.x;
    int nb = t >> 4;
    int h4 = (t & 15) << 2;
    float4 acc = *(const float4*)(b + h4);
    const float* x = sX + nb * 64;
#pragma unroll 8
    for (int k = 0; k < 64; ++k) {
        float xv = x[k];
        float4 w = *(const float4*)(sW + k * 64 + h4);
        acc.x = fmaf(xv, w.x, acc.x);
        acc.y = fmaf(xv, w.y, acc.y);
        acc.z = fmaf(xv, w.z, acc.z);
        acc.w = fmaf(xv, w.w, acc.w);
    }
    int node = base + nb;
    float4 r;
    r.x = fmaxf(acc.x, 0.f);
    r.y = fmaxf(acc.y, 0.f);
    r.z = fmaxf(acc.z, 0.f);
    r.w = fmaxf(acc.w, 0.f);
    *(float4*)(out + (size_t)node * 64 + h4) = r;
}

// ---------------- edge aggregation: agg[dst] += x[src] (raw sum) ----------------
// thread = (edge, 4-float chunk); 16 threads per edge; 4 edges per wave.
__global__ __launch_bounds__(256) void aggregate_kernel(const float* __restrict__ x,
                                                        const int* __restrict__ src,
                                                        const int* __restrict__ dst,
                                                        float* __restrict__ agg, int E) {
    int gid = blockIdx.x * 256 + threadIdx.x;
    int e = gid >> 4;
    if (e >= E) return;
    int c = (gid & 15) << 2;
    int s = src[e], d = dst[e];
    float4 v = *(const float4*)(x + (size_t)s * 64 + c);
    float* a = agg + (size_t)d * 64 + c;
    unsafeAtomicAdd(a + 0, v.x);
    unsafeAtomicAdd(a + 1, v.y);
    unsafeAtomicAdd(a + 2, v.z);
    unsafeAtomicAdd(a + 3, v.w);
}

// ---------------- SAGE combine:
// out = (sum_w*invw) @ wlw [+ (sum_c*invc) @ wlc] + y @ (wrw [+ wrc]) + blw [+ blc]
// In-place safe per-row (out may alias mw). ----------------
template <int HAS_C>
__global__ __launch_bounds__(256) void combine_kernel(
    const float* __restrict__ mw, const float* __restrict__ invw,
    const float* __restrict__ mc, const float* __restrict__ invc,
    const float* __restrict__ y,
    const float* __restrict__ wlw, const float* __restrict__ wlc,
    const float* __restrict__ wrw, const float* __restrict__ wrc,
    const float* __restrict__ blw, const float* __restrict__ blc,
    float* __restrict__ out) {
    __shared__ float sWlw[4096];
    __shared__ float sWr[4096];
    __shared__ float sWlc[HAS_C ? 4096 : 4];
    __shared__ float sM[1024];
    __shared__ float sY[1024];
    __shared__ float sMc[HAS_C ? 1024 : 4];
    for (int i = threadIdx.x; i < 4096; i += 256) {
        sWlw[i] = wlw[i];
        sWr[i] = HAS_C ? (wrw[i] + wrc[i]) : wrw[i];
        if (HAS_C) sWlc[i] = wlc[i];
    }
    int base = blockIdx.x * 16;
    {
        int i4 = threadIdx.x;  // 256 float4 = 16 rows x 16 chunks
        int row = i4 >> 4;
        float iw = invw[base + row];
        float4 v = ((const float4*)(mw + (size_t)base * 64))[i4];
        ((float4*)sM)[i4] = make_float4(v.x * iw, v.y * iw, v.z * iw, v.w * iw);
        ((float4*)sY)[i4] = ((const float4*)(y + (size_t)base * 64))[i4];
        if (HAS_C) {
            float ic = invc[base + row];
            float4 u = ((const float4*)(mc + (size_t)base * 64))[i4];
            ((float4*)sMc)[i4] = make_float4(u.x * ic, u.y * ic, u.z * ic, u.w * ic);
        }
    }
    __syncthreads();
    int t = threadIdx.x;
    int nb = t >> 4;
    int h4 = (t & 15) << 2;
    float4 acc = *(const float4*)(blw + h4);
    if (HAS_C) {
        float4 b2 = *(const float4*)(blc + h4);
        acc.x += b2.x; acc.y += b2.y; acc.z += b2.z; acc.w += b2.w;
    }
    const float* xm = sM + nb * 64;
    const float* xy = sY + nb * 64;
    const float* xc2 = sMc + nb * 64;
#pragma unroll 4
    for (int k = 0; k < 64; ++k) {
        float a1 = xm[k];
        float4 w1 = *(const float4*)(sWlw + k * 64 + h4);
        acc.x = fmaf(a1, w1.x, acc.x);
        acc.y = fmaf(a1, w1.y, acc.y);
        acc.z = fmaf(a1, w1.z, acc.z);
        acc.w = fmaf(a1, w1.w, acc.w);
        float a3 = xy[k];
        float4 w3 = *(const float4*)(sWr + k * 64 + h4);
        acc.x = fmaf(a3, w3.x, acc.x);
        acc.y = fmaf(a3, w3.y, acc.y);
        acc.z = fmaf(a3, w3.z, acc.z);
        acc.w = fmaf(a3, w3.w, acc.w);
        if (HAS_C) {
            float a2 = xc2[k];
            float4 w2 = *(const float4*)(sWlc + k * 64 + h4);
            acc.x = fmaf(a2, w2.x, acc.x);
            acc.y = fmaf(a2, w2.y, acc.y);
            acc.z = fmaf(a2, w2.z, acc.z);
            acc.w = fmaf(a2, w2.w, acc.w);
        }
    }
    *(float4*)(out + (size_t)(base + nb) * 64 + h4) = acc;
}

// ---------------- final: out = y @ lin_w + lin_b  [100k,64]x[64,16] ----------------
__global__ __launch_bounds__(256) void final_kernel(const float* __restrict__ y,
                                                    const float* __restrict__ W,
                                                    const float* __restrict__ b,
                                                    float* __restrict__ out) {
    __shared__ float sW[64 * 16];
    __shared__ float sY[16 * 64];
    __shared__ float sB[16];
    for (int i = threadIdx.x; i < 1024; i += 256) sW[i] = W[i];
    if (threadIdx.x < 16) sB[threadIdx.x] = b[threadIdx.x];
    int base = blockIdx.x * 16;
    ((float4*)sY)[threadIdx.x] = ((const float4*)(y + (size_t)base * 64))[threadIdx.x];
    __syncthreads();
    int nb = threadIdx.x >> 4;
    int o = threadIdx.x & 15;
    float acc = sB[o];
    const float* x = sY + nb * 64;
#pragma unroll 8
    for (int k = 0; k < 64; ++k) acc = fmaf(x[k], sW[k * 16 + o], acc);
    out[(size_t)(base + nb) * 16 + o] = acc;
}

extern "C" void kernel_launch(void* const* d_in, const int* in_sizes, int n_in,
                              void* d_out, int out_size, void* d_ws, size_t ws_size,
                              hipStream_t stream) {
    (void)in_sizes; (void)n_in; (void)out_size; (void)ws_size;
    const float* xda = (const float*)d_in[0];
    const float* xca = (const float*)d_in[1];
    const float* xdp = (const float*)d_in[2];
    const float* xcp = (const float*)d_in[3];
    const float* winA_w = (const float*)d_in[4];
    const float* winA_b = (const float*)d_in[5];
    const float* winP_w = (const float*)d_in[6];
    const float* winP_b = (const float*)d_in[7];
    const float* writes_wl = (const float*)d_in[8];
    const float* writes_bl = (const float*)d_in[9];
    const float* writes_wr = (const float*)d_in[10];
    const float* wb_wl = (const float*)d_in[11];
    const float* wb_bl = (const float*)d_in[12];
    const float* wb_wr = (const float*)d_in[13];
    const float* cites_wl = (const float*)d_in[14];
    const float* cites_bl = (const float*)d_in[15];
    const float* cites_wr = (const float*)d_in[16];
    const float* lin_w = (const float*)d_in[17];
    const float* lin_b = (const float*)d_in[18];
    const int* w_src = (const int*)d_in[19];
    const int* w_dst = (const int*)d_in[20];
    const int* b_src = (const int*)d_in[21];
    const int* b_dst = (const int*)d_in[22];
    const int* c_src = (const int*)d_in[23];
    const int* c_dst = (const int*)d_in[24];

    float* ws = (float*)d_ws;
    const size_t NF = (size_t)NNODE * 64;
    float* B0 = ws;            // y_a0, later L1 agg_writes, later y_p2
    float* B1 = ws + NF;       // y_p0, later L1 agg_cites
    float* B2 = ws + 2 * NF;   // L0 agg_writes -> y_p1
    float* B3 = ws + 3 * NF;   // L0 agg_cites
    float* B4 = ws + 4 * NF;   // L0 agg_wb -> y_a1
    float* inv_w = ws + 5 * NF;
    float* inv_c = inv_w + NNODE;
    float* inv_b = inv_c + NNODE;

    const int EB = NEDGE / 256;        // 6250
    const int NB = NNODE / 16;         // 6250
    const int AB = (NEDGE * 16) / 256; // 100000

    // degree counts + inverses (edge structure is layer-invariant)
    hipMemsetAsync(inv_w, 0, 3 * NNODE * sizeof(float), stream);
    count_kernel<<<EB, 256, 0, stream>>>(w_dst, inv_w, NEDGE);
    count_kernel<<<EB, 256, 0, stream>>>(c_dst, inv_c, NEDGE);
    count_kernel<<<EB, 256, 0, stream>>>(b_dst, inv_b, NEDGE);
    inv_kernel<<<(3 * NNODE + 255) / 256, 256, 0, stream>>>(inv_w, 3 * NNODE);

    // input projections
    proj_kernel<<<NB, 256, 0, stream>>>(xda, xca, winA_w, winA_b, B0);
    proj_kernel<<<NB, 256, 0, stream>>>(xdp, xcp, winP_w, winP_b, B1);

    // ---- layer 0 ----
    hipMemsetAsync(B2, 0, 3 * NF * sizeof(float), stream);
    aggregate_kernel<<<AB, 256, 0, stream>>>(B0, w_src, w_dst, B2, NEDGE);
    aggregate_kernel<<<AB, 256, 0, stream>>>(B1, c_src, c_dst, B3, NEDGE);
    aggregate_kernel<<<AB, 256, 0, stream>>>(B1, b_src, b_dst, B4, NEDGE);
    combine_kernel<1><<<NB, 256, 0, stream>>>(B2, inv_w, B3, inv_c, B1,
        writes_wl, cites_wl, writes_wr, cites_wr, writes_bl, cites_bl, B2);
    combine_kernel<0><<<NB, 256, 0, stream>>>(B4, inv_b, nullptr, nullptr, B0,
        wb_wl, nullptr, wb_wr, nullptr, wb_bl, nullptr, B4);

    // ---- layer 1 ---- (author update is dead code in the reference: skipped)
    hipMemsetAsync(B0, 0, 2 * NF * sizeof(float), stream);
    aggregate_kernel<<<AB, 256, 0, stream>>>(B4, w_src, w_dst, B0, NEDGE);
    aggregate_kernel<<<AB, 256, 0, stream>>>(B2, c_src, c_dst, B1, NEDGE);
    combine_kernel<1><<<NB, 256, 0, stream>>>(B0, inv_w, B1, inv_c, B2,
        writes_wl + 4096, cites_wl + 4096, writes_wr + 4096, cites_wr + 4096,
        writes_bl + 64, cites_bl + 64, B0);

    // final projection to OUT=16
    final_kernel<<<NB, 256, 0, stream>>>(B0, lin_w, lin_b, (float*)d_out);
}

// Round 2
// 1212.395 us; speedup vs baseline: 6.0289x; 6.0289x over previous
//
#include <hip/hip_runtime.h>

#define NNODE 100000
#define NEDGE 1600000
#define SCAN_B 1024
#define SCAN_NBLK 98  // ceil(100000/1024)

// ---------------- CSR build: histogram ----------------
__global__ __launch_bounds__(256) void hist_kernel(const int* __restrict__ dst,
                                                   int* __restrict__ cnt, int E) {
    int e = blockIdx.x * 256 + threadIdx.x;
    if (e < E) atomicAdd(&cnt[dst[e]], 1);
}

// ---------------- CSR build: 3-kernel exclusive scan ----------------
__global__ __launch_bounds__(SCAN_B) void scan1(const int* __restrict__ cnt,
                                                int* __restrict__ excl,
                                                int* __restrict__ part, int n) {
    __shared__ int s[SCAN_B];
    int t = threadIdx.x;
    int g = blockIdx.x * SCAN_B + t;
    int v = (g < n) ? cnt[g] : 0;
    s[t] = v;
    __syncthreads();
    for (int off = 1; off < SCAN_B; off <<= 1) {
        int a = s[t];
        int b = (t >= off) ? s[t - off] : 0;
        __syncthreads();
        s[t] = a + b;
        __syncthreads();
    }
    if (g < n) excl[g] = s[t] - v;
    if (t == SCAN_B - 1) part[blockIdx.x] = s[t];
}

__global__ void scan2(int* __restrict__ part, int nb) {
    if (threadIdx.x == 0 && blockIdx.x == 0) {
        int run = 0;
        for (int i = 0; i < nb; ++i) { int v = part[i]; part[i] = run; run += v; }
    }
}

__global__ __launch_bounds__(SCAN_B) void scan3(int* __restrict__ excl,
                                                const int* __restrict__ part,
                                                int n, int total) {
    int g = blockIdx.x * SCAN_B + threadIdx.x;
    if (g < n) excl[g] += part[blockIdx.x];
    if (g == 0) excl[n] = total;
}

// ---------------- CSR build: cursor init + scatter ----------------
__global__ __launch_bounds__(256) void copy_kernel(const int* __restrict__ a,
                                                   int* __restrict__ b, int n) {
    int i = blockIdx.x * 256 + threadIdx.x;
    if (i < n) b[i] = a[i];
}

__global__ __launch_bounds__(256) void scatter_kernel(const int* __restrict__ src,
                                                      const int* __restrict__ dst,
                                                      int* __restrict__ cursor,
                                                      int* __restrict__ ssrc, int E) {
    int e = blockIdx.x * 256 + threadIdx.x;
    if (e < E) {
        int p = atomicAdd(&cursor[dst[e]], 1);
        ssrc[p] = src[e];
    }
}

// ---------------- gather-mean aggregation: one wave per dst node ----------------
// lane = feature index; serial over edge list, 4-deep unrolled independent loads.
__global__ __launch_bounds__(256) void gather_mean_kernel(const float* __restrict__ x,
                                                          const int* __restrict__ rowptr,
                                                          const int* __restrict__ ssrc,
                                                          float* __restrict__ out, int n) {
    int wid = (blockIdx.x * 256 + threadIdx.x) >> 6;
    int lane = threadIdx.x & 63;
    if (wid >= n) return;
    int start = rowptr[wid], end = rowptr[wid + 1];
    float acc = 0.f;
    int e = start;
    for (; e + 4 <= end; e += 4) {
        int s0 = ssrc[e], s1 = ssrc[e + 1], s2 = ssrc[e + 2], s3 = ssrc[e + 3];
        float v0 = x[(size_t)s0 * 64 + lane];
        float v1 = x[(size_t)s1 * 64 + lane];
        float v2 = x[(size_t)s2 * 64 + lane];
        float v3 = x[(size_t)s3 * 64 + lane];
        acc += v0 + v1 + v2 + v3;
    }
    for (; e < end; ++e) acc += x[(size_t)ssrc[e] * 64 + lane];
    float scale = 1.0f / fmaxf((float)(end - start), 1.0f);
    out[(size_t)wid * 64 + lane] = acc * scale;
}

// ---------------- input projection: relu(concat(xd,xc) @ W + b) ----------------
__global__ __launch_bounds__(256) void proj_kernel(const float* __restrict__ xd,
                                                   const float* __restrict__ xc,
                                                   const float* __restrict__ W,
                                                   const float* __restrict__ b,
                                                   float* __restrict__ out) {
    __shared__ float sW[64 * 64];
    __shared__ float sX[16 * 64];
    for (int i = threadIdx.x; i < 4096; i += 256) sW[i] = W[i];
    int base = blockIdx.x * 16;
    for (int i = threadIdx.x; i < 1024; i += 256) {
        int node = base + (i >> 6);
        int k = i & 63;
        sX[i] = (k < 32) ? xd[(size_t)node * 32 + k] : xc[(size_t)node * 32 + k - 32];
    }
    __syncthreads();
    int t = threadIdx.x;
    int nb = t >> 4;
    int h4 = (t & 15) << 2;
    float4 acc = *(const float4*)(b + h4);
    const float* x = sX + nb * 64;
#pragma unroll 8
    for (int k = 0; k < 64; ++k) {
        float xv = x[k];
        float4 w = *(const float4*)(sW + k * 64 + h4);
        acc.x = fmaf(xv, w.x, acc.x);
        acc.y = fmaf(xv, w.y, acc.y);
        acc.z = fmaf(xv, w.z, acc.z);
        acc.w = fmaf(xv, w.w, acc.w);
    }
    int node = base + nb;
    float4 r;
    r.x = fmaxf(acc.x, 0.f);
    r.y = fmaxf(acc.y, 0.f);
    r.z = fmaxf(acc.z, 0.f);
    r.w = fmaxf(acc.w, 0.f);
    *(float4*)(out + (size_t)node * 64 + h4) = r;
}

// ---------------- SAGE combine: out = mw @ wlw [+ mc @ wlc] + y @ (wrw[+wrc]) + bias
// mw/mc are already means. In-place safe per-row (out may alias mw). ----------------
template <int HAS_C>
__global__ __launch_bounds__(256) void combine_kernel(
    const float* __restrict__ mw, const float* __restrict__ mc,
    const float* __restrict__ y,
    const float* __restrict__ wlw, const float* __restrict__ wlc,
    const float* __restrict__ wrw, const float* __restrict__ wrc,
    const float* __restrict__ blw, const float* __restrict__ blc,
    float* __restrict__ out) {
    __shared__ float sWlw[4096];
    __shared__ float sWr[4096];
    __shared__ float sWlc[HAS_C ? 4096 : 4];
    __shared__ float sM[1024];
    __shared__ float sY[1024];
    __shared__ float sMc[HAS_C ? 1024 : 4];
    for (int i = threadIdx.x; i < 4096; i += 256) {
        sWlw[i] = wlw[i];
        sWr[i] = HAS_C ? (wrw[i] + wrc[i]) : wrw[i];
        if (HAS_C) sWlc[i] = wlc[i];
    }
    int base = blockIdx.x * 16;
    {
        int i4 = threadIdx.x;
        ((float4*)sM)[i4] = ((const float4*)(mw + (size_t)base * 64))[i4];
        ((float4*)sY)[i4] = ((const float4*)(y + (size_t)base * 64))[i4];
        if (HAS_C) ((float4*)sMc)[i4] = ((const float4*)(mc + (size_t)base * 64))[i4];
    }
    __syncthreads();
    int t = threadIdx.x;
    int nb = t >> 4;
    int h4 = (t & 15) << 2;
    float4 acc = *(const float4*)(blw + h4);
    if (HAS_C) {
        float4 b2 = *(const float4*)(blc + h4);
        acc.x += b2.x; acc.y += b2.y; acc.z += b2.z; acc.w += b2.w;
    }
    const float* xm = sM + nb * 64;
    const float* xy = sY + nb * 64;
    const float* xc2 = sMc + nb * 64;
#pragma unroll 4
    for (int k = 0; k < 64; ++k) {
        float a1 = xm[k];
        float4 w1 = *(const float4*)(sWlw + k * 64 + h4);
        acc.x = fmaf(a1, w1.x, acc.x);
        acc.y = fmaf(a1, w1.y, acc.y);
        acc.z = fmaf(a1, w1.z, acc.z);
        acc.w = fmaf(a1, w1.w, acc.w);
        float a3 = xy[k];
        float4 w3 = *(const float4*)(sWr + k * 64 + h4);
        acc.x = fmaf(a3, w3.x, acc.x);
        acc.y = fmaf(a3, w3.y, acc.y);
        acc.z = fmaf(a3, w3.z, acc.z);
        acc.w = fmaf(a3, w3.w, acc.w);
        if (HAS_C) {
            float a2 = xc2[k];
            float4 w2 = *(const float4*)(sWlc + k * 64 + h4);
            acc.x = fmaf(a2, w2.x, acc.x);
            acc.y = fmaf(a2, w2.y, acc.y);
            acc.z = fmaf(a2, w2.z, acc.z);
            acc.w = fmaf(a2, w2.w, acc.w);
        }
    }
    *(float4*)(out + (size_t)(base + nb) * 64 + h4) = acc;
}

// ---------------- final: out = y @ lin_w + lin_b  [100k,64]x[64,16] ----------------
__global__ __launch_bounds__(256) void final_kernel(const float* __restrict__ y,
                                                    const float* __restrict__ W,
                                                    const float* __restrict__ b,
                                                    float* __restrict__ out) {
    __shared__ float sW[64 * 16];
    __shared__ float sY[16 * 64];
    __shared__ float sB[16];
    for (int i = threadIdx.x; i < 1024; i += 256) sW[i] = W[i];
    if (threadIdx.x < 16) sB[threadIdx.x] = b[threadIdx.x];
    int base = blockIdx.x * 16;
    ((float4*)sY)[threadIdx.x] = ((const float4*)(y + (size_t)base * 64))[threadIdx.x];
    __syncthreads();
    int nb = threadIdx.x >> 4;
    int o = threadIdx.x & 15;
    float acc = sB[o];
    const float* x = sY + nb * 64;
#pragma unroll 8
    for (int k = 0; k < 64; ++k) acc = fmaf(x[k], sW[k * 16 + o], acc);
    out[(size_t)(base + nb) * 16 + o] = acc;
}

extern "C" void kernel_launch(void* const* d_in, const int* in_sizes, int n_in,
                              void* d_out, int out_size, void* d_ws, size_t ws_size,
                              hipStream_t stream) {
    (void)in_sizes; (void)n_in; (void)out_size; (void)ws_size;
    const float* xda = (const float*)d_in[0];
    const float* xca = (const float*)d_in[1];
    const float* xdp = (const float*)d_in[2];
    const float* xcp = (const float*)d_in[3];
    const float* winA_w = (const float*)d_in[4];
    const float* winA_b = (const float*)d_in[5];
    const float* winP_w = (const float*)d_in[6];
    const float* winP_b = (const float*)d_in[7];
    const float* writes_wl = (const float*)d_in[8];
    const float* writes_bl = (const float*)d_in[9];
    const float* writes_wr = (const float*)d_in[10];
    const float* wb_wl = (const float*)d_in[11];
    const float* wb_bl = (const float*)d_in[12];
    const float* wb_wr = (const float*)d_in[13];
    const float* cites_wl = (const float*)d_in[14];
    const float* cites_bl = (const float*)d_in[15];
    const float* cites_wr = (const float*)d_in[16];
    const float* lin_w = (const float*)d_in[17];
    const float* lin_b = (const float*)d_in[18];
    const int* w_src = (const int*)d_in[19];
    const int* w_dst = (const int*)d_in[20];
    const int* b_src = (const int*)d_in[21];
    const int* b_dst = (const int*)d_in[22];
    const int* c_src = (const int*)d_in[23];
    const int* c_dst = (const int*)d_in[24];

    float* ws = (float*)d_ws;
    const size_t NF = (size_t)NNODE * 64;
    float* B0 = ws;            // y_a0, later L1 mean_writes, later y_p2
    float* B1 = ws + NF;       // y_p0, later L1 mean_cites
    float* B2 = ws + 2 * NF;   // L0 mean_writes -> y_p1
    float* B3 = ws + 3 * NF;   // L0 mean_cites
    float* B4 = ws + 4 * NF;   // L0 mean_wb -> y_a1

    // CSR scratch (per edge type: cnt/cursor, rowptr, ssrc, partials)
    int* ip = (int*)(ws + 5 * NF);
    int* cnt_w = ip;                 // reused as cursor
    int* cnt_c = cnt_w + NNODE;
    int* cnt_b = cnt_c + NNODE;
    int* rp_w = cnt_b + NNODE;       // NNODE+1 each
    int* rp_c = rp_w + (NNODE + 1);
    int* rp_b = rp_c + (NNODE + 1);
    int* ss_w = rp_b + (NNODE + 1);  // NEDGE each
    int* ss_c = ss_w + NEDGE;
    int* ss_b = ss_c + NEDGE;
    int* part_w = ss_b + NEDGE;      // 128 each
    int* part_c = part_w + 128;
    int* part_b = part_c + 128;

    const int EB = NEDGE / 256;         // 6250
    const int NB = NNODE / 16;          // 6250
    const int GB = (NNODE * 64) / 256;  // 25000 (wave per node)
    const int CB = (NNODE + 255) / 256; // 391

    // ---- CSR build (edge structure is layer-invariant) ----
    hipMemsetAsync(cnt_w, 0, 3 * NNODE * sizeof(int), stream);
    hist_kernel<<<EB, 256, 0, stream>>>(w_dst, cnt_w, NEDGE);
    hist_kernel<<<EB, 256, 0, stream>>>(c_dst, cnt_c, NEDGE);
    hist_kernel<<<EB, 256, 0, stream>>>(b_dst, cnt_b, NEDGE);
    scan1<<<SCAN_NBLK, SCAN_B, 0, stream>>>(cnt_w, rp_w, part_w, NNODE);
    scan1<<<SCAN_NBLK, SCAN_B, 0, stream>>>(cnt_c, rp_c, part_c, NNODE);
    scan1<<<SCAN_NBLK, SCAN_B, 0, stream>>>(cnt_b, rp_b, part_b, NNODE);
    scan2<<<1, 64, 0, stream>>>(part_w, SCAN_NBLK);
    scan2<<<1, 64, 0, stream>>>(part_c, SCAN_NBLK);
    scan2<<<1, 64, 0, stream>>>(part_b, SCAN_NBLK);
    scan3<<<SCAN_NBLK, SCAN_B, 0, stream>>>(rp_w, part_w, NNODE, NEDGE);
    scan3<<<SCAN_NBLK, SCAN_B, 0, stream>>>(rp_c, part_c, NNODE, NEDGE);
    scan3<<<SCAN_NBLK, SCAN_B, 0, stream>>>(rp_b, part_b, NNODE, NEDGE);
    copy_kernel<<<CB, 256, 0, stream>>>(rp_w, cnt_w, NNODE);
    copy_kernel<<<CB, 256, 0, stream>>>(rp_c, cnt_c, NNODE);
    copy_kernel<<<CB, 256, 0, stream>>>(rp_b, cnt_b, NNODE);
    scatter_kernel<<<EB, 256, 0, stream>>>(w_src, w_dst, cnt_w, ss_w, NEDGE);
    scatter_kernel<<<EB, 256, 0, stream>>>(c_src, c_dst, cnt_c, ss_c, NEDGE);
    scatter_kernel<<<EB, 256, 0, stream>>>(b_src, b_dst, cnt_b, ss_b, NEDGE);

    // ---- input projections ----
    proj_kernel<<<NB, 256, 0, stream>>>(xda, xca, winA_w, winA_b, B0);
    proj_kernel<<<NB, 256, 0, stream>>>(xdp, xcp, winP_w, winP_b, B1);

    // ---- layer 0 ----
    gather_mean_kernel<<<GB, 256, 0, stream>>>(B0, rp_w, ss_w, B2, NNODE);
    gather_mean_kernel<<<GB, 256, 0, stream>>>(B1, rp_c, ss_c, B3, NNODE);
    gather_mean_kernel<<<GB, 256, 0, stream>>>(B1, rp_b, ss_b, B4, NNODE);
    combine_kernel<1><<<NB, 256, 0, stream>>>(B2, B3, B1,
        writes_wl, cites_wl, writes_wr, cites_wr, writes_bl, cites_bl, B2);
    combine_kernel<0><<<NB, 256, 0, stream>>>(B4, nullptr, B0,
        wb_wl, nullptr, wb_wr, nullptr, wb_bl, nullptr, B4);

    // ---- layer 1 ---- (author update is dead code in the reference: skipped)
    gather_mean_kernel<<<GB, 256, 0, stream>>>(B4, rp_w, ss_w, B0, NNODE);
    gather_mean_kernel<<<GB, 256, 0, stream>>>(B2, rp_c, ss_c, B1, NNODE);
    combine_kernel<1><<<NB, 256, 0, stream>>>(B0, B1, B2,
        writes_wl + 4096, cites_wl + 4096, writes_wr + 4096, cites_wr + 4096,
        writes_bl + 64, cites_bl + 64, B0);

    // ---- final projection to OUT=16 ----
    final_kernel<<<NB, 256, 0, stream>>>(B0, lin_w, lin_b, (float*)d_out);
}

// Round 3
// 958.156 us; speedup vs baseline: 7.6287x; 1.2653x over previous
//
#include <hip/hip_runtime.h>

#define NNODE 100000
#define NEDGE 1600000
#define SCAN_B 1024
#define SCAN_NBLK 98   // ceil(100000/1024)
#define NBUCK 196      // ceil(100000/512)
#define BSH 9          // 512 nodes per bucket

// ============ CSR build (batched over 3 edge types via blockIdx.y) ============

__global__ __launch_bounds__(256) void hist_kernel(const int* __restrict__ d0,
                                                   const int* __restrict__ d1,
                                                   const int* __restrict__ d2,
                                                   int* __restrict__ cnt) {
    int e = blockIdx.x * 256 + threadIdx.x;
    int y = blockIdx.y;
    const int* dst = (y == 0) ? d0 : (y == 1) ? d1 : d2;
    if (e < NEDGE) atomicAdd(&cnt[(size_t)y * NNODE + dst[e]], 1);
}

__global__ __launch_bounds__(SCAN_B) void scan1(const int* __restrict__ cnt,
                                                int* __restrict__ rp,
                                                int* __restrict__ part) {
    int y = blockIdx.y;
    cnt += (size_t)y * NNODE;
    rp += (size_t)y * (NNODE + 1);
    part += y * 128;
    __shared__ int s[SCAN_B];
    int t = threadIdx.x;
    int g = blockIdx.x * SCAN_B + t;
    int v = (g < NNODE) ? cnt[g] : 0;
    s[t] = v;
    __syncthreads();
    for (int off = 1; off < SCAN_B; off <<= 1) {
        int a = s[t];
        int b = (t >= off) ? s[t - off] : 0;
        __syncthreads();
        s[t] = a + b;
        __syncthreads();
    }
    if (g < NNODE) rp[g] = s[t] - v;
    if (t == SCAN_B - 1) part[blockIdx.x] = s[t];
}

// one block per edge type; 98 partials scanned in LDS
__global__ __launch_bounds__(128) void scan2(int* __restrict__ part) {
    part += blockIdx.x * 128;
    __shared__ int s[128];
    int t = threadIdx.x;
    int v = (t < SCAN_NBLK) ? part[t] : 0;
    s[t] = v;
    __syncthreads();
    for (int off = 1; off < 128; off <<= 1) {
        int a = s[t];
        int b = (t >= off) ? s[t - off] : 0;
        __syncthreads();
        s[t] = a + b;
        __syncthreads();
    }
    if (t < SCAN_NBLK) part[t] = s[t] - v;  // exclusive
}

__global__ __launch_bounds__(SCAN_B) void scan3(int* __restrict__ rp,
                                                const int* __restrict__ part) {
    int y = blockIdx.y;
    rp += (size_t)y * (NNODE + 1);
    part += y * 128;
    int g = blockIdx.x * SCAN_B + threadIdx.x;
    if (g < NNODE) rp[g] += part[blockIdx.x];
    if (g == 0) rp[NNODE] = NEDGE;
}

__global__ __launch_bounds__(256) void bcinit_kernel(const int* __restrict__ rp,
                                                     int* __restrict__ bc) {
    int y = blockIdx.x;
    int b = threadIdx.x;
    if (b < NBUCK) bc[y * 256 + b] = rp[(size_t)y * (NNODE + 1) + ((size_t)b << BSH)];
}

// Phase A: partition edges into dst-buckets (allocation-ordered append streams).
__global__ __launch_bounds__(256) void partition_kernel(
    const int* __restrict__ s0, const int* __restrict__ s1, const int* __restrict__ s2,
    const int* __restrict__ d0, const int* __restrict__ d1, const int* __restrict__ d2,
    int* __restrict__ bc, int2* __restrict__ pairs) {
    int y = blockIdx.y;
    const int* src = (y == 0) ? s0 : (y == 1) ? s1 : s2;
    const int* dst = (y == 0) ? d0 : (y == 1) ? d1 : d2;
    int* bcur = bc + y * 256;
    int2* pr = pairs + (size_t)y * NEDGE;

    __shared__ int2 sE[1024];
    __shared__ int sCnt[NBUCK];
    __shared__ int sBase[NBUCK];
    __shared__ int sOff[NBUCK];
    int t = threadIdx.x;
    for (int i = t; i < NBUCK; i += 256) { sCnt[i] = 0; sOff[i] = 0; }
    __syncthreads();
    int base = blockIdx.x * 1024;
#pragma unroll 4
    for (int i = t; i < 1024; i += 256) {
        int e = base + i;
        int2 p = make_int2(0, -1);
        if (e < NEDGE) {
            p.x = src[e];
            p.y = dst[e];
            atomicAdd(&sCnt[p.y >> BSH], 1);
        }
        sE[i] = p;
    }
    __syncthreads();
    for (int b = t; b < NBUCK; b += 256)
        if (sCnt[b]) sBase[b] = atomicAdd(&bcur[b], sCnt[b]);
    __syncthreads();
#pragma unroll 4
    for (int i = t; i < 1024; i += 256) {
        int2 p = sE[i];
        if (p.y >= 0) {
            int b = p.y >> BSH;
            int pos = sBase[b] + atomicAdd(&sOff[b], 1);
            pr[pos] = p;
        }
    }
}

// Phase B: within-bucket scatter; LDS cursors, writes stay in one L2 region.
__global__ __launch_bounds__(256) void bucket_scatter_kernel(
    const int* __restrict__ rp, const int2* __restrict__ pairs,
    int* __restrict__ ssrc) {
    int y = blockIdx.y;
    rp += (size_t)y * (NNODE + 1);
    pairs += (size_t)y * NEDGE;
    ssrc += (size_t)y * NEDGE;
    __shared__ int cur[512];
    int b = blockIdx.x;
    int node0 = b << BSH;
    int nn = min(512, NNODE - node0);
    int t = threadIdx.x;
    for (int i = t; i < nn; i += 256) cur[i] = rp[node0 + i];
    __syncthreads();
    int start = rp[node0];
    int end = rp[min(node0 + 512, NNODE)];
    for (int e = start + t; e < end; e += 256) {
        int2 p = pairs[e];
        int pos = atomicAdd(&cur[p.y - node0], 1);
        ssrc[pos] = p.x;
    }
}

// ============ gather-mean aggregation: one wave per dst node ============
__global__ __launch_bounds__(256) void gather_mean_kernel(const float* __restrict__ x,
                                                          const int* __restrict__ rowptr,
                                                          const int* __restrict__ ssrc,
                                                          float* __restrict__ out, int n) {
    int wid = (blockIdx.x * 256 + threadIdx.x) >> 6;
    int lane = threadIdx.x & 63;
    if (wid >= n) return;
    int start = rowptr[wid], end = rowptr[wid + 1];
    float acc = 0.f;
    int e = start;
    for (; e + 4 <= end; e += 4) {
        int s0 = ssrc[e], s1 = ssrc[e + 1], s2 = ssrc[e + 2], s3 = ssrc[e + 3];
        float v0 = x[(size_t)s0 * 64 + lane];
        float v1 = x[(size_t)s1 * 64 + lane];
        float v2 = x[(size_t)s2 * 64 + lane];
        float v3 = x[(size_t)s3 * 64 + lane];
        acc += v0 + v1 + v2 + v3;
    }
    for (; e < end; ++e) acc += x[(size_t)ssrc[e] * 64 + lane];
    float scale = 1.0f / fmaxf((float)(end - start), 1.0f);
    out[(size_t)wid * 64 + lane] = acc * scale;
}

// ============ input projection: relu(concat(xd,xc) @ W + b) ============
__global__ __launch_bounds__(256) void proj_kernel(const float* __restrict__ xd,
                                                   const float* __restrict__ xc,
                                                   const float* __restrict__ W,
                                                   const float* __restrict__ b,
                                                   float* __restrict__ out) {
    __shared__ float sW[64 * 64];
    __shared__ float sX[16 * 64];
    for (int i = threadIdx.x; i < 4096; i += 256) sW[i] = W[i];
    int base = blockIdx.x * 16;
    for (int i = threadIdx.x; i < 1024; i += 256) {
        int node = base + (i >> 6);
        int k = i & 63;
        sX[i] = (k < 32) ? xd[(size_t)node * 32 + k] : xc[(size_t)node * 32 + k - 32];
    }
    __syncthreads();
    int t = threadIdx.x;
    int nb = t >> 4;
    int h4 = (t & 15) << 2;
    float4 acc = *(const float4*)(b + h4);
    const float* x = sX + nb * 64;
#pragma unroll 8
    for (int k = 0; k < 64; ++k) {
        float xv = x[k];
        float4 w = *(const float4*)(sW + k * 64 + h4);
        acc.x = fmaf(xv, w.x, acc.x);
        acc.y = fmaf(xv, w.y, acc.y);
        acc.z = fmaf(xv, w.z, acc.z);
        acc.w = fmaf(xv, w.w, acc.w);
    }
    int node = base + nb;
    float4 r;
    r.x = fmaxf(acc.x, 0.f);
    r.y = fmaxf(acc.y, 0.f);
    r.z = fmaxf(acc.z, 0.f);
    r.w = fmaxf(acc.w, 0.f);
    *(float4*)(out + (size_t)node * 64 + h4) = r;
}

// ============ SAGE combine ============
template <int HAS_C>
__global__ __launch_bounds__(256) void combine_kernel(
    const float* __restrict__ mw, const float* __restrict__ mc,
    const float* __restrict__ y,
    const float* __restrict__ wlw, const float* __restrict__ wlc,
    const float* __restrict__ wrw, const float* __restrict__ wrc,
    const float* __restrict__ blw, const float* __restrict__ blc,
    float* __restrict__ out) {
    __shared__ float sWlw[4096];
    __shared__ float sWr[4096];
    __shared__ float sWlc[HAS_C ? 4096 : 4];
    __shared__ float sM[1024];
    __shared__ float sY[1024];
    __shared__ float sMc[HAS_C ? 1024 : 4];
    for (int i = threadIdx.x; i < 4096; i += 256) {
        sWlw[i] = wlw[i];
        sWr[i] = HAS_C ? (wrw[i] + wrc[i]) : wrw[i];
        if (HAS_C) sWlc[i] = wlc[i];
    }
    int base = blockIdx.x * 16;
    {
        int i4 = threadIdx.x;
        ((float4*)sM)[i4] = ((const float4*)(mw + (size_t)base * 64))[i4];
        ((float4*)sY)[i4] = ((const float4*)(y + (size_t)base * 64))[i4];
        if (HAS_C) ((float4*)sMc)[i4] = ((const float4*)(mc + (size_t)base * 64))[i4];
    }
    __syncthreads();
    int t = threadIdx.x;
    int nb = t >> 4;
    int h4 = (t & 15) << 2;
    float4 acc = *(const float4*)(blw + h4);
    if (HAS_C) {
        float4 b2 = *(const float4*)(blc + h4);
        acc.x += b2.x; acc.y += b2.y; acc.z += b2.z; acc.w += b2.w;
    }
    const float* xm = sM + nb * 64;
    const float* xy = sY + nb * 64;
    const float* xc2 = sMc + nb * 64;
#pragma unroll 4
    for (int k = 0; k < 64; ++k) {
        float a1 = xm[k];
        float4 w1 = *(const float4*)(sWlw + k * 64 + h4);
        acc.x = fmaf(a1, w1.x, acc.x);
        acc.y = fmaf(a1, w1.y, acc.y);
        acc.z = fmaf(a1, w1.z, acc.z);
        acc.w = fmaf(a1, w1.w, acc.w);
        float a3 = xy[k];
        float4 w3 = *(const float4*)(sWr + k * 64 + h4);
        acc.x = fmaf(a3, w3.x, acc.x);
        acc.y = fmaf(a3, w3.y, acc.y);
        acc.z = fmaf(a3, w3.z, acc.z);
        acc.w = fmaf(a3, w3.w, acc.w);
        if (HAS_C) {
            float a2 = xc2[k];
            float4 w2 = *(const float4*)(sWlc + k * 64 + h4);
            acc.x = fmaf(a2, w2.x, acc.x);
            acc.y = fmaf(a2, w2.y, acc.y);
            acc.z = fmaf(a2, w2.z, acc.z);
            acc.w = fmaf(a2, w2.w, acc.w);
        }
    }
    *(float4*)(out + (size_t)(base + nb) * 64 + h4) = acc;
}

// ============ final: out = y @ lin_w + lin_b ============
__global__ __launch_bounds__(256) void final_kernel(const float* __restrict__ y,
                                                    const float* __restrict__ W,
                                                    const float* __restrict__ b,
                                                    float* __restrict__ out) {
    __shared__ float sW[64 * 16];
    __shared__ float sY[16 * 64];
    __shared__ float sB[16];
    for (int i = threadIdx.x; i < 1024; i += 256) sW[i] = W[i];
    if (threadIdx.x < 16) sB[threadIdx.x] = b[threadIdx.x];
    int base = blockIdx.x * 16;
    ((float4*)sY)[threadIdx.x] = ((const float4*)(y + (size_t)base * 64))[threadIdx.x];
    __syncthreads();
    int nb = threadIdx.x >> 4;
    int o = threadIdx.x & 15;
    float acc = sB[o];
    const float* x = sY + nb * 64;
#pragma unroll 8
    for (int k = 0; k < 64; ++k) acc = fmaf(x[k], sW[k * 16 + o], acc);
    out[(size_t)(base + nb) * 16 + o] = acc;
}

extern "C" void kernel_launch(void* const* d_in, const int* in_sizes, int n_in,
                              void* d_out, int out_size, void* d_ws, size_t ws_size,
                              hipStream_t stream) {
    (void)in_sizes; (void)n_in; (void)out_size; (void)ws_size;
    const float* xda = (const float*)d_in[0];
    const float* xca = (const float*)d_in[1];
    const float* xdp = (const float*)d_in[2];
    const float* xcp = (const float*)d_in[3];
    const float* winA_w = (const float*)d_in[4];
    const float* winA_b = (const float*)d_in[5];
    const float* winP_w = (const float*)d_in[6];
    const float* winP_b = (const float*)d_in[7];
    const float* writes_wl = (const float*)d_in[8];
    const float* writes_bl = (const float*)d_in[9];
    const float* writes_wr = (const float*)d_in[10];
    const float* wb_wl = (const float*)d_in[11];
    const float* wb_bl = (const float*)d_in[12];
    const float* wb_wr = (const float*)d_in[13];
    const float* cites_wl = (const float*)d_in[14];
    const float* cites_bl = (const float*)d_in[15];
    const float* cites_wr = (const float*)d_in[16];
    const float* lin_w = (const float*)d_in[17];
    const float* lin_b = (const float*)d_in[18];
    const int* w_src = (const int*)d_in[19];
    const int* w_dst = (const int*)d_in[20];
    const int* b_src = (const int*)d_in[21];
    const int* b_dst = (const int*)d_in[22];
    const int* c_src = (const int*)d_in[23];
    const int* c_dst = (const int*)d_in[24];

    float* ws = (float*)d_ws;
    const size_t NF = (size_t)NNODE * 64;
    float* B0 = ws;            // y_a0 -> L1 mean_writes -> y_p2
    float* B1 = ws + NF;       // y_p0 -> L1 mean_cites
    float* B2 = ws + 2 * NF;   // L0 mean_writes -> y_p1
    float* B3 = ws + 3 * NF;   // L0 mean_cites
    float* B4 = ws + 4 * NF;   // L0 mean_wb -> y_a1

    // int scratch after the 5 feature buffers
    int* ip = (int*)(ws + 5 * NF);
    int* rp = ip;                        // 3 * (NNODE+1)
    int* cnt = rp + 3 * (NNODE + 1);     // 3 * NNODE
    int* part = cnt + 3 * NNODE;         // 3 * 128
    int* bc = part + 3 * 128;            // 3 * 256
    int* ssrc = bc + 3 * 256;            // 3 * NEDGE
    // pair buffer lifetime: CSR build only; feature buffers B2..B4 are written
    // only after CSR build completes -> alias pairs onto B2 (needs 38.4MB < 76.8MB)
    int2* pairs = (int2*)B2;

    const int EB = NEDGE / 256;          // 6250
    const int NB = NNODE / 16;           // 6250
    const int GB = (NNODE * 64) / 256;   // 25000
    const int PB = (NEDGE + 1023) / 1024;  // 1563

    // ---- CSR build (batched over the 3 edge types) ----
    hipMemsetAsync(cnt, 0, 3 * NNODE * sizeof(int), stream);
    hist_kernel<<<dim3(EB, 3), 256, 0, stream>>>(w_dst, c_dst, b_dst, cnt);
    scan1<<<dim3(SCAN_NBLK, 3), SCAN_B, 0, stream>>>(cnt, rp, part);
    scan2<<<3, 128, 0, stream>>>(part);
    scan3<<<dim3(SCAN_NBLK, 3), SCAN_B, 0, stream>>>(rp, part);
    bcinit_kernel<<<3, 256, 0, stream>>>(rp, bc);
    partition_kernel<<<dim3(PB, 3), 256, 0, stream>>>(w_src, c_src, b_src,
                                                      w_dst, c_dst, b_dst, bc, pairs);
    bucket_scatter_kernel<<<dim3(NBUCK, 3), 256, 0, stream>>>(rp, pairs, ssrc);

    const int* rp_w = rp;
    const int* rp_c = rp + (NNODE + 1);
    const int* rp_b = rp + 2 * (NNODE + 1);
    const int* ss_w = ssrc;
    const int* ss_c = ssrc + NEDGE;
    const int* ss_b = ssrc + 2 * NEDGE;

    // ---- input projections ----
    proj_kernel<<<NB, 256, 0, stream>>>(xda, xca, winA_w, winA_b, B0);
    proj_kernel<<<NB, 256, 0, stream>>>(xdp, xcp, winP_w, winP_b, B1);

    // ---- layer 0 ----
    gather_mean_kernel<<<GB, 256, 0, stream>>>(B0, rp_w, ss_w, B2, NNODE);
    gather_mean_kernel<<<GB, 256, 0, stream>>>(B1, rp_c, ss_c, B3, NNODE);
    gather_mean_kernel<<<GB, 256, 0, stream>>>(B1, rp_b, ss_b, B4, NNODE);
    combine_kernel<1><<<NB, 256, 0, stream>>>(B2, B3, B1,
        writes_wl, cites_wl, writes_wr, cites_wr, writes_bl, cites_bl, B2);
    combine_kernel<0><<<NB, 256, 0, stream>>>(B4, nullptr, B0,
        wb_wl, nullptr, wb_wr, nullptr, wb_bl, nullptr, B4);

    // ---- layer 1 ---- (author update is dead code in the reference: skipped)
    gather_mean_kernel<<<GB, 256, 0, stream>>>(B4, rp_w, ss_w, B0, NNODE);
    gather_mean_kernel<<<GB, 256, 0, stream>>>(B2, rp_c, ss_c, B1, NNODE);
    combine_kernel<1><<<NB, 256, 0, stream>>>(B0, B1, B2,
        writes_wl + 4096, cites_wl + 4096, writes_wr + 4096, cites_wr + 4096,
        writes_bl + 64, cites_bl + 64, B0);

    // ---- final projection to OUT=16 ----
    final_kernel<<<NB, 256, 0, stream>>>(B0, lin_w, lin_b, (float*)d_out);
}

// Round 4
// 839.463 us; speedup vs baseline: 8.7073x; 1.1414x over previous
//
#include <hip/hip_runtime.h>

#define NNODE 100000
#define NEDGE 1600000
#define NBUCK 196      // ceil(100000/512)
#define BSH 9          // 512 nodes per bucket
#define BBST 260       // bb row stride (>= NBUCK+1)

// ============ CSR build (batched over 3 edge types via blockIdx.y) ============

// Bucket histogram: LDS per-block, one global atomic per (block,bucket).
__global__ __launch_bounds__(256) void bhist_kernel(const int* __restrict__ d0,
                                                    const int* __restrict__ d1,
                                                    const int* __restrict__ d2,
                                                    int* __restrict__ bcnt) {
    int y = blockIdx.y;
    const int* dst = (y == 0) ? d0 : (y == 1) ? d1 : d2;
    __shared__ int h[NBUCK];
    int t = threadIdx.x;
    for (int i = t; i < NBUCK; i += 256) h[i] = 0;
    __syncthreads();
    int base = blockIdx.x * 1024;
#pragma unroll 4
    for (int i = t; i < 1024; i += 256) {
        int e = base + i;
        if (e < NEDGE) atomicAdd(&h[dst[e] >> BSH], 1);
    }
    __syncthreads();
    for (int b = t; b < NBUCK; b += 256)
        if (h[b]) atomicAdd(&bcnt[y * 256 + b], h[b]);
}

// Scan 196 bucket counts per type -> bucket bases bb + partition cursors bcur.
__global__ __launch_bounds__(256) void bscan_kernel(const int* __restrict__ bcnt,
                                                    int* __restrict__ bb,
                                                    int* __restrict__ bcur) {
    int y = blockIdx.x;
    __shared__ int s[256];
    int t = threadIdx.x;
    int v = (t < NBUCK) ? bcnt[y * 256 + t] : 0;
    s[t] = v;
    __syncthreads();
    for (int off = 1; off < 256; off <<= 1) {
        int a = s[t];
        int b = (t >= off) ? s[t - off] : 0;
        __syncthreads();
        s[t] = a + b;
        __syncthreads();
    }
    int excl = s[t] - v;
    if (t <= NBUCK) bb[y * BBST + t] = (t == NBUCK) ? NEDGE : excl;
    if (t < NBUCK) bcur[y * 256 + t] = excl;
}

// Phase A: partition edges into dst-buckets (allocation-ordered append streams).
__global__ __launch_bounds__(256) void partition_kernel(
    const int* __restrict__ s0, const int* __restrict__ s1, const int* __restrict__ s2,
    const int* __restrict__ d0, const int* __restrict__ d1, const int* __restrict__ d2,
    int* __restrict__ bc, int2* __restrict__ pairs) {
    int y = blockIdx.y;
    const int* src = (y == 0) ? s0 : (y == 1) ? s1 : s2;
    const int* dst = (y == 0) ? d0 : (y == 1) ? d1 : d2;
    int* bcur = bc + y * 256;
    int2* pr = pairs + (size_t)y * NEDGE;

    __shared__ int2 sE[1024];
    __shared__ int sCnt[NBUCK];
    __shared__ int sBase[NBUCK];
    __shared__ int sOff[NBUCK];
    int t = threadIdx.x;
    for (int i = t; i < NBUCK; i += 256) { sCnt[i] = 0; sOff[i] = 0; }
    __syncthreads();
    int base = blockIdx.x * 1024;
#pragma unroll 4
    for (int i = t; i < 1024; i += 256) {
        int e = base + i;
        int2 p = make_int2(0, -1);
        if (e < NEDGE) {
            p.x = src[e];
            p.y = dst[e];
            atomicAdd(&sCnt[p.y >> BSH], 1);
        }
        sE[i] = p;
    }
    __syncthreads();
    for (int b = t; b < NBUCK; b += 256)
        if (sCnt[b]) sBase[b] = atomicAdd(&bcur[b], sCnt[b]);
    __syncthreads();
#pragma unroll 4
    for (int i = t; i < 1024; i += 256) {
        int2 p = sE[i];
        if (p.y >= 0) {
            int b = p.y >> BSH;
            int pos = sBase[b] + atomicAdd(&sOff[b], 1);
            pr[pos] = p;
        }
    }
}

// Phase B: per-bucket CSR finalize — LDS node histogram + LDS scan -> rowptr
// (coalesced write) + LDS-cursor scatter of src ids. No global atomics.
__global__ __launch_bounds__(256) void bucket_csr_kernel(const int* __restrict__ bb,
                                                         const int2* __restrict__ pairs,
                                                         int* __restrict__ rowptr,
                                                         int* __restrict__ ssrc) {
    int y = blockIdx.y;
    bb += y * BBST;
    pairs += (size_t)y * NEDGE;
    rowptr += (size_t)y * (NNODE + 1);
    ssrc += (size_t)y * NEDGE;

    __shared__ int cnt[512];
    __shared__ int cur[512];
    __shared__ int s1[256];
    int b = blockIdx.x;
    int t = threadIdx.x;
    int node0 = b << BSH;
    int start = bb[b], end = bb[b + 1];

    cnt[t] = 0;
    cnt[t + 256] = 0;
    __syncthreads();
    for (int e = start + t; e < end; e += 256)
        atomicAdd(&cnt[pairs[e].y - node0], 1);
    __syncthreads();
    // exclusive scan over 512 counters: 2 elems/thread + Hillis-Steele over 256
    int a0 = cnt[2 * t], a1 = cnt[2 * t + 1];
    s1[t] = a0 + a1;
    __syncthreads();
    for (int off = 1; off < 256; off <<= 1) {
        int a = s1[t];
        int c = (t >= off) ? s1[t - off] : 0;
        __syncthreads();
        s1[t] = a + c;
        __syncthreads();
    }
    int eb = start + s1[t] - (a0 + a1);  // exclusive base for elem 2t
    cur[2 * t] = eb;
    cur[2 * t + 1] = eb + a0;
    int n0 = node0 + 2 * t;
    if (n0 < NNODE) rowptr[n0] = eb;
    if (n0 + 1 < NNODE) rowptr[n0 + 1] = eb + a0;
    if (b == NBUCK - 1 && t == 0) rowptr[NNODE] = NEDGE;
    __syncthreads();
    for (int e = start + t; e < end; e += 256) {
        int2 p = pairs[e];
        int pos = atomicAdd(&cur[p.y - node0], 1);
        ssrc[pos] = p.x;
    }
}

// ============ gather-mean aggregation: one wave per dst node ============
__global__ __launch_bounds__(256) void gather_mean_kernel(const float* __restrict__ x,
                                                          const int* __restrict__ rowptr,
                                                          const int* __restrict__ ssrc,
                                                          float* __restrict__ out, int n) {
    int wid = (blockIdx.x * 256 + threadIdx.x) >> 6;
    int lane = threadIdx.x & 63;
    if (wid >= n) return;
    int start = rowptr[wid], end = rowptr[wid + 1];
    float acc = 0.f;
    int e = start;
    for (; e + 4 <= end; e += 4) {
        int s0 = ssrc[e], s1 = ssrc[e + 1], s2 = ssrc[e + 2], s3 = ssrc[e + 3];
        float v0 = x[(size_t)s0 * 64 + lane];
        float v1 = x[(size_t)s1 * 64 + lane];
        float v2 = x[(size_t)s2 * 64 + lane];
        float v3 = x[(size_t)s3 * 64 + lane];
        acc += v0 + v1 + v2 + v3;
    }
    for (; e < end; ++e) acc += x[(size_t)ssrc[e] * 64 + lane];
    float scale = 1.0f / fmaxf((float)(end - start), 1.0f);
    out[(size_t)wid * 64 + lane] = acc * scale;
}

// ============ input projection: relu(concat(xd,xc) @ W + b) ============
__global__ __launch_bounds__(256) void proj_kernel(const float* __restrict__ xd,
                                                   const float* __restrict__ xc,
                                                   const float* __restrict__ W,
                                                   const float* __restrict__ b,
                                                   float* __restrict__ out) {
    __shared__ float sW[64 * 64];
    __shared__ float sX[16 * 64];
    for (int i = threadIdx.x; i < 4096; i += 256) sW[i] = W[i];
    int base = blockIdx.x * 16;
    for (int i = threadIdx.x; i < 1024; i += 256) {
        int node = base + (i >> 6);
        int k = i & 63;
        sX[i] = (k < 32) ? xd[(size_t)node * 32 + k] : xc[(size_t)node * 32 + k - 32];
    }
    __syncthreads();
    int t = threadIdx.x;
    int nb = t >> 4;
    int h4 = (t & 15) << 2;
    float4 acc = *(const float4*)(b + h4);
    const float* x = sX + nb * 64;
#pragma unroll 8
    for (int k = 0; k < 64; ++k) {
        float xv = x[k];
        float4 w = *(const float4*)(sW + k * 64 + h4);
        acc.x = fmaf(xv, w.x, acc.x);
        acc.y = fmaf(xv, w.y, acc.y);
        acc.z = fmaf(xv, w.z, acc.z);
        acc.w = fmaf(xv, w.w, acc.w);
    }
    int node = base + nb;
    float4 r;
    r.x = fmaxf(acc.x, 0.f);
    r.y = fmaxf(acc.y, 0.f);
    r.z = fmaxf(acc.z, 0.f);
    r.w = fmaxf(acc.w, 0.f);
    *(float4*)(out + (size_t)node * 64 + h4) = r;
}

// ============ SAGE combine ============
template <int HAS_C>
__global__ __launch_bounds__(256) void combine_kernel(
    const float* __restrict__ mw, const float* __restrict__ mc,
    const float* __restrict__ y,
    const float* __restrict__ wlw, const float* __restrict__ wlc,
    const float* __restrict__ wrw, const float* __restrict__ wrc,
    const float* __restrict__ blw, const float* __restrict__ blc,
    float* __restrict__ out) {
    __shared__ float sWlw[4096];
    __shared__ float sWr[4096];
    __shared__ float sWlc[HAS_C ? 4096 : 4];
    __shared__ float sM[1024];
    __shared__ float sY[1024];
    __shared__ float sMc[HAS_C ? 1024 : 4];
    for (int i = threadIdx.x; i < 4096; i += 256) {
        sWlw[i] = wlw[i];
        sWr[i] = HAS_C ? (wrw[i] + wrc[i]) : wrw[i];
        if (HAS_C) sWlc[i] = wlc[i];
    }
    int base = blockIdx.x * 16;
    {
        int i4 = threadIdx.x;
        ((float4*)sM)[i4] = ((const float4*)(mw + (size_t)base * 64))[i4];
        ((float4*)sY)[i4] = ((const float4*)(y + (size_t)base * 64))[i4];
        if (HAS_C) ((float4*)sMc)[i4] = ((const float4*)(mc + (size_t)base * 64))[i4];
    }
    __syncthreads();
    int t = threadIdx.x;
    int nb = t >> 4;
    int h4 = (t & 15) << 2;
    float4 acc = *(const float4*)(blw + h4);
    if (HAS_C) {
        float4 b2 = *(const float4*)(blc + h4);
        acc.x += b2.x; acc.y += b2.y; acc.z += b2.z; acc.w += b2.w;
    }
    const float* xm = sM + nb * 64;
    const float* xy = sY + nb * 64;
    const float* xc2 = sMc + nb * 64;
#pragma unroll 4
    for (int k = 0; k < 64; ++k) {
        float a1 = xm[k];
        float4 w1 = *(const float4*)(sWlw + k * 64 + h4);
        acc.x = fmaf(a1, w1.x, acc.x);
        acc.y = fmaf(a1, w1.y, acc.y);
        acc.z = fmaf(a1, w1.z, acc.z);
        acc.w = fmaf(a1, w1.w, acc.w);
        float a3 = xy[k];
        float4 w3 = *(const float4*)(sWr + k * 64 + h4);
        acc.x = fmaf(a3, w3.x, acc.x);
        acc.y = fmaf(a3, w3.y, acc.y);
        acc.z = fmaf(a3, w3.z, acc.z);
        acc.w = fmaf(a3, w3.w, acc.w);
        if (HAS_C) {
            float a2 = xc2[k];
            float4 w2 = *(const float4*)(sWlc + k * 64 + h4);
            acc.x = fmaf(a2, w2.x, acc.x);
            acc.y = fmaf(a2, w2.y, acc.y);
            acc.z = fmaf(a2, w2.z, acc.z);
            acc.w = fmaf(a2, w2.w, acc.w);
        }
    }
    *(float4*)(out + (size_t)(base + nb) * 64 + h4) = acc;
}

// ============ final: out = y @ lin_w + lin_b ============
__global__ __launch_bounds__(256) void final_kernel(const float* __restrict__ y,
                                                    const float* __restrict__ W,
                                                    const float* __restrict__ b,
                                                    float* __restrict__ out) {
    __shared__ float sW[64 * 16];
    __shared__ float sY[16 * 64];
    __shared__ float sB[16];
    for (int i = threadIdx.x; i < 1024; i += 256) sW[i] = W[i];
    if (threadIdx.x < 16) sB[threadIdx.x] = b[threadIdx.x];
    int base = blockIdx.x * 16;
    ((float4*)sY)[threadIdx.x] = ((const float4*)(y + (size_t)base * 64))[threadIdx.x];
    __syncthreads();
    int nb = threadIdx.x >> 4;
    int o = threadIdx.x & 15;
    float acc = sB[o];
    const float* x = sY + nb * 64;
#pragma unroll 8
    for (int k = 0; k < 64; ++k) acc = fmaf(x[k], sW[k * 16 + o], acc);
    out[(size_t)(base + nb) * 16 + o] = acc;
}

extern "C" void kernel_launch(void* const* d_in, const int* in_sizes, int n_in,
                              void* d_out, int out_size, void* d_ws, size_t ws_size,
                              hipStream_t stream) {
    (void)in_sizes; (void)n_in; (void)out_size; (void)ws_size;
    const float* xda = (const float*)d_in[0];
    const float* xca = (const float*)d_in[1];
    const float* xdp = (const float*)d_in[2];
    const float* xcp = (const float*)d_in[3];
    const float* winA_w = (const float*)d_in[4];
    const float* winA_b = (const float*)d_in[5];
    const float* winP_w = (const float*)d_in[6];
    const float* winP_b = (const float*)d_in[7];
    const float* writes_wl = (const float*)d_in[8];
    const float* writes_bl = (const float*)d_in[9];
    const float* writes_wr = (const float*)d_in[10];
    const float* wb_wl = (const float*)d_in[11];
    const float* wb_bl = (const float*)d_in[12];
    const float* wb_wr = (const float*)d_in[13];
    const float* cites_wl = (const float*)d_in[14];
    const float* cites_bl = (const float*)d_in[15];
    const float* cites_wr = (const float*)d_in[16];
    const float* lin_w = (const float*)d_in[17];
    const float* lin_b = (const float*)d_in[18];
    const int* w_src = (const int*)d_in[19];
    const int* w_dst = (const int*)d_in[20];
    const int* b_src = (const int*)d_in[21];
    const int* b_dst = (const int*)d_in[22];
    const int* c_src = (const int*)d_in[23];
    const int* c_dst = (const int*)d_in[24];

    float* ws = (float*)d_ws;
    const size_t NF = (size_t)NNODE * 64;
    float* B0 = ws;            // y_a0 -> L1 mean_writes -> y_p2
    float* B1 = ws + NF;       // y_p0 -> L1 mean_cites
    float* B2 = ws + 2 * NF;   // L0 mean_writes -> y_p1
    float* B3 = ws + 3 * NF;   // L0 mean_cites
    float* B4 = ws + 4 * NF;   // L0 mean_wb -> y_a1

    // int scratch after the 5 feature buffers
    int* ip = (int*)(ws + 5 * NF);
    int* rp = ip;                        // 3 * (NNODE+1)
    int* bcnt = rp + 3 * (NNODE + 1);    // 3 * 256
    int* bb = bcnt + 3 * 256;            // 3 * BBST
    int* bcur = bb + 3 * BBST;           // 3 * 256
    int* ssrc = bcur + 3 * 256;          // 3 * NEDGE
    // pair buffer lifetime: CSR build only; feature buffers B2..B4 are written
    // only after CSR build completes -> alias pairs onto B2/B3 (38.4MB < 76.8MB)
    int2* pairs = (int2*)B2;

    const int NB = NNODE / 16;             // 6250
    const int GB = (NNODE * 64) / 256;     // 25000
    const int PB = (NEDGE + 1023) / 1024;  // 1563

    // ---- CSR build (batched over the 3 edge types; no global per-node atomics) ----
    hipMemsetAsync(bcnt, 0, 3 * 256 * sizeof(int), stream);
    bhist_kernel<<<dim3(PB, 3), 256, 0, stream>>>(w_dst, c_dst, b_dst, bcnt);
    bscan_kernel<<<3, 256, 0, stream>>>(bcnt, bb, bcur);
    partition_kernel<<<dim3(PB, 3), 256, 0, stream>>>(w_src, c_src, b_src,
                                                      w_dst, c_dst, b_dst, bcur, pairs);
    bucket_csr_kernel<<<dim3(NBUCK, 3), 256, 0, stream>>>(bb, pairs, rp, ssrc);

    const int* rp_w = rp;
    const int* rp_c = rp + (NNODE + 1);
    const int* rp_b = rp + 2 * (NNODE + 1);
    const int* ss_w = ssrc;
    const int* ss_c = ssrc + NEDGE;
    const int* ss_b = ssrc + 2 * NEDGE;

    // ---- input projections ----
    proj_kernel<<<NB, 256, 0, stream>>>(xda, xca, winA_w, winA_b, B0);
    proj_kernel<<<NB, 256, 0, stream>>>(xdp, xcp, winP_w, winP_b, B1);

    // ---- layer 0 ----
    gather_mean_kernel<<<GB, 256, 0, stream>>>(B0, rp_w, ss_w, B2, NNODE);
    gather_mean_kernel<<<GB, 256, 0, stream>>>(B1, rp_c, ss_c, B3, NNODE);
    gather_mean_kernel<<<GB, 256, 0, stream>>>(B1, rp_b, ss_b, B4, NNODE);
    combine_kernel<1><<<NB, 256, 0, stream>>>(B2, B3, B1,
        writes_wl, cites_wl, writes_wr, cites_wr, writes_bl, cites_bl, B2);
    combine_kernel<0><<<NB, 256, 0, stream>>>(B4, nullptr, B0,
        wb_wl, nullptr, wb_wr, nullptr, wb_bl, nullptr, B4);

    // ---- layer 1 ---- (author update is dead code in the reference: skipped)
    gather_mean_kernel<<<GB, 256, 0, stream>>>(B4, rp_w, ss_w, B0, NNODE);
    gather_mean_kernel<<<GB, 256, 0, stream>>>(B2, rp_c, ss_c, B1, NNODE);
    combine_kernel<1><<<NB, 256, 0, stream>>>(B0, B1, B2,
        writes_wl + 4096, cites_wl + 4096, writes_wr + 4096, cites_wr + 4096,
        writes_bl + 64, cites_bl + 64, B0);

    // ---- final projection to OUT=16 ----
    final_kernel<<<NB, 256, 0, stream>>>(B0, lin_w, lin_b, (float*)d_out);
}

// Round 5
// 664.938 us; speedup vs baseline: 10.9927x; 1.2625x over previous
//
#include <hip/hip_runtime.h>
#include <hip/hip_fp16.h>

#define NNODE 100000
#define NEDGE 1600000
#define NBUCK 196      // ceil(100000/512)
#define BSH 9          // 512 nodes per bucket
#define BBST 260       // bb row stride (>= NBUCK+1)
#define PCH 8192       // edges per partition block

// ============ CSR build (batched over 3 edge types via blockIdx.y) ============

// Bucket histogram: LDS per-block, one global atomic per (block,bucket).
__global__ __launch_bounds__(256) void bhist_kernel(const int* __restrict__ d0,
                                                    const int* __restrict__ d1,
                                                    const int* __restrict__ d2,
                                                    int* __restrict__ bcnt) {
    int y = blockIdx.y;
    const int* dst = (y == 0) ? d0 : (y == 1) ? d1 : d2;
    __shared__ int h[NBUCK];
    int t = threadIdx.x;
    for (int i = t; i < NBUCK; i += 256) h[i] = 0;
    __syncthreads();
    int base = blockIdx.x * 1024;
#pragma unroll 4
    for (int i = t; i < 1024; i += 256) {
        int e = base + i;
        if (e < NEDGE) atomicAdd(&h[dst[e] >> BSH], 1);
    }
    __syncthreads();
    for (int b = t; b < NBUCK; b += 256)
        if (h[b]) atomicAdd(&bcnt[y * 256 + b], h[b]);
}

// Scan 196 bucket counts per type -> bucket bases bb + partition cursors bcur.
__global__ __launch_bounds__(256) void bscan_kernel(const int* __restrict__ bcnt,
                                                    int* __restrict__ bb,
                                                    int* __restrict__ bcur) {
    int y = blockIdx.x;
    __shared__ int s[256];
    int t = threadIdx.x;
    int v = (t < NBUCK) ? bcnt[y * 256 + t] : 0;
    s[t] = v;
    __syncthreads();
    for (int off = 1; off < 256; off <<= 1) {
        int a = s[t];
        int b = (t >= off) ? s[t - off] : 0;
        __syncthreads();
        s[t] = a + b;
        __syncthreads();
    }
    int excl = s[t] - v;
    if (t <= NBUCK) bb[y * BBST + t] = (t == NBUCK) ? NEDGE : excl;
    if (t < NBUCK) bcur[y * 256 + t] = excl;
}

// Phase A: partition edges into dst-bucket streams. 2-pass re-read per chunk,
// packed (local_dst<<17)|src writes (src<2^17, local<2^9).
__global__ __launch_bounds__(256) void partition_kernel(
    const int* __restrict__ s0, const int* __restrict__ s1, const int* __restrict__ s2,
    const int* __restrict__ d0, const int* __restrict__ d1, const int* __restrict__ d2,
    int* __restrict__ bc, int* __restrict__ pairs) {
    int y = blockIdx.y;
    const int* src = (y == 0) ? s0 : (y == 1) ? s1 : s2;
    const int* dst = (y == 0) ? d0 : (y == 1) ? d1 : d2;
    int* bcur = bc + y * 256;
    int* pr = pairs + (size_t)y * NEDGE;

    __shared__ int sCnt[NBUCK];
    __shared__ int sBase[NBUCK];
    int t = threadIdx.x;
    for (int i = t; i < NBUCK; i += 256) sCnt[i] = 0;
    __syncthreads();
    int c0 = blockIdx.x * PCH;
    int cend = min(c0 + PCH, NEDGE);
    for (int e = c0 + t; e < cend; e += 256)
        atomicAdd(&sCnt[dst[e] >> BSH], 1);
    __syncthreads();
    for (int b = t; b < NBUCK; b += 256) {
        int c = sCnt[b];
        sBase[b] = c ? atomicAdd(&bcur[b], c) : 0;
    }
    __syncthreads();
    for (int i = t; i < NBUCK; i += 256) sCnt[i] = 0;
    __syncthreads();
    for (int e = c0 + t; e < cend; e += 256) {
        int d = dst[e];
        int b = d >> BSH;
        int off = atomicAdd(&sCnt[b], 1);
        pr[sBase[b] + off] = ((d & 511) << 17) | src[e];
    }
}

// Phase B: per-bucket CSR finalize — LDS node histogram + LDS scan -> rowptr
// (coalesced write) + LDS-cursor scatter of src ids. No global atomics.
__global__ __launch_bounds__(256) void bucket_csr_kernel(const int* __restrict__ bb,
                                                         const int* __restrict__ pairs,
                                                         int* __restrict__ rowptr,
                                                         int* __restrict__ ssrc) {
    int y = blockIdx.y;
    bb += y * BBST;
    pairs += (size_t)y * NEDGE;
    rowptr += (size_t)y * (NNODE + 1);
    ssrc += (size_t)y * NEDGE;

    __shared__ int cnt[512];
    __shared__ int cur[512];
    __shared__ int s1[256];
    int b = blockIdx.x;
    int t = threadIdx.x;
    int node0 = b << BSH;
    int start = bb[b], end = bb[b + 1];

    cnt[t] = 0;
    cnt[t + 256] = 0;
    __syncthreads();
    for (int e = start + t; e < end; e += 256)
        atomicAdd(&cnt[pairs[e] >> 17], 1);
    __syncthreads();
    int a0 = cnt[2 * t], a1 = cnt[2 * t + 1];
    s1[t] = a0 + a1;
    __syncthreads();
    for (int off = 1; off < 256; off <<= 1) {
        int a = s1[t];
        int c = (t >= off) ? s1[t - off] : 0;
        __syncthreads();
        s1[t] = a + c;
        __syncthreads();
    }
    int eb = start + s1[t] - (a0 + a1);
    cur[2 * t] = eb;
    cur[2 * t + 1] = eb + a0;
    int n0 = node0 + 2 * t;
    if (n0 < NNODE) rowptr[n0] = eb;
    if (n0 + 1 < NNODE) rowptr[n0 + 1] = eb + a0;
    if (b == NBUCK - 1 && t == 0) rowptr[NNODE] = NEDGE;
    __syncthreads();
    for (int e = start + t; e < end; e += 256) {
        int p = pairs[e];
        int pos = atomicAdd(&cur[p >> 17], 1);
        ssrc[pos] = p & 0x1FFFF;
    }
}

// ============ gather-mean: one wave per dst node, fp16 rows, 2 edges/wave ============
__global__ __launch_bounds__(256) void gather_mean_kernel(const __half* __restrict__ x,
                                                          const int* __restrict__ rowptr,
                                                          const int* __restrict__ ssrc,
                                                          __half* __restrict__ out, int n) {
    int wid = (blockIdx.x * 256 + threadIdx.x) >> 6;
    int lane = threadIdx.x & 63;
    if (wid >= n) return;
    int hh = lane >> 5;        // half-wave id: edge parity
    int fp = (lane & 31) << 1; // feature pair base
    int start = rowptr[wid], end = rowptr[wid + 1];
    float ax = 0.f, ay = 0.f;
    int e = start + hh;
    for (; e + 6 < end; e += 8) {
        int s0 = ssrc[e], s1 = ssrc[e + 2], s2 = ssrc[e + 4], s3 = ssrc[e + 6];
        float2 f0 = __half22float2(*(const __half2*)(x + ((size_t)s0 << 6) + fp));
        float2 f1 = __half22float2(*(const __half2*)(x + ((size_t)s1 << 6) + fp));
        float2 f2 = __half22float2(*(const __half2*)(x + ((size_t)s2 << 6) + fp));
        float2 f3 = __half22float2(*(const __half2*)(x + ((size_t)s3 << 6) + fp));
        ax += f0.x + f1.x + f2.x + f3.x;
        ay += f0.y + f1.y + f2.y + f3.y;
    }
    for (; e < end; e += 2) {
        float2 f = __half22float2(*(const __half2*)(x + ((size_t)ssrc[e] << 6) + fp));
        ax += f.x;
        ay += f.y;
    }
    ax += __shfl_xor(ax, 32);
    ay += __shfl_xor(ay, 32);
    if (hh == 0) {
        float scale = 1.0f / fmaxf((float)(end - start), 1.0f);
        *(__half2*)(out + ((size_t)wid << 6) + fp) = __floats2half2_rn(ax * scale, ay * scale);
    }
}

// ============ input projection: relu(concat(xd,xc) @ W + b) -> fp16 ============
__global__ __launch_bounds__(256) void proj_kernel(const float* __restrict__ xd,
                                                   const float* __restrict__ xc,
                                                   const float* __restrict__ W,
                                                   const float* __restrict__ b,
                                                   __half* __restrict__ out) {
    __shared__ float sW[64 * 64];
    __shared__ float sX[16 * 64];
    for (int i = threadIdx.x; i < 4096; i += 256) sW[i] = W[i];
    int base = blockIdx.x * 16;
    for (int i = threadIdx.x; i < 1024; i += 256) {
        int node = base + (i >> 6);
        int k = i & 63;
        sX[i] = (k < 32) ? xd[(size_t)node * 32 + k] : xc[(size_t)node * 32 + k - 32];
    }
    __syncthreads();
    int t = threadIdx.x;
    int nb = t >> 4;
    int h4 = (t & 15) << 2;
    float4 acc = *(const float4*)(b + h4);
    const float* x = sX + nb * 64;
#pragma unroll 8
    for (int k = 0; k < 64; ++k) {
        float xv = x[k];
        float4 w = *(const float4*)(sW + k * 64 + h4);
        acc.x = fmaf(xv, w.x, acc.x);
        acc.y = fmaf(xv, w.y, acc.y);
        acc.z = fmaf(xv, w.z, acc.z);
        acc.w = fmaf(xv, w.w, acc.w);
    }
    __half2* o = (__half2*)(out + ((size_t)(base + nb) << 6) + h4);
    o[0] = __floats2half2_rn(fmaxf(acc.x, 0.f), fmaxf(acc.y, 0.f));
    o[1] = __floats2half2_rn(fmaxf(acc.z, 0.f), fmaxf(acc.w, 0.f));
}

// ============ SAGE combine (fp16 features in/out, fp32 math) ============
template <int HAS_C>
__global__ __launch_bounds__(256) void combine_kernel(
    const __half* __restrict__ mw, const __half* __restrict__ mc,
    const __half* __restrict__ y,
    const float* __restrict__ wlw, const float* __restrict__ wlc,
    const float* __restrict__ wrw, const float* __restrict__ wrc,
    const float* __restrict__ blw, const float* __restrict__ blc,
    __half* __restrict__ out) {
    __shared__ float sWlw[4096];
    __shared__ float sWr[4096];
    __shared__ float sWlc[HAS_C ? 4096 : 4];
    __shared__ float sM[1024];
    __shared__ float sY[1024];
    __shared__ float sMc[HAS_C ? 1024 : 4];
    for (int i = threadIdx.x; i < 4096; i += 256) {
        sWlw[i] = wlw[i];
        sWr[i] = HAS_C ? (wrw[i] + wrc[i]) : wrw[i];
        if (HAS_C) sWlc[i] = wlc[i];
    }
    int base = blockIdx.x * 16;
    {
        const __half2* mr = (const __half2*)(mw + ((size_t)base << 6));
        const __half2* yr = (const __half2*)(y + ((size_t)base << 6));
        const __half2* cr = HAS_C ? (const __half2*)(mc + ((size_t)base << 6)) : nullptr;
        for (int i = threadIdx.x; i < 512; i += 256) {
            ((float2*)sM)[i] = __half22float2(mr[i]);
            ((float2*)sY)[i] = __half22float2(yr[i]);
            if (HAS_C) ((float2*)sMc)[i] = __half22float2(cr[i]);
        }
    }
    __syncthreads();
    int t = threadIdx.x;
    int nb = t >> 4;
    int h4 = (t & 15) << 2;
    float4 acc = *(const float4*)(blw + h4);
    if (HAS_C) {
        float4 b2 = *(const float4*)(blc + h4);
        acc.x += b2.x; acc.y += b2.y; acc.z += b2.z; acc.w += b2.w;
    }
    const float* xm = sM + nb * 64;
    const float* xy = sY + nb * 64;
    const float* xc2 = sMc + nb * 64;
#pragma unroll 4
    for (int k = 0; k < 64; ++k) {
        float a1 = xm[k];
        float4 w1 = *(const float4*)(sWlw + k * 64 + h4);
        acc.x = fmaf(a1, w1.x, acc.x);
        acc.y = fmaf(a1, w1.y, acc.y);
        acc.z = fmaf(a1, w1.z, acc.z);
        acc.w = fmaf(a1, w1.w, acc.w);
        float a3 = xy[k];
        float4 w3 = *(const float4*)(sWr + k * 64 + h4);
        acc.x = fmaf(a3, w3.x, acc.x);
        acc.y = fmaf(a3, w3.y, acc.y);
        acc.z = fmaf(a3, w3.z, acc.z);
        acc.w = fmaf(a3, w3.w, acc.w);
        if (HAS_C) {
            float a2 = xc2[k];
            float4 w2 = *(const float4*)(sWlc + k * 64 + h4);
            acc.x = fmaf(a2, w2.x, acc.x);
            acc.y = fmaf(a2, w2.y, acc.y);
            acc.z = fmaf(a2, w2.z, acc.z);
            acc.w = fmaf(a2, w2.w, acc.w);
        }
    }
    __half2* o = (__half2*)(out + ((size_t)(base + nb) << 6) + h4);
    o[0] = __floats2half2_rn(acc.x, acc.y);
    o[1] = __floats2half2_rn(acc.z, acc.w);
}

// ============ final: out = y @ lin_w + lin_b (fp16 y -> fp32 out) ============
__global__ __launch_bounds__(256) void final_kernel(const __half* __restrict__ y,
                                                    const float* __restrict__ W,
                                                    const float* __restrict__ b,
                                                    float* __restrict__ out) {
    __shared__ float sW[64 * 16];
    __shared__ float sY[16 * 64];
    __shared__ float sB[16];
    for (int i = threadIdx.x; i < 1024; i += 256) sW[i] = W[i];
    if (threadIdx.x < 16) sB[threadIdx.x] = b[threadIdx.x];
    int base = blockIdx.x * 16;
    {
        const __half2* yr = (const __half2*)(y + ((size_t)base << 6));
        for (int i = threadIdx.x; i < 512; i += 256)
            ((float2*)sY)[i] = __half22float2(yr[i]);
    }
    __syncthreads();
    int nb = threadIdx.x >> 4;
    int o = threadIdx.x & 15;
    float acc = sB[o];
    const float* x = sY + nb * 64;
#pragma unroll 8
    for (int k = 0; k < 64; ++k) acc = fmaf(x[k], sW[k * 16 + o], acc);
    out[(size_t)(base + nb) * 16 + o] = acc;
}

extern "C" void kernel_launch(void* const* d_in, const int* in_sizes, int n_in,
                              void* d_out, int out_size, void* d_ws, size_t ws_size,
                              hipStream_t stream) {
    (void)in_sizes; (void)n_in; (void)out_size; (void)ws_size;
    const float* xda = (const float*)d_in[0];
    const float* xca = (const float*)d_in[1];
    const float* xdp = (const float*)d_in[2];
    const float* xcp = (const float*)d_in[3];
    const float* winA_w = (const float*)d_in[4];
    const float* winA_b = (const float*)d_in[5];
    const float* winP_w = (const float*)d_in[6];
    const float* winP_b = (const float*)d_in[7];
    const float* writes_wl = (const float*)d_in[8];
    const float* writes_bl = (const float*)d_in[9];
    const float* writes_wr = (const float*)d_in[10];
    const float* wb_wl = (const float*)d_in[11];
    const float* wb_bl = (const float*)d_in[12];
    const float* wb_wr = (const float*)d_in[13];
    const float* cites_wl = (const float*)d_in[14];
    const float* cites_bl = (const float*)d_in[15];
    const float* cites_wr = (const float*)d_in[16];
    const float* lin_w = (const float*)d_in[17];
    const float* lin_b = (const float*)d_in[18];
    const int* w_src = (const int*)d_in[19];
    const int* w_dst = (const int*)d_in[20];
    const int* b_src = (const int*)d_in[21];
    const int* b_dst = (const int*)d_in[22];
    const int* c_src = (const int*)d_in[23];
    const int* c_dst = (const int*)d_in[24];

    const size_t NF = (size_t)NNODE * 64;
    __half* B0 = (__half*)d_ws;      // y_a0 -> L1 mean_writes -> y_p2
    __half* B1 = B0 + NF;            // y_p0 -> L1 mean_cites
    __half* B2 = B1 + NF;            // L0 mean_writes -> y_p1
    __half* B3 = B2 + NF;            // L0 mean_cites
    __half* B4 = B3 + NF;            // L0 mean_wb -> y_a1

    int* ip = (int*)(B4 + NF);
    int* rp = ip;                        // 3 * (NNODE+1)
    int* bcnt = rp + 3 * (NNODE + 1);    // 3 * 256
    int* bb = bcnt + 3 * 256;            // 3 * BBST
    int* bcur = bb + 3 * BBST;           // 3 * 256
    int* ssrc = bcur + 3 * 256;          // 3 * NEDGE
    // packed pair buffer lifetime: CSR build only; B2..B4 written afterwards
    // -> alias 3*NEDGE ints (19.2MB) onto B2.. (38.4MB available)
    int* pairs = (int*)B2;

    const int NB = NNODE / 16;              // 6250
    const int GB = (NNODE * 64) / 256;      // 25000
    const int HB = (NEDGE + 1023) / 1024;   // 1563
    const int PB = (NEDGE + PCH - 1) / PCH; // 196

    // ---- CSR build ----
    hipMemsetAsync(bcnt, 0, 3 * 256 * sizeof(int), stream);
    bhist_kernel<<<dim3(HB, 3), 256, 0, stream>>>(w_dst, c_dst, b_dst, bcnt);
    bscan_kernel<<<3, 256, 0, stream>>>(bcnt, bb, bcur);
    partition_kernel<<<dim3(PB, 3), 256, 0, stream>>>(w_src, c_src, b_src,
                                                      w_dst, c_dst, b_dst, bcur, pairs);
    bucket_csr_kernel<<<dim3(NBUCK, 3), 256, 0, stream>>>(bb, pairs, rp, ssrc);

    const int* rp_w = rp;
    const int* rp_c = rp + (NNODE + 1);
    const int* rp_b = rp + 2 * (NNODE + 1);
    const int* ss_w = ssrc;
    const int* ss_c = ssrc + NEDGE;
    const int* ss_b = ssrc + 2 * NEDGE;

    // ---- input projections ----
    proj_kernel<<<NB, 256, 0, stream>>>(xda, xca, winA_w, winA_b, B0);
    proj_kernel<<<NB, 256, 0, stream>>>(xdp, xcp, winP_w, winP_b, B1);

    // ---- layer 0 ----
    gather_mean_kernel<<<GB, 256, 0, stream>>>(B0, rp_w, ss_w, B2, NNODE);
    gather_mean_kernel<<<GB, 256, 0, stream>>>(B1, rp_c, ss_c, B3, NNODE);
    gather_mean_kernel<<<GB, 256, 0, stream>>>(B1, rp_b, ss_b, B4, NNODE);
    combine_kernel<1><<<NB, 256, 0, stream>>>(B2, B3, B1,
        writes_wl, cites_wl, writes_wr, cites_wr, writes_bl, cites_bl, B2);
    combine_kernel<0><<<NB, 256, 0, stream>>>(B4, nullptr, B0,
        wb_wl, nullptr, wb_wr, nullptr, wb_bl, nullptr, B4);

    // ---- layer 1 ---- (author update is dead code in the reference: skipped)
    gather_mean_kernel<<<GB, 256, 0, stream>>>(B4, rp_w, ss_w, B0, NNODE);
    gather_mean_kernel<<<GB, 256, 0, stream>>>(B2, rp_c, ss_c, B1, NNODE);
    combine_kernel<1><<<NB, 256, 0, stream>>>(B0, B1, B2,
        writes_wl + 4096, cites_wl + 4096, writes_wr + 4096, cites_wr + 4096,
        writes_bl + 64, cites_bl + 64, B0);

    // ---- final projection to OUT=16 ----
    final_kernel<<<NB, 256, 0, stream>>>(B0, lin_w, lin_b, (float*)d_out);
}

// Round 6
// 524.987 us; speedup vs baseline: 13.9231x; 1.2666x over previous
//
#include <hip/hip_runtime.h>
#include <hip/hip_fp16.h>

#define NNODE 100000
#define NEDGE 1600000
#define NBUCK 196      // ceil(100000/512)
#define BSH 9          // 512 nodes per bucket
#define BBST 260       // bb row stride (>= NBUCK+1)
#define PCH 8192       // edges per partition block

typedef _Float16 f16x8 __attribute__((ext_vector_type(8)));
typedef float f32x4 __attribute__((ext_vector_type(4)));

// ============ CSR build (batched over 3 edge types via blockIdx.y) ============

__global__ __launch_bounds__(256) void bhist_kernel(const int* __restrict__ d0,
                                                    const int* __restrict__ d1,
                                                    const int* __restrict__ d2,
                                                    int* __restrict__ bcnt) {
    int y = blockIdx.y;
    const int* dst = (y == 0) ? d0 : (y == 1) ? d1 : d2;
    __shared__ int h[NBUCK];
    int t = threadIdx.x;
    for (int i = t; i < NBUCK; i += 256) h[i] = 0;
    __syncthreads();
    int base = blockIdx.x * 1024;
#pragma unroll 4
    for (int i = t; i < 1024; i += 256) {
        int e = base + i;
        if (e < NEDGE) atomicAdd(&h[dst[e] >> BSH], 1);
    }
    __syncthreads();
    for (int b = t; b < NBUCK; b += 256)
        if (h[b]) atomicAdd(&bcnt[y * 256 + b], h[b]);
}

__global__ __launch_bounds__(256) void bscan_kernel(const int* __restrict__ bcnt,
                                                    int* __restrict__ bb,
                                                    int* __restrict__ bcur) {
    int y = blockIdx.x;
    __shared__ int s[256];
    int t = threadIdx.x;
    int v = (t < NBUCK) ? bcnt[y * 256 + t] : 0;
    s[t] = v;
    __syncthreads();
    for (int off = 1; off < 256; off <<= 1) {
        int a = s[t];
        int b = (t >= off) ? s[t - off] : 0;
        __syncthreads();
        s[t] = a + b;
        __syncthreads();
    }
    int excl = s[t] - v;
    if (t <= NBUCK) bb[y * BBST + t] = (t == NBUCK) ? NEDGE : excl;
    if (t < NBUCK) bcur[y * 256 + t] = excl;
}

// Phase A: partition into dst-bucket streams; packed (local_dst<<17)|src.
__global__ __launch_bounds__(256) void partition_kernel(
    const int* __restrict__ s0, const int* __restrict__ s1, const int* __restrict__ s2,
    const int* __restrict__ d0, const int* __restrict__ d1, const int* __restrict__ d2,
    int* __restrict__ bc, int* __restrict__ pairs) {
    int y = blockIdx.y;
    const int* src = (y == 0) ? s0 : (y == 1) ? s1 : s2;
    const int* dst = (y == 0) ? d0 : (y == 1) ? d1 : d2;
    int* bcur = bc + y * 256;
    int* pr = pairs + (size_t)y * NEDGE;

    __shared__ int sCnt[NBUCK];
    __shared__ int sBase[NBUCK];
    int t = threadIdx.x;
    for (int i = t; i < NBUCK; i += 256) sCnt[i] = 0;
    __syncthreads();
    int c0 = blockIdx.x * PCH;
    int cend = min(c0 + PCH, NEDGE);
    for (int e = c0 + t; e < cend; e += 256)
        atomicAdd(&sCnt[dst[e] >> BSH], 1);
    __syncthreads();
    for (int b = t; b < NBUCK; b += 256) {
        int c = sCnt[b];
        sBase[b] = c ? atomicAdd(&bcur[b], c) : 0;
    }
    __syncthreads();
    for (int i = t; i < NBUCK; i += 256) sCnt[i] = 0;
    __syncthreads();
    for (int e = c0 + t; e < cend; e += 256) {
        int d = dst[e];
        int b = d >> BSH;
        int off = atomicAdd(&sCnt[b], 1);
        pr[sBase[b] + off] = ((d & 511) << 17) | src[e];
    }
}

// Phase B: per-bucket CSR finalize — LDS histogram/scan -> rowptr + scatter.
__global__ __launch_bounds__(256) void bucket_csr_kernel(const int* __restrict__ bb,
                                                         const int* __restrict__ pairs,
                                                         int* __restrict__ rowptr,
                                                         int* __restrict__ ssrc) {
    int y = blockIdx.y;
    bb += y * BBST;
    pairs += (size_t)y * NEDGE;
    rowptr += (size_t)y * (NNODE + 1);
    ssrc += (size_t)y * NEDGE;

    __shared__ int cnt[512];
    __shared__ int cur[512];
    __shared__ int s1[256];
    int b = blockIdx.x;
    int t = threadIdx.x;
    int node0 = b << BSH;
    int start = bb[b], end = bb[b + 1];

    cnt[t] = 0;
    cnt[t + 256] = 0;
    __syncthreads();
    for (int e = start + t; e < end; e += 256)
        atomicAdd(&cnt[pairs[e] >> 17], 1);
    __syncthreads();
    int a0 = cnt[2 * t], a1 = cnt[2 * t + 1];
    s1[t] = a0 + a1;
    __syncthreads();
    for (int off = 1; off < 256; off <<= 1) {
        int a = s1[t];
        int c = (t >= off) ? s1[t - off] : 0;
        __syncthreads();
        s1[t] = a + c;
        __syncthreads();
    }
    int eb = start + s1[t] - (a0 + a1);
    cur[2 * t] = eb;
    cur[2 * t + 1] = eb + a0;
    int n0 = node0 + 2 * t;
    if (n0 < NNODE) rowptr[n0] = eb;
    if (n0 + 1 < NNODE) rowptr[n0 + 1] = eb + a0;
    if (b == NBUCK - 1 && t == 0) rowptr[NNODE] = NEDGE;
    __syncthreads();
    for (int e = start + t; e < end; e += 256) {
        int p = pairs[e];
        int pos = atomicAdd(&cur[p >> 17], 1);
        ssrc[pos] = p & 0x1FFFF;
    }
}

// ============ gather-mean: one wave per dst node, fp16 rows, 2 edges/wave ============
__global__ __launch_bounds__(256) void gather_mean_kernel(const __half* __restrict__ x,
                                                          const int* __restrict__ rowptr,
                                                          const int* __restrict__ ssrc,
                                                          __half* __restrict__ out, int n) {
    int wid = (blockIdx.x * 256 + threadIdx.x) >> 6;
    int lane = threadIdx.x & 63;
    if (wid >= n) return;
    int hh = lane >> 5;
    int fp = (lane & 31) << 1;
    int start = rowptr[wid], end = rowptr[wid + 1];
    float ax = 0.f, ay = 0.f;
    int e = start + hh;
    for (; e + 6 < end; e += 8) {
        int s0 = ssrc[e], s1 = ssrc[e + 2], s2 = ssrc[e + 4], s3 = ssrc[e + 6];
        float2 f0 = __half22float2(*(const __half2*)(x + ((size_t)s0 << 6) + fp));
        float2 f1 = __half22float2(*(const __half2*)(x + ((size_t)s1 << 6) + fp));
        float2 f2 = __half22float2(*(const __half2*)(x + ((size_t)s2 << 6) + fp));
        float2 f3 = __half22float2(*(const __half2*)(x + ((size_t)s3 << 6) + fp));
        ax += f0.x + f1.x + f2.x + f3.x;
        ay += f0.y + f1.y + f2.y + f3.y;
    }
    for (; e < end; e += 2) {
        float2 f = __half22float2(*(const __half2*)(x + ((size_t)ssrc[e] << 6) + fp));
        ax += f.x;
        ay += f.y;
    }
    ax += __shfl_xor(ax, 32);
    ay += __shfl_xor(ay, 32);
    if (hh == 0) {
        float scale = 1.0f / fmaxf((float)(end - start), 1.0f);
        *(__half2*)(out + ((size_t)wid << 6) + fp) = __floats2half2_rn(ax * scale, ay * scale);
    }
}

// ============ weight prep: fp16 W^T (+ summed wr, summed biases) ============
__global__ __launch_bounds__(256) void wprep_kernel(
    const float* __restrict__ writes_wl, const float* __restrict__ cites_wl,
    const float* __restrict__ writes_wr, const float* __restrict__ cites_wr,
    const float* __restrict__ wb_wl, const float* __restrict__ wb_wr,
    const float* __restrict__ winA_w, const float* __restrict__ winP_w,
    const float* __restrict__ lin_w,
    const float* __restrict__ writes_bl, const float* __restrict__ cites_bl,
    __half* __restrict__ wtP0, __half* __restrict__ wtP1, __half* __restrict__ wtA,
    __half* __restrict__ wtPJA, __half* __restrict__ wtPJP, __half* __restrict__ wtLIN,
    float* __restrict__ biasP) {
    int i = blockIdx.x * 256 + threadIdx.x;
    if (i < 24576) {                       // paper combine W^T [64][192] x 2 layers
        int l = i / 12288, j = i % 12288;
        int n = j / 192, k = j % 192;
        float v;
        if (k < 64) v = writes_wl[l * 4096 + k * 64 + n];
        else if (k < 128) v = cites_wl[l * 4096 + (k - 64) * 64 + n];
        else v = writes_wr[l * 4096 + (k - 128) * 64 + n] +
                 cites_wr[l * 4096 + (k - 128) * 64 + n];
        (l ? wtP1 : wtP0)[n * 192 + k] = __float2half(v);
    } else if (i < 32768) {                // author combine W^T [64][128], layer 0
        int j = i - 24576;
        int n = j / 128, k = j % 128;
        float v = (k < 64) ? wb_wl[k * 64 + n] : wb_wr[(k - 64) * 64 + n];
        wtA[n * 128 + k] = __float2half(v);
    } else if (i < 36864) {                // proj author W^T [64][64]
        int j = i - 32768;
        wtPJA[j] = __float2half(winA_w[(j % 64) * 64 + j / 64]);
    } else if (i < 40960) {                // proj paper W^T [64][64]
        int j = i - 36864;
        wtPJP[j] = __float2half(winP_w[(j % 64) * 64 + j / 64]);
    } else if (i < 41984) {                // lin W^T [16][64]
        int j = i - 40960;
        wtLIN[j] = __float2half(lin_w[(j % 64) * 16 + j / 64]);
    } else if (i < 42112) {                // summed paper biases, 2 layers
        int j = i - 41984;
        biasP[j] = writes_bl[j] + cites_bl[j];
    }
}

// ============ MFMA node-GEMMs: wave = 16 nodes, no LDS ============
// A layout: row=lane&15, k=8*(lane>>4)+reg (16B contiguous from fp16 rows).
// B layout: col=lane&15, k contiguous from W^T rows. C: col=lane&15, row=4*(lane>>4)+reg.

__device__ inline f16x8 cvt8(const float* p) {
    float4 a = *(const float4*)p, b = *(const float4*)(p + 4);
    f16x8 r;
    r[0] = (_Float16)a.x; r[1] = (_Float16)a.y; r[2] = (_Float16)a.z; r[3] = (_Float16)a.w;
    r[4] = (_Float16)b.x; r[5] = (_Float16)b.y; r[6] = (_Float16)b.z; r[7] = (_Float16)b.w;
    return r;
}

// relu(concat(xd,xc) @ W + b) -> fp16
__global__ __launch_bounds__(256) void proj_mfma(const float* __restrict__ xd,
                                                 const float* __restrict__ xc,
                                                 const __half* __restrict__ wt,
                                                 const float* __restrict__ bias,
                                                 __half* __restrict__ out) {
    int wid = (blockIdx.x * 256 + threadIdx.x) >> 6;
    if (wid >= NNODE / 16) return;
    int lane = threadIdx.x & 63;
    int row = lane & 15, kq = lane >> 4;
    int node0 = wid << 4;
    f16x8 af0 = cvt8(xd + (size_t)(node0 + row) * 32 + kq * 8);
    f16x8 af1 = cvt8(xc + (size_t)(node0 + row) * 32 + kq * 8);
#pragma unroll
    for (int nt = 0; nt < 4; ++nt) {
        int col = nt * 16 + row;
        const __half* wp = wt + (size_t)col * 64 + kq * 8;
        f32x4 acc = {0.f, 0.f, 0.f, 0.f};
        acc = __builtin_amdgcn_mfma_f32_16x16x32_f16(af0, *(const f16x8*)(wp), acc, 0, 0, 0);
        acc = __builtin_amdgcn_mfma_f32_16x16x32_f16(af1, *(const f16x8*)(wp + 32), acc, 0, 0, 0);
        float b = bias[col];
#pragma unroll
        for (int r = 0; r < 4; ++r)
            out[((size_t)(node0 + kq * 4 + r) << 6) + col] = __float2half(fmaxf(acc[r] + b, 0.f));
    }
}

// out = [a0|a1(|a2)] @ W + bias -> fp16. In-place safe (wave touches own 16 rows).
template <int NSEG>
__global__ __launch_bounds__(256) void combine_mfma(const __half* __restrict__ a0,
                                                    const __half* __restrict__ a1,
                                                    const __half* __restrict__ a2,
                                                    const __half* __restrict__ wt,
                                                    const float* __restrict__ bias,
                                                    __half* __restrict__ out) {
    int wid = (blockIdx.x * 256 + threadIdx.x) >> 6;
    if (wid >= NNODE / 16) return;
    int lane = threadIdx.x & 63;
    int row = lane & 15, kq = lane >> 4;
    int node0 = wid << 4;
    const int K = NSEG * 64;
    const __half* as[3] = {a0, a1, a2};
    f16x8 af[2 * NSEG];
#pragma unroll
    for (int s = 0; s < NSEG; ++s) {
        const __half* p = as[s] + ((size_t)(node0 + row) << 6) + kq * 8;
        af[2 * s] = *(const f16x8*)(p);
        af[2 * s + 1] = *(const f16x8*)(p + 32);
    }
#pragma unroll
    for (int nt = 0; nt < 4; ++nt) {
        int col = nt * 16 + row;
        const __half* wp = wt + (size_t)col * K + kq * 8;
        f32x4 acc = {0.f, 0.f, 0.f, 0.f};
#pragma unroll
        for (int t = 0; t < 2 * NSEG; ++t)
            acc = __builtin_amdgcn_mfma_f32_16x16x32_f16(af[t], *(const f16x8*)(wp + t * 32), acc, 0, 0, 0);
        float b = bias[col];
#pragma unroll
        for (int r = 0; r < 4; ++r)
            out[((size_t)(node0 + kq * 4 + r) << 6) + col] = __float2half(acc[r] + b);
    }
}

// out = y @ lin_w + lin_b -> fp32 [NNODE][16]
__global__ __launch_bounds__(256) void final_mfma(const __half* __restrict__ y,
                                                  const __half* __restrict__ wt,
                                                  const float* __restrict__ bias,
                                                  float* __restrict__ out) {
    int wid = (blockIdx.x * 256 + threadIdx.x) >> 6;
    if (wid >= NNODE / 16) return;
    int lane = threadIdx.x & 63;
    int row = lane & 15, kq = lane >> 4;
    int node0 = wid << 4;
    const __half* p = y + ((size_t)(node0 + row) << 6) + kq * 8;
    f16x8 af0 = *(const f16x8*)(p);
    f16x8 af1 = *(const f16x8*)(p + 32);
    const __half* wp = wt + (size_t)row * 64 + kq * 8;
    f32x4 acc = {0.f, 0.f, 0.f, 0.f};
    acc = __builtin_amdgcn_mfma_f32_16x16x32_f16(af0, *(const f16x8*)(wp), acc, 0, 0, 0);
    acc = __builtin_amdgcn_mfma_f32_16x16x32_f16(af1, *(const f16x8*)(wp + 32), acc, 0, 0, 0);
    float b = bias[row];
#pragma unroll
    for (int r = 0; r < 4; ++r)
        out[(size_t)(node0 + kq * 4 + r) * 16 + row] = acc[r] + b;
}

extern "C" void kernel_launch(void* const* d_in, const int* in_sizes, int n_in,
                              void* d_out, int out_size, void* d_ws, size_t ws_size,
                              hipStream_t stream) {
    (void)in_sizes; (void)n_in; (void)out_size; (void)ws_size;
    const float* xda = (const float*)d_in[0];
    const float* xca = (const float*)d_in[1];
    const float* xdp = (const float*)d_in[2];
    const float* xcp = (const float*)d_in[3];
    const float* winA_w = (const float*)d_in[4];
    const float* winA_b = (const float*)d_in[5];
    const float* winP_w = (const float*)d_in[6];
    const float* winP_b = (const float*)d_in[7];
    const float* writes_wl = (const float*)d_in[8];
    const float* writes_bl = (const float*)d_in[9];
    const float* writes_wr = (const float*)d_in[10];
    const float* wb_wl = (const float*)d_in[11];
    const float* wb_bl = (const float*)d_in[12];
    const float* wb_wr = (const float*)d_in[13];
    const float* cites_wl = (const float*)d_in[14];
    const float* cites_bl = (const float*)d_in[15];
    const float* cites_wr = (const float*)d_in[16];
    const float* lin_w = (const float*)d_in[17];
    const float* lin_b = (const float*)d_in[18];
    const int* w_src = (const int*)d_in[19];
    const int* w_dst = (const int*)d_in[20];
    const int* b_src = (const int*)d_in[21];
    const int* b_dst = (const int*)d_in[22];
    const int* c_src = (const int*)d_in[23];
    const int* c_dst = (const int*)d_in[24];

    const size_t NF = (size_t)NNODE * 64;
    __half* B0 = (__half*)d_ws;      // y_a0 -> L1 mean_writes -> y_p2
    __half* B1 = B0 + NF;            // y_p0 -> L1 mean_cites
    __half* B2 = B1 + NF;            // L0 mean_writes -> y_p1
    __half* B3 = B2 + NF;            // L0 mean_cites
    __half* B4 = B3 + NF;            // L0 mean_wb -> y_a1

    // prepped weights (16B-aligned: 5*NF*2 bytes is a multiple of 16)
    __half* wtP0 = B4 + NF;          // 12288
    __half* wtP1 = wtP0 + 12288;     // 12288
    __half* wtA = wtP1 + 12288;      // 8192
    __half* wtPJA = wtA + 8192;      // 4096
    __half* wtPJP = wtPJA + 4096;    // 4096
    __half* wtLIN = wtPJP + 4096;    // 1024
    float* biasP = (float*)(wtLIN + 1024);  // 128

    int* ip = (int*)(biasP + 128);
    int* rp = ip;                        // 3 * (NNODE+1)
    int* bcnt = rp + 3 * (NNODE + 1);    // 3 * 256
    int* bb = bcnt + 3 * 256;            // 3 * BBST
    int* bcur = bb + 3 * BBST;           // 3 * 256
    int* ssrc = bcur + 3 * 256;          // 3 * NEDGE
    // packed pair buffer: CSR build only; aliased onto B2.. (19.2MB < 38.4MB)
    int* pairs = (int*)B2;

    const int GB = (NNODE * 64) / 256;      // 25000 (wave per node)
    const int MB = (NNODE / 16 + 3) / 4;    // 1563 (wave per 16 nodes)
    const int HB = (NEDGE + 1023) / 1024;   // 1563
    const int PB = (NEDGE + PCH - 1) / PCH; // 196

    // ---- weight prep + CSR build ----
    wprep_kernel<<<165, 256, 0, stream>>>(writes_wl, cites_wl, writes_wr, cites_wr,
                                          wb_wl, wb_wr, winA_w, winP_w, lin_w,
                                          writes_bl, cites_bl,
                                          wtP0, wtP1, wtA, wtPJA, wtPJP, wtLIN, biasP);
    hipMemsetAsync(bcnt, 0, 3 * 256 * sizeof(int), stream);
    bhist_kernel<<<dim3(HB, 3), 256, 0, stream>>>(w_dst, c_dst, b_dst, bcnt);
    bscan_kernel<<<3, 256, 0, stream>>>(bcnt, bb, bcur);
    partition_kernel<<<dim3(PB, 3), 256, 0, stream>>>(w_src, c_src, b_src,
                                                      w_dst, c_dst, b_dst, bcur, pairs);
    bucket_csr_kernel<<<dim3(NBUCK, 3), 256, 0, stream>>>(bb, pairs, rp, ssrc);

    const int* rp_w = rp;
    const int* rp_c = rp + (NNODE + 1);
    const int* rp_b = rp + 2 * (NNODE + 1);
    const int* ss_w = ssrc;
    const int* ss_c = ssrc + NEDGE;
    const int* ss_b = ssrc + 2 * NEDGE;

    // ---- input projections ----
    proj_mfma<<<MB, 256, 0, stream>>>(xda, xca, wtPJA, winA_b, B0);
    proj_mfma<<<MB, 256, 0, stream>>>(xdp, xcp, wtPJP, winP_b, B1);

    // ---- layer 0 ----
    gather_mean_kernel<<<GB, 256, 0, stream>>>(B0, rp_w, ss_w, B2, NNODE);
    gather_mean_kernel<<<GB, 256, 0, stream>>>(B1, rp_c, ss_c, B3, NNODE);
    gather_mean_kernel<<<GB, 256, 0, stream>>>(B1, rp_b, ss_b, B4, NNODE);
    combine_mfma<3><<<MB, 256, 0, stream>>>(B2, B3, B1, wtP0, biasP, B2);
    combine_mfma<2><<<MB, 256, 0, stream>>>(B4, B0, nullptr, wtA, wb_bl, B4);

    // ---- layer 1 ---- (author update is dead code in the reference: skipped)
    gather_mean_kernel<<<GB, 256, 0, stream>>>(B4, rp_w, ss_w, B0, NNODE);
    gather_mean_kernel<<<GB, 256, 0, stream>>>(B2, rp_c, ss_c, B1, NNODE);
    combine_mfma<3><<<MB, 256, 0, stream>>>(B0, B1, B2, wtP1, biasP + 64, B0);

    // ---- final projection to OUT=16 ----
    final_mfma<<<MB, 256, 0, stream>>>(B0, wtLIN, lin_b, (float*)d_out);
}

// Round 7
// 493.423 us; speedup vs baseline: 14.8138x; 1.0640x over previous
//
#include <hip/hip_runtime.h>
#include <hip/hip_fp16.h>

#define NNODE 100000
#define NEDGE 1600000
#define NBUCK 196      // ceil(100000/512)
#define BSH 9          // 512 nodes per bucket
#define BBST 260       // bb row stride (>= NBUCK+1)
#define PCH 8192       // edges per partition block

typedef _Float16 f16x8 __attribute__((ext_vector_type(8)));
typedef float f32x4 __attribute__((ext_vector_type(4)));

// ============ CSR build (batched over 3 edge types via blockIdx.y) ============

__global__ __launch_bounds__(256) void bhist_kernel(const int* __restrict__ d0,
                                                    const int* __restrict__ d1,
                                                    const int* __restrict__ d2,
                                                    int* __restrict__ bcnt) {
    int y = blockIdx.y;
    const int* dst = (y == 0) ? d0 : (y == 1) ? d1 : d2;
    __shared__ int h[NBUCK];
    int t = threadIdx.x;
    for (int i = t; i < NBUCK; i += 256) h[i] = 0;
    __syncthreads();
    int base = blockIdx.x * 1024;
#pragma unroll 4
    for (int i = t; i < 1024; i += 256) {
        int e = base + i;
        if (e < NEDGE) atomicAdd(&h[dst[e] >> BSH], 1);
    }
    __syncthreads();
    for (int b = t; b < NBUCK; b += 256)
        if (h[b]) atomicAdd(&bcnt[y * 256 + b], h[b]);
}

__global__ __launch_bounds__(256) void bscan_kernel(const int* __restrict__ bcnt,
                                                    int* __restrict__ bb,
                                                    int* __restrict__ bcur) {
    int y = blockIdx.x;
    __shared__ int s[256];
    int t = threadIdx.x;
    int v = (t < NBUCK) ? bcnt[y * 256 + t] : 0;
    s[t] = v;
    __syncthreads();
    for (int off = 1; off < 256; off <<= 1) {
        int a = s[t];
        int b = (t >= off) ? s[t - off] : 0;
        __syncthreads();
        s[t] = a + b;
        __syncthreads();
    }
    int excl = s[t] - v;
    if (t <= NBUCK) bb[y * BBST + t] = (t == NBUCK) ? NEDGE : excl;
    if (t < NBUCK) bcur[y * 256 + t] = excl;
}

// Phase A: partition into dst-bucket streams via per-block LDS counting sort;
// global writes are linear-in-LDS-order -> coalesced run streams.
__global__ __launch_bounds__(256) void partition_kernel(
    const int* __restrict__ s0, const int* __restrict__ s1, const int* __restrict__ s2,
    const int* __restrict__ d0, const int* __restrict__ d1, const int* __restrict__ d2,
    int* __restrict__ bc, int* __restrict__ pairs) {
    int y = blockIdx.y;
    const int* src = (y == 0) ? s0 : (y == 1) ? s1 : s2;
    const int* dst = (y == 0) ? d0 : (y == 1) ? d1 : d2;
    int* bcur = bc + y * 256;
    int* pr = pairs + (size_t)y * NEDGE;

    __shared__ int sCur[NBUCK];          // counts -> running local cursor
    __shared__ int sDelta[NBUCK];        // globalBase - localOfs
    __shared__ int sScan[256];
    __shared__ int sSort[PCH];           // bucket-sorted packed pairs
    __shared__ unsigned char sBid[PCH];  // bucket id per slot
    int t = threadIdx.x;
    for (int i = t; i < NBUCK; i += 256) sCur[i] = 0;
    __syncthreads();
    int c0 = blockIdx.x * PCH;
    int cend = min(c0 + PCH, NEDGE);
    int nblk = cend - c0;
    // pass 1: count
    for (int e = c0 + t; e < cend; e += 256)
        atomicAdd(&sCur[dst[e] >> BSH], 1);
    __syncthreads();
    // scan 196 counts
    int v = (t < NBUCK) ? sCur[t] : 0;
    sScan[t] = v;
    __syncthreads();
    for (int off = 1; off < 256; off <<= 1) {
        int a = sScan[t];
        int b = (t >= off) ? sScan[t - off] : 0;
        __syncthreads();
        sScan[t] = a + b;
        __syncthreads();
    }
    if (t < NBUCK) {
        int excl = sScan[t] - v;
        int gb = v ? atomicAdd(&bcur[t], v) : 0;
        sCur[t] = excl;           // local cursor
        sDelta[t] = gb - excl;
    }
    __syncthreads();
    // pass 2: place into LDS sorted by bucket
    for (int e = c0 + t; e < cend; e += 256) {
        int d = dst[e];
        int b = d >> BSH;
        int slot = atomicAdd(&sCur[b], 1);
        sSort[slot] = ((d & 511) << 17) | src[e];
        sBid[slot] = (unsigned char)b;
    }
    __syncthreads();
    // flush: consecutive slots -> consecutive global within each run
    for (int i = t; i < nblk; i += 256)
        pr[sDelta[sBid[i]] + i] = sSort[i];
}

// Phase B: per-bucket CSR finalize — LDS histogram/scan -> rowptr + scatter.
__global__ __launch_bounds__(256) void bucket_csr_kernel(const int* __restrict__ bb,
                                                         const int* __restrict__ pairs,
                                                         int* __restrict__ rowptr,
                                                         int* __restrict__ ssrc) {
    int y = blockIdx.y;
    bb += y * BBST;
    pairs += (size_t)y * NEDGE;
    rowptr += (size_t)y * (NNODE + 1);
    ssrc += (size_t)y * NEDGE;

    __shared__ int cnt[512];
    __shared__ int cur[512];
    __shared__ int s1[256];
    int b = blockIdx.x;
    int t = threadIdx.x;
    int node0 = b << BSH;
    int start = bb[b], end = bb[b + 1];

    cnt[t] = 0;
    cnt[t + 256] = 0;
    __syncthreads();
    for (int e = start + t; e < end; e += 256)
        atomicAdd(&cnt[pairs[e] >> 17], 1);
    __syncthreads();
    int a0 = cnt[2 * t], a1 = cnt[2 * t + 1];
    s1[t] = a0 + a1;
    __syncthreads();
    for (int off = 1; off < 256; off <<= 1) {
        int a = s1[t];
        int c = (t >= off) ? s1[t - off] : 0;
        __syncthreads();
        s1[t] = a + c;
        __syncthreads();
    }
    int eb = start + s1[t] - (a0 + a1);
    cur[2 * t] = eb;
    cur[2 * t + 1] = eb + a0;
    int n0 = node0 + 2 * t;
    if (n0 < NNODE) rowptr[n0] = eb;
    if (n0 + 1 < NNODE) rowptr[n0 + 1] = eb + a0;
    if (b == NBUCK - 1 && t == 0) rowptr[NNODE] = NEDGE;
    __syncthreads();
    for (int e = start + t; e < end; e += 256) {
        int p = pairs[e];
        int pos = atomicAdd(&cur[p >> 17], 1);
        ssrc[pos] = p & 0x1FFFF;
    }
}

// ============ gather-mean: wave per dst node, quarter-wave per edge ============
// 16 lanes x 8B cover a 128B fp16 row; 4 edges/wave x unroll 4 = 16 rows in flight.
__global__ __launch_bounds__(256) void gather_mean_kernel(const __half* __restrict__ x,
                                                          const int* __restrict__ rowptr,
                                                          const int* __restrict__ ssrc,
                                                          __half* __restrict__ out, int n) {
    int wid = (blockIdx.x * 256 + threadIdx.x) >> 6;
    int lane = threadIdx.x & 63;
    if (wid >= n) return;
    int qq = lane >> 4;        // edge slot 0..3
    int fo = (lane & 15) << 2; // feature quad base
    int start = rowptr[wid], end = rowptr[wid + 1];
    float a0 = 0.f, a1 = 0.f, a2 = 0.f, a3 = 0.f;
    int e = start + qq;
    for (; e + 12 < end; e += 16) {
        int v0 = ssrc[e], v1 = ssrc[e + 4], v2 = ssrc[e + 8], v3 = ssrc[e + 12];
        uint2 r0 = *(const uint2*)(x + ((size_t)v0 << 6) + fo);
        uint2 r1 = *(const uint2*)(x + ((size_t)v1 << 6) + fo);
        uint2 r2 = *(const uint2*)(x + ((size_t)v2 << 6) + fo);
        uint2 r3 = *(const uint2*)(x + ((size_t)v3 << 6) + fo);
        float2 f;
        f = __half22float2(*(__half2*)&r0.x); a0 += f.x; a1 += f.y;
        f = __half22float2(*(__half2*)&r0.y); a2 += f.x; a3 += f.y;
        f = __half22float2(*(__half2*)&r1.x); a0 += f.x; a1 += f.y;
        f = __half22float2(*(__half2*)&r1.y); a2 += f.x; a3 += f.y;
        f = __half22float2(*(__half2*)&r2.x); a0 += f.x; a1 += f.y;
        f = __half22float2(*(__half2*)&r2.y); a2 += f.x; a3 += f.y;
        f = __half22float2(*(__half2*)&r3.x); a0 += f.x; a1 += f.y;
        f = __half22float2(*(__half2*)&r3.y); a2 += f.x; a3 += f.y;
    }
    for (; e < end; e += 4) {
        uint2 r = *(const uint2*)(x + ((size_t)ssrc[e] << 6) + fo);
        float2 f;
        f = __half22float2(*(__half2*)&r.x); a0 += f.x; a1 += f.y;
        f = __half22float2(*(__half2*)&r.y); a2 += f.x; a3 += f.y;
    }
    a0 += __shfl_xor(a0, 16); a0 += __shfl_xor(a0, 32);
    a1 += __shfl_xor(a1, 16); a1 += __shfl_xor(a1, 32);
    a2 += __shfl_xor(a2, 16); a2 += __shfl_xor(a2, 32);
    a3 += __shfl_xor(a3, 16); a3 += __shfl_xor(a3, 32);
    if (qq == 0) {
        float scale = 1.0f / fmaxf((float)(end - start), 1.0f);
        uint2 w;
        *(__half2*)&w.x = __floats2half2_rn(a0 * scale, a1 * scale);
        *(__half2*)&w.y = __floats2half2_rn(a2 * scale, a3 * scale);
        *(uint2*)(out + ((size_t)wid << 6) + fo) = w;
    }
}

// ============ weight prep: fp16 W^T (+ summed wr, summed biases) ============
__global__ __launch_bounds__(256) void wprep_kernel(
    const float* __restrict__ writes_wl, const float* __restrict__ cites_wl,
    const float* __restrict__ writes_wr, const float* __restrict__ cites_wr,
    const float* __restrict__ wb_wl, const float* __restrict__ wb_wr,
    const float* __restrict__ winA_w, const float* __restrict__ winP_w,
    const float* __restrict__ lin_w,
    const float* __restrict__ writes_bl, const float* __restrict__ cites_bl,
    __half* __restrict__ wtP0, __half* __restrict__ wtP1, __half* __restrict__ wtA,
    __half* __restrict__ wtPJA, __half* __restrict__ wtPJP, __half* __restrict__ wtLIN,
    float* __restrict__ biasP) {
    int i = blockIdx.x * 256 + threadIdx.x;
    if (i < 24576) {                       // paper combine W^T [64][192] x 2 layers
        int l = i / 12288, j = i % 12288;
        int n = j / 192, k = j % 192;
        float v;
        if (k < 64) v = writes_wl[l * 4096 + k * 64 + n];
        else if (k < 128) v = cites_wl[l * 4096 + (k - 64) * 64 + n];
        else v = writes_wr[l * 4096 + (k - 128) * 64 + n] +
                 cites_wr[l * 4096 + (k - 128) * 64 + n];
        (l ? wtP1 : wtP0)[n * 192 + k] = __float2half(v);
    } else if (i < 32768) {                // author combine W^T [64][128], layer 0
        int j = i - 24576;
        int n = j / 128, k = j % 128;
        float v = (k < 64) ? wb_wl[k * 64 + n] : wb_wr[(k - 64) * 64 + n];
        wtA[n * 128 + k] = __float2half(v);
    } else if (i < 36864) {                // proj author W^T [64][64]
        int j = i - 32768;
        wtPJA[j] = __float2half(winA_w[(j % 64) * 64 + j / 64]);
    } else if (i < 40960) {                // proj paper W^T [64][64]
        int j = i - 36864;
        wtPJP[j] = __float2half(winP_w[(j % 64) * 64 + j / 64]);
    } else if (i < 41984) {                // lin W^T [16][64]
        int j = i - 40960;
        wtLIN[j] = __float2half(lin_w[(j % 64) * 16 + j / 64]);
    } else if (i < 42112) {                // summed paper biases, 2 layers
        int j = i - 41984;
        biasP[j] = writes_bl[j] + cites_bl[j];
    }
}

// ============ MFMA node-GEMMs: wave = 16 nodes, no LDS ============
__device__ inline f16x8 cvt8(const float* p) {
    float4 a = *(const float4*)p, b = *(const float4*)(p + 4);
    f16x8 r;
    r[0] = (_Float16)a.x; r[1] = (_Float16)a.y; r[2] = (_Float16)a.z; r[3] = (_Float16)a.w;
    r[4] = (_Float16)b.x; r[5] = (_Float16)b.y; r[6] = (_Float16)b.z; r[7] = (_Float16)b.w;
    return r;
}

__global__ __launch_bounds__(256) void proj_mfma(const float* __restrict__ xd,
                                                 const float* __restrict__ xc,
                                                 const __half* __restrict__ wt,
                                                 const float* __restrict__ bias,
                                                 __half* __restrict__ out) {
    int wid = (blockIdx.x * 256 + threadIdx.x) >> 6;
    if (wid >= NNODE / 16) return;
    int lane = threadIdx.x & 63;
    int row = lane & 15, kq = lane >> 4;
    int node0 = wid << 4;
    f16x8 af0 = cvt8(xd + (size_t)(node0 + row) * 32 + kq * 8);
    f16x8 af1 = cvt8(xc + (size_t)(node0 + row) * 32 + kq * 8);
#pragma unroll
    for (int nt = 0; nt < 4; ++nt) {
        int col = nt * 16 + row;
        const __half* wp = wt + (size_t)col * 64 + kq * 8;
        f32x4 acc = {0.f, 0.f, 0.f, 0.f};
        acc = __builtin_amdgcn_mfma_f32_16x16x32_f16(af0, *(const f16x8*)(wp), acc, 0, 0, 0);
        acc = __builtin_amdgcn_mfma_f32_16x16x32_f16(af1, *(const f16x8*)(wp + 32), acc, 0, 0, 0);
        float b = bias[col];
#pragma unroll
        for (int r = 0; r < 4; ++r)
            out[((size_t)(node0 + kq * 4 + r) << 6) + col] = __float2half(fmaxf(acc[r] + b, 0.f));
    }
}

template <int NSEG>
__global__ __launch_bounds__(256) void combine_mfma(const __half* __restrict__ a0,
                                                    const __half* __restrict__ a1,
                                                    const __half* __restrict__ a2,
                                                    const __half* __restrict__ wt,
                                                    const float* __restrict__ bias,
                                                    __half* __restrict__ out) {
    int wid = (blockIdx.x * 256 + threadIdx.x) >> 6;
    if (wid >= NNODE / 16) return;
    int lane = threadIdx.x & 63;
    int row = lane & 15, kq = lane >> 4;
    int node0 = wid << 4;
    const int K = NSEG * 64;
    const __half* as[3] = {a0, a1, a2};
    f16x8 af[2 * NSEG];
#pragma unroll
    for (int s = 0; s < NSEG; ++s) {
        const __half* p = as[s] + ((size_t)(node0 + row) << 6) + kq * 8;
        af[2 * s] = *(const f16x8*)(p);
        af[2 * s + 1] = *(const f16x8*)(p + 32);
    }
#pragma unroll
    for (int nt = 0; nt < 4; ++nt) {
        int col = nt * 16 + row;
        const __half* wp = wt + (size_t)col * K + kq * 8;
        f32x4 acc = {0.f, 0.f, 0.f, 0.f};
#pragma unroll
        for (int t = 0; t < 2 * NSEG; ++t)
            acc = __builtin_amdgcn_mfma_f32_16x16x32_f16(af[t], *(const f16x8*)(wp + t * 32), acc, 0, 0, 0);
        float b = bias[col];
#pragma unroll
        for (int r = 0; r < 4; ++r)
            out[((size_t)(node0 + kq * 4 + r) << 6) + col] = __float2half(acc[r] + b);
    }
}

__global__ __launch_bounds__(256) void final_mfma(const __half* __restrict__ y,
                                                  const __half* __restrict__ wt,
                                                  const float* __restrict__ bias,
                                                  float* __restrict__ out) {
    int wid = (blockIdx.x * 256 + threadIdx.x) >> 6;
    if (wid >= NNODE / 16) return;
    int lane = threadIdx.x & 63;
    int row = lane & 15, kq = lane >> 4;
    int node0 = wid << 4;
    const __half* p = y + ((size_t)(node0 + row) << 6) + kq * 8;
    f16x8 af0 = *(const f16x8*)(p);
    f16x8 af1 = *(const f16x8*)(p + 32);
    const __half* wp = wt + (size_t)row * 64 + kq * 8;
    f32x4 acc = {0.f, 0.f, 0.f, 0.f};
    acc = __builtin_amdgcn_mfma_f32_16x16x32_f16(af0, *(const f16x8*)(wp), acc, 0, 0, 0);
    acc = __builtin_amdgcn_mfma_f32_16x16x32_f16(af1, *(const f16x8*)(wp + 32), acc, 0, 0, 0);
    float b = bias[row];
#pragma unroll
    for (int r = 0; r < 4; ++r)
        out[(size_t)(node0 + kq * 4 + r) * 16 + row] = acc[r] + b;
}

extern "C" void kernel_launch(void* const* d_in, const int* in_sizes, int n_in,
                              void* d_out, int out_size, void* d_ws, size_t ws_size,
                              hipStream_t stream) {
    (void)in_sizes; (void)n_in; (void)out_size; (void)ws_size;
    const float* xda = (const float*)d_in[0];
    const float* xca = (const float*)d_in[1];
    const float* xdp = (const float*)d_in[2];
    const float* xcp = (const float*)d_in[3];
    const float* winA_w = (const float*)d_in[4];
    const float* winA_b = (const float*)d_in[5];
    const float* winP_w = (const float*)d_in[6];
    const float* winP_b = (const float*)d_in[7];
    const float* writes_wl = (const float*)d_in[8];
    const float* writes_bl = (const float*)d_in[9];
    const float* writes_wr = (const float*)d_in[10];
    const float* wb_wl = (const float*)d_in[11];
    const float* wb_bl = (const float*)d_in[12];
    const float* wb_wr = (const float*)d_in[13];
    const float* cites_wl = (const float*)d_in[14];
    const float* cites_bl = (const float*)d_in[15];
    const float* cites_wr = (const float*)d_in[16];
    const float* lin_w = (const float*)d_in[17];
    const float* lin_b = (const float*)d_in[18];
    const int* w_src = (const int*)d_in[19];
    const int* w_dst = (const int*)d_in[20];
    const int* b_src = (const int*)d_in[21];
    const int* b_dst = (const int*)d_in[22];
    const int* c_src = (const int*)d_in[23];
    const int* c_dst = (const int*)d_in[24];

    const size_t NF = (size_t)NNODE * 64;
    __half* B0 = (__half*)d_ws;      // y_a0 -> L1 mean_writes -> y_p2
    __half* B1 = B0 + NF;            // y_p0 -> L1 mean_cites
    __half* B2 = B1 + NF;            // L0 mean_writes -> y_p1
    __half* B3 = B2 + NF;            // L0 mean_cites
    __half* B4 = B3 + NF;            // L0 mean_wb -> y_a1

    __half* wtP0 = B4 + NF;          // 12288
    __half* wtP1 = wtP0 + 12288;     // 12288
    __half* wtA = wtP1 + 12288;      // 8192
    __half* wtPJA = wtA + 8192;      // 4096
    __half* wtPJP = wtPJA + 4096;    // 4096
    __half* wtLIN = wtPJP + 4096;    // 1024
    float* biasP = (float*)(wtLIN + 1024);  // 128

    int* ip = (int*)(biasP + 128);
    int* rp = ip;                        // 3 * (NNODE+1)
    int* bcnt = rp + 3 * (NNODE + 1);    // 3 * 256
    int* bb = bcnt + 3 * 256;            // 3 * BBST
    int* bcur = bb + 3 * BBST;           // 3 * 256
    int* ssrc = bcur + 3 * 256;          // 3 * NEDGE
    int* pairs = (int*)B2;               // CSR-build-only alias

    const int GB = (NNODE * 64) / 256;      // 25000 (wave per node)
    const int MB = (NNODE / 16 + 3) / 4;    // 1563 (wave per 16 nodes)
    const int HB = (NEDGE + 1023) / 1024;   // 1563
    const int PB = (NEDGE + PCH - 1) / PCH; // 196

    // ---- weight prep + CSR build ----
    wprep_kernel<<<165, 256, 0, stream>>>(writes_wl, cites_wl, writes_wr, cites_wr,
                                          wb_wl, wb_wr, winA_w, winP_w, lin_w,
                                          writes_bl, cites_bl,
                                          wtP0, wtP1, wtA, wtPJA, wtPJP, wtLIN, biasP);
    hipMemsetAsync(bcnt, 0, 3 * 256 * sizeof(int), stream);
    bhist_kernel<<<dim3(HB, 3), 256, 0, stream>>>(w_dst, c_dst, b_dst, bcnt);
    bscan_kernel<<<3, 256, 0, stream>>>(bcnt, bb, bcur);
    partition_kernel<<<dim3(PB, 3), 256, 0, stream>>>(w_src, c_src, b_src,
                                                      w_dst, c_dst, b_dst, bcur, pairs);
    bucket_csr_kernel<<<dim3(NBUCK, 3), 256, 0, stream>>>(bb, pairs, rp, ssrc);

    const int* rp_w = rp;
    const int* rp_c = rp + (NNODE + 1);
    const int* rp_b = rp + 2 * (NNODE + 1);
    const int* ss_w = ssrc;
    const int* ss_c = ssrc + NEDGE;
    const int* ss_b = ssrc + 2 * NEDGE;

    // ---- input projections ----
    proj_mfma<<<MB, 256, 0, stream>>>(xda, xca, wtPJA, winA_b, B0);
    proj_mfma<<<MB, 256, 0, stream>>>(xdp, xcp, wtPJP, winP_b, B1);

    // ---- layer 0 ----
    gather_mean_kernel<<<GB, 256, 0, stream>>>(B0, rp_w, ss_w, B2, NNODE);
    gather_mean_kernel<<<GB, 256, 0, stream>>>(B1, rp_c, ss_c, B3, NNODE);
    gather_mean_kernel<<<GB, 256, 0, stream>>>(B1, rp_b, ss_b, B4, NNODE);
    combine_mfma<3><<<MB, 256, 0, stream>>>(B2, B3, B1, wtP0, biasP, B2);
    combine_mfma<2><<<MB, 256, 0, stream>>>(B4, B0, nullptr, wtA, wb_bl, B4);

    // ---- layer 1 ---- (author update is dead code in the reference: skipped)
    gather_mean_kernel<<<GB, 256, 0, stream>>>(B4, rp_w, ss_w, B0, NNODE);
    gather_mean_kernel<<<GB, 256, 0, stream>>>(B2, rp_c, ss_c, B1, NNODE);
    combine_mfma<3><<<MB, 256, 0, stream>>>(B0, B1, B2, wtP1, biasP + 64, B0);

    // ---- final projection to OUT=16 ----
    final_mfma<<<MB, 256, 0, stream>>>(B0, wtLIN, lin_b, (float*)d_out);
}

// Round 8
// 416.780 us; speedup vs baseline: 17.5379x; 1.1839x over previous
//
#include <hip/hip_runtime.h>
#include <hip/hip_fp16.h>

#define NNODE 100000
#define NEDGE 1600000
#define NBUCK 196      // ceil(100000/512)
#define BSH 9          // 512 nodes per bucket
#define PCH 8192       // edges per partition block
#define CAP 9216       // fixed bucket capacity (mean 8163 + 11.6 sigma)

typedef _Float16 f16x8 __attribute__((ext_vector_type(8)));
typedef float f32x4 __attribute__((ext_vector_type(4)));

// ============ CSR build (batched over 3 edge types via blockIdx.y) ============

// cursor init: bucket b's region starts at b*CAP
__global__ __launch_bounds__(256) void initcur_kernel(int* __restrict__ bcur) {
    int y = blockIdx.x;
    int b = threadIdx.x;
    if (b < NBUCK) bcur[y * 256 + b] = b * CAP;
}

// Phase A: partition into fixed-capacity dst-bucket streams via per-block LDS
// counting sort; global writes are linear-in-LDS-order -> coalesced run streams.
__global__ __launch_bounds__(256) void partition_kernel(
    const int* __restrict__ s0, const int* __restrict__ s1, const int* __restrict__ s2,
    const int* __restrict__ d0, const int* __restrict__ d1, const int* __restrict__ d2,
    int* __restrict__ bc, int* __restrict__ pairs) {
    int y = blockIdx.y;
    const int* src = (y == 0) ? s0 : (y == 1) ? s1 : s2;
    const int* dst = (y == 0) ? d0 : (y == 1) ? d1 : d2;
    int* bcur = bc + y * 256;
    int* pr = pairs + (size_t)y * (NBUCK * CAP);

    __shared__ int sCur[NBUCK];          // counts -> running local cursor
    __shared__ int sDelta[NBUCK];        // globalBase - localOfs
    __shared__ int sScan[256];
    __shared__ int sSort[PCH];           // bucket-sorted packed pairs
    __shared__ unsigned char sBid[PCH];  // bucket id per slot
    int t = threadIdx.x;
    for (int i = t; i < NBUCK; i += 256) sCur[i] = 0;
    __syncthreads();
    int c0 = blockIdx.x * PCH;
    int cend = min(c0 + PCH, NEDGE);
    int nblk = cend - c0;
    // pass 1: count
    for (int e = c0 + t; e < cend; e += 256)
        atomicAdd(&sCur[dst[e] >> BSH], 1);
    __syncthreads();
    // scan 196 counts
    int v = (t < NBUCK) ? sCur[t] : 0;
    sScan[t] = v;
    __syncthreads();
    for (int off = 1; off < 256; off <<= 1) {
        int a = sScan[t];
        int b = (t >= off) ? sScan[t - off] : 0;
        __syncthreads();
        sScan[t] = a + b;
        __syncthreads();
    }
    if (t < NBUCK) {
        int excl = sScan[t] - v;
        int gb = v ? atomicAdd(&bcur[t], v) : 0;
        sCur[t] = excl;           // local cursor
        sDelta[t] = gb - excl;
    }
    __syncthreads();
    // pass 2: place into LDS sorted by bucket
    for (int e = c0 + t; e < cend; e += 256) {
        int d = dst[e];
        int b = d >> BSH;
        int slot = atomicAdd(&sCur[b], 1);
        sSort[slot] = ((d & 511) << 17) | src[e];
        sBid[slot] = (unsigned char)b;
    }
    __syncthreads();
    // flush: consecutive slots -> consecutive global within each run
    for (int i = t; i < nblk; i += 256)
        pr[sDelta[sBid[i]] + i] = sSort[i];
}

// Phase B: per-bucket CSR finalize — LDS histogram/scan -> int2 rowptr{start,end}
// + LDS-cursor scatter of src ids into the padded bucket region.
__global__ __launch_bounds__(256) void bucket_csr_kernel(const int* __restrict__ bc,
                                                         const int* __restrict__ pairs,
                                                         int2* __restrict__ rowptr2,
                                                         int* __restrict__ ssrc) {
    int y = blockIdx.y;
    pairs += (size_t)y * (NBUCK * CAP);
    rowptr2 += (size_t)y * NNODE;
    ssrc += (size_t)y * (NBUCK * CAP);

    __shared__ int cnt[512];
    __shared__ int cur[512];
    __shared__ int s1[256];
    int b = blockIdx.x;
    int t = threadIdx.x;
    int node0 = b << BSH;
    int start = b * CAP;
    int end = bc[y * 256 + b];   // final cursor = start + bucket count

    cnt[t] = 0;
    cnt[t + 256] = 0;
    __syncthreads();
    for (int e = start + t; e < end; e += 256)
        atomicAdd(&cnt[pairs[e] >> 17], 1);
    __syncthreads();
    int a0 = cnt[2 * t], a1 = cnt[2 * t + 1];
    s1[t] = a0 + a1;
    __syncthreads();
    for (int off = 1; off < 256; off <<= 1) {
        int a = s1[t];
        int c = (t >= off) ? s1[t - off] : 0;
        __syncthreads();
        s1[t] = a + c;
        __syncthreads();
    }
    int eb = start + s1[t] - (a0 + a1);
    cur[2 * t] = eb;
    cur[2 * t + 1] = eb + a0;
    int n0 = node0 + 2 * t;
    if (n0 + 1 < NNODE) {
        int4 rr = make_int4(eb, eb + a0, eb + a0, eb + a0 + a1);
        *(int4*)(rowptr2 + n0) = rr;
    } else if (n0 < NNODE) {
        rowptr2[n0] = make_int2(eb, eb + a0);
    }
    __syncthreads();
    for (int e = start + t; e < end; e += 256) {
        int p = pairs[e];
        int pos = atomicAdd(&cur[p >> 17], 1);
        ssrc[pos] = p & 0x1FFFF;
    }
}

// ============ gather-mean: wave per dst node, quarter-wave per edge ============
// 16 lanes x 8B cover a 128B fp16 row; 4 edges/wave x unroll 4 = 16 rows in flight.
__global__ __launch_bounds__(256) void gather_mean_kernel(const __half* __restrict__ x,
                                                          const int2* __restrict__ rowptr2,
                                                          const int* __restrict__ ssrc,
                                                          __half* __restrict__ out, int n) {
    int wid = (blockIdx.x * 256 + threadIdx.x) >> 6;
    int lane = threadIdx.x & 63;
    if (wid >= n) return;
    int qq = lane >> 4;        // edge slot 0..3
    int fo = (lane & 15) << 2; // feature quad base
    int2 se = rowptr2[wid];
    int start = se.x, end = se.y;
    float a0 = 0.f, a1 = 0.f, a2 = 0.f, a3 = 0.f;
    int e = start + qq;
    for (; e + 12 < end; e += 16) {
        int v0 = ssrc[e], v1 = ssrc[e + 4], v2 = ssrc[e + 8], v3 = ssrc[e + 12];
        uint2 r0 = *(const uint2*)(x + ((size_t)v0 << 6) + fo);
        uint2 r1 = *(const uint2*)(x + ((size_t)v1 << 6) + fo);
        uint2 r2 = *(const uint2*)(x + ((size_t)v2 << 6) + fo);
        uint2 r3 = *(const uint2*)(x + ((size_t)v3 << 6) + fo);
        float2 f;
        f = __half22float2(*(__half2*)&r0.x); a0 += f.x; a1 += f.y;
        f = __half22float2(*(__half2*)&r0.y); a2 += f.x; a3 += f.y;
        f = __half22float2(*(__half2*)&r1.x); a0 += f.x; a1 += f.y;
        f = __half22float2(*(__half2*)&r1.y); a2 += f.x; a3 += f.y;
        f = __half22float2(*(__half2*)&r2.x); a0 += f.x; a1 += f.y;
        f = __half22float2(*(__half2*)&r2.y); a2 += f.x; a3 += f.y;
        f = __half22float2(*(__half2*)&r3.x); a0 += f.x; a1 += f.y;
        f = __half22float2(*(__half2*)&r3.y); a2 += f.x; a3 += f.y;
    }
    for (; e < end; e += 4) {
        uint2 r = *(const uint2*)(x + ((size_t)ssrc[e] << 6) + fo);
        float2 f;
        f = __half22float2(*(__half2*)&r.x); a0 += f.x; a1 += f.y;
        f = __half22float2(*(__half2*)&r.y); a2 += f.x; a3 += f.y;
    }
    a0 += __shfl_xor(a0, 16); a0 += __shfl_xor(a0, 32);
    a1 += __shfl_xor(a1, 16); a1 += __shfl_xor(a1, 32);
    a2 += __shfl_xor(a2, 16); a2 += __shfl_xor(a2, 32);
    a3 += __shfl_xor(a3, 16); a3 += __shfl_xor(a3, 32);
    if (qq == 0) {
        float scale = 1.0f / fmaxf((float)(end - start), 1.0f);
        uint2 w;
        *(__half2*)&w.x = __floats2half2_rn(a0 * scale, a1 * scale);
        *(__half2*)&w.y = __floats2half2_rn(a2 * scale, a3 * scale);
        *(uint2*)(out + ((size_t)wid << 6) + fo) = w;
    }
}

// ============ weight prep: fp16 W^T (+ summed wr, summed biases) ============
__global__ __launch_bounds__(256) void wprep_kernel(
    const float* __restrict__ writes_wl, const float* __restrict__ cites_wl,
    const float* __restrict__ writes_wr, const float* __restrict__ cites_wr,
    const float* __restrict__ wb_wl, const float* __restrict__ wb_wr,
    const float* __restrict__ winA_w, const float* __restrict__ winP_w,
    const float* __restrict__ lin_w,
    const float* __restrict__ writes_bl, const float* __restrict__ cites_bl,
    __half* __restrict__ wtP0, __half* __restrict__ wtP1, __half* __restrict__ wtA,
    __half* __restrict__ wtPJA, __half* __restrict__ wtPJP, __half* __restrict__ wtLIN,
    float* __restrict__ biasP) {
    int i = blockIdx.x * 256 + threadIdx.x;
    if (i < 24576) {                       // paper combine W^T [64][192] x 2 layers
        int l = i / 12288, j = i % 12288;
        int n = j / 192, k = j % 192;
        float v;
        if (k < 64) v = writes_wl[l * 4096 + k * 64 + n];
        else if (k < 128) v = cites_wl[l * 4096 + (k - 64) * 64 + n];
        else v = writes_wr[l * 4096 + (k - 128) * 64 + n] +
                 cites_wr[l * 4096 + (k - 128) * 64 + n];
        (l ? wtP1 : wtP0)[n * 192 + k] = __float2half(v);
    } else if (i < 32768) {                // author combine W^T [64][128], layer 0
        int j = i - 24576;
        int n = j / 128, k = j % 128;
        float v = (k < 64) ? wb_wl[k * 64 + n] : wb_wr[(k - 64) * 64 + n];
        wtA[n * 128 + k] = __float2half(v);
    } else if (i < 36864) {                // proj author W^T [64][64]
        int j = i - 32768;
        wtPJA[j] = __float2half(winA_w[(j % 64) * 64 + j / 64]);
    } else if (i < 40960) {                // proj paper W^T [64][64]
        int j = i - 36864;
        wtPJP[j] = __float2half(winP_w[(j % 64) * 64 + j / 64]);
    } else if (i < 41984) {                // lin W^T [16][64]
        int j = i - 40960;
        wtLIN[j] = __float2half(lin_w[(j % 64) * 16 + j / 64]);
    } else if (i < 42112) {                // summed paper biases, 2 layers
        int j = i - 41984;
        biasP[j] = writes_bl[j] + cites_bl[j];
    }
}

// ============ MFMA node-GEMMs: wave = 16 nodes, no LDS ============
__device__ inline f16x8 cvt8(const float* p) {
    float4 a = *(const float4*)p, b = *(const float4*)(p + 4);
    f16x8 r;
    r[0] = (_Float16)a.x; r[1] = (_Float16)a.y; r[2] = (_Float16)a.z; r[3] = (_Float16)a.w;
    r[4] = (_Float16)b.x; r[5] = (_Float16)b.y; r[6] = (_Float16)b.z; r[7] = (_Float16)b.w;
    return r;
}

__global__ __launch_bounds__(256) void proj_mfma(const float* __restrict__ xd,
                                                 const float* __restrict__ xc,
                                                 const __half* __restrict__ wt,
                                                 const float* __restrict__ bias,
                                                 __half* __restrict__ out) {
    int wid = (blockIdx.x * 256 + threadIdx.x) >> 6;
    if (wid >= NNODE / 16) return;
    int lane = threadIdx.x & 63;
    int row = lane & 15, kq = lane >> 4;
    int node0 = wid << 4;
    f16x8 af0 = cvt8(xd + (size_t)(node0 + row) * 32 + kq * 8);
    f16x8 af1 = cvt8(xc + (size_t)(node0 + row) * 32 + kq * 8);
#pragma unroll
    for (int nt = 0; nt < 4; ++nt) {
        int col = nt * 16 + row;
        const __half* wp = wt + (size_t)col * 64 + kq * 8;
        f32x4 acc = {0.f, 0.f, 0.f, 0.f};
        acc = __builtin_amdgcn_mfma_f32_16x16x32_f16(af0, *(const f16x8*)(wp), acc, 0, 0, 0);
        acc = __builtin_amdgcn_mfma_f32_16x16x32_f16(af1, *(const f16x8*)(wp + 32), acc, 0, 0, 0);
        float b = bias[col];
#pragma unroll
        for (int r = 0; r < 4; ++r)
            out[((size_t)(node0 + kq * 4 + r) << 6) + col] = __float2half(fmaxf(acc[r] + b, 0.f));
    }
}

template <int NSEG>
__global__ __launch_bounds__(256) void combine_mfma(const __half* __restrict__ a0,
                                                    const __half* __restrict__ a1,
                                                    const __half* __restrict__ a2,
                                                    const __half* __restrict__ wt,
                                                    const float* __restrict__ bias,
                                                    __half* __restrict__ out) {
    int wid = (blockIdx.x * 256 + threadIdx.x) >> 6;
    if (wid >= NNODE / 16) return;
    int lane = threadIdx.x & 63;
    int row = lane & 15, kq = lane >> 4;
    int node0 = wid << 4;
    const int K = NSEG * 64;
    const __half* as[3] = {a0, a1, a2};
    f16x8 af[2 * NSEG];
#pragma unroll
    for (int s = 0; s < NSEG; ++s) {
        const __half* p = as[s] + ((size_t)(node0 + row) << 6) + kq * 8;
        af[2 * s] = *(const f16x8*)(p);
        af[2 * s + 1] = *(const f16x8*)(p + 32);
    }
#pragma unroll
    for (int nt = 0; nt < 4; ++nt) {
        int col = nt * 16 + row;
        const __half* wp = wt + (size_t)col * K + kq * 8;
        f32x4 acc = {0.f, 0.f, 0.f, 0.f};
#pragma unroll
        for (int t = 0; t < 2 * NSEG; ++t)
            acc = __builtin_amdgcn_mfma_f32_16x16x32_f16(af[t], *(const f16x8*)(wp + t * 32), acc, 0, 0, 0);
        float b = bias[col];
#pragma unroll
        for (int r = 0; r < 4; ++r)
            out[((size_t)(node0 + kq * 4 + r) << 6) + col] = __float2half(acc[r] + b);
    }
}

__global__ __launch_bounds__(256) void final_mfma(const __half* __restrict__ y,
                                                  const __half* __restrict__ wt,
                                                  const float* __restrict__ bias,
                                                  float* __restrict__ out) {
    int wid = (blockIdx.x * 256 + threadIdx.x) >> 6;
    if (wid >= NNODE / 16) return;
    int lane = threadIdx.x & 63;
    int row = lane & 15, kq = lane >> 4;
    int node0 = wid << 4;
    const __half* p = y + ((size_t)(node0 + row) << 6) + kq * 8;
    f16x8 af0 = *(const f16x8*)(p);
    f16x8 af1 = *(const f16x8*)(p + 32);
    const __half* wp = wt + (size_t)row * 64 + kq * 8;
    f32x4 acc = {0.f, 0.f, 0.f, 0.f};
    acc = __builtin_amdgcn_mfma_f32_16x16x32_f16(af0, *(const f16x8*)(wp), acc, 0, 0, 0);
    acc = __builtin_amdgcn_mfma_f32_16x16x32_f16(af1, *(const f16x8*)(wp + 32), acc, 0, 0, 0);
    float b = bias[row];
#pragma unroll
    for (int r = 0; r < 4; ++r)
        out[(size_t)(node0 + kq * 4 + r) * 16 + row] = acc[r] + b;
}

extern "C" void kernel_launch(void* const* d_in, const int* in_sizes, int n_in,
                              void* d_out, int out_size, void* d_ws, size_t ws_size,
                              hipStream_t stream) {
    (void)in_sizes; (void)n_in; (void)out_size; (void)ws_size;
    const float* xda = (const float*)d_in[0];
    const float* xca = (const float*)d_in[1];
    const float* xdp = (const float*)d_in[2];
    const float* xcp = (const float*)d_in[3];
    const float* winA_w = (const float*)d_in[4];
    const float* winA_b = (const float*)d_in[5];
    const float* winP_w = (const float*)d_in[6];
    const float* winP_b = (const float*)d_in[7];
    const float* writes_wl = (const float*)d_in[8];
    const float* writes_bl = (const float*)d_in[9];
    const float* writes_wr = (const float*)d_in[10];
    const float* wb_wl = (const float*)d_in[11];
    const float* wb_bl = (const float*)d_in[12];
    const float* wb_wr = (const float*)d_in[13];
    const float* cites_wl = (const float*)d_in[14];
    const float* cites_bl = (const float*)d_in[15];
    const float* cites_wr = (const float*)d_in[16];
    const float* lin_w = (const float*)d_in[17];
    const float* lin_b = (const float*)d_in[18];
    const int* w_src = (const int*)d_in[19];
    const int* w_dst = (const int*)d_in[20];
    const int* b_src = (const int*)d_in[21];
    const int* b_dst = (const int*)d_in[22];
    const int* c_src = (const int*)d_in[23];
    const int* c_dst = (const int*)d_in[24];

    const size_t NF = (size_t)NNODE * 64;
    const size_t BUK = (size_t)NBUCK * CAP;   // padded slots per edge type
    __half* B0 = (__half*)d_ws;      // y_a0 -> L1 mean_writes -> y_p2
    __half* B1 = B0 + NF;            // y_p0 -> L1 mean_cites
    __half* B2 = B1 + NF;            // L0 mean_writes -> y_p1
    __half* B3 = B2 + NF;            // L0 mean_cites
    __half* B4 = B3 + NF;            // L0 mean_wb -> y_a1

    __half* wtP0 = B4 + NF;          // 12288
    __half* wtP1 = wtP0 + 12288;     // 12288
    __half* wtA = wtP1 + 12288;      // 8192
    __half* wtPJA = wtA + 8192;      // 4096
    __half* wtPJP = wtPJA + 4096;    // 4096
    __half* wtLIN = wtPJP + 4096;    // 1024
    float* biasP = (float*)(wtLIN + 1024);  // 128

    int* ip = (int*)(biasP + 128);
    int2* rp2 = (int2*)ip;               // 3 * NNODE int2
    int* bcur = (int*)(rp2 + 3 * NNODE); // 3 * 256
    int* ssrc = bcur + 3 * 256;          // 3 * BUK
    int* pairs = (int*)B2;               // CSR-build-only alias (3*BUK ints = 21.7MB < 38.4MB)

    const int GB = (NNODE * 64) / 256;      // 25000 (wave per node)
    const int MB = (NNODE / 16 + 3) / 4;    // 1563 (wave per 16 nodes)
    const int PB = (NEDGE + PCH - 1) / PCH; // 196

    // ---- weight prep + CSR build (no histogram pass; fixed-capacity buckets) ----
    wprep_kernel<<<165, 256, 0, stream>>>(writes_wl, cites_wl, writes_wr, cites_wr,
                                          wb_wl, wb_wr, winA_w, winP_w, lin_w,
                                          writes_bl, cites_bl,
                                          wtP0, wtP1, wtA, wtPJA, wtPJP, wtLIN, biasP);
    initcur_kernel<<<3, 256, 0, stream>>>(bcur);
    partition_kernel<<<dim3(PB, 3), 256, 0, stream>>>(w_src, c_src, b_src,
                                                      w_dst, c_dst, b_dst, bcur, pairs);
    bucket_csr_kernel<<<dim3(NBUCK, 3), 256, 0, stream>>>(bcur, pairs, rp2, ssrc);

    const int2* rp_w = rp2;
    const int2* rp_c = rp2 + NNODE;
    const int2* rp_b = rp2 + 2 * NNODE;
    const int* ss_w = ssrc;
    const int* ss_c = ssrc + BUK;
    const int* ss_b = ssrc + 2 * BUK;

    // ---- input projections ----
    proj_mfma<<<MB, 256, 0, stream>>>(xda, xca, wtPJA, winA_b, B0);
    proj_mfma<<<MB, 256, 0, stream>>>(xdp, xcp, wtPJP, winP_b, B1);

    // ---- layer 0 ----
    gather_mean_kernel<<<GB, 256, 0, stream>>>(B0, rp_w, ss_w, B2, NNODE);
    gather_mean_kernel<<<GB, 256, 0, stream>>>(B1, rp_c, ss_c, B3, NNODE);
    gather_mean_kernel<<<GB, 256, 0, stream>>>(B1, rp_b, ss_b, B4, NNODE);
    combine_mfma<3><<<MB, 256, 0, stream>>>(B2, B3, B1, wtP0, biasP, B2);
    combine_mfma<2><<<MB, 256, 0, stream>>>(B4, B0, nullptr, wtA, wb_bl, B4);

    // ---- layer 1 ---- (author update is dead code in the reference: skipped)
    gather_mean_kernel<<<GB, 256, 0, stream>>>(B4, rp_w, ss_w, B0, NNODE);
    gather_mean_kernel<<<GB, 256, 0, stream>>>(B2, rp_c, ss_c, B1, NNODE);
    combine_mfma<3><<<MB, 256, 0, stream>>>(B0, B1, B2, wtP1, biasP + 64, B0);

    // ---- final projection to OUT=16 ----
    final_mfma<<<MB, 256, 0, stream>>>(B0, wtLIN, lin_b, (float*)d_out);
}

// Round 9
// 383.956 us; speedup vs baseline: 19.0372x; 1.0855x over previous
//
#include <hip/hip_runtime.h>
#include <hip/hip_fp16.h>

#define NNODE 100000
#define NEDGE 1600000
#define NBUCK 196      // ceil(100000/512)
#define BSH 9          // 512 nodes per bucket
#define PCH 8192       // edges per partition block
#define CAP 9216       // fixed bucket capacity (mean 8163 + 11.6 sigma)

typedef _Float16 f16x8 __attribute__((ext_vector_type(8)));
typedef float f32x4 __attribute__((ext_vector_type(4)));

// ============ CSR build (batched over 3 edge types via blockIdx.y) ============

// cursor init: bucket b's region starts at b*CAP
__global__ __launch_bounds__(256) void initcur_kernel(int* __restrict__ bcur) {
    int y = blockIdx.x;
    int b = threadIdx.x;
    if (b < NBUCK) bcur[y * 256 + b] = b * CAP;
}

// Phase A: partition into fixed-capacity dst-bucket streams via per-block LDS
// counting sort; per-bucket runs flushed wave-cooperatively (coalesced).
__global__ __launch_bounds__(256) void partition_kernel(
    const int* __restrict__ s0, const int* __restrict__ s1, const int* __restrict__ s2,
    const int* __restrict__ d0, const int* __restrict__ d1, const int* __restrict__ d2,
    int* __restrict__ bc, int* __restrict__ pairs) {
    int y = blockIdx.y;
    const int* src = (y == 0) ? s0 : (y == 1) ? s1 : s2;
    const int* dst = (y == 0) ? d0 : (y == 1) ? d1 : d2;
    int* bcur = bc + y * 256;
    int* pr = pairs + (size_t)y * (NBUCK * CAP);

    __shared__ int sCur[NBUCK];    // counts -> cursor -> local run end
    __shared__ int sStart[NBUCK];  // local run start
    __shared__ int sGB[NBUCK];     // global base
    __shared__ int sScan[256];
    __shared__ int sSort[PCH];     // bucket-sorted packed pairs (32 KB)
    int t = threadIdx.x;
    for (int i = t; i < NBUCK; i += 256) sCur[i] = 0;
    __syncthreads();
    int c0 = blockIdx.x * PCH;
    int cend = min(c0 + PCH, NEDGE);
    // pass 1: count
    for (int e = c0 + t; e < cend; e += 256)
        atomicAdd(&sCur[dst[e] >> BSH], 1);
    __syncthreads();
    // scan 196 counts
    int v = (t < NBUCK) ? sCur[t] : 0;
    sScan[t] = v;
    __syncthreads();
    for (int off = 1; off < 256; off <<= 1) {
        int a = sScan[t];
        int b = (t >= off) ? sScan[t - off] : 0;
        __syncthreads();
        sScan[t] = a + b;
        __syncthreads();
    }
    if (t < NBUCK) {
        int excl = sScan[t] - v;
        sStart[t] = excl;
        sCur[t] = excl;
        sGB[t] = v ? atomicAdd(&bcur[t], v) : 0;
    }
    __syncthreads();
    // pass 2: place into LDS sorted by bucket
    for (int e = c0 + t; e < cend; e += 256) {
        int d = dst[e];
        int b = d >> BSH;
        int slot = atomicAdd(&sCur[b], 1);
        sSort[slot] = ((d & 511) << 17) | src[e];
    }
    __syncthreads();
    // flush: wave w handles buckets w, w+4, ... (runs are contiguous)
    int w = t >> 6, ln = t & 63;
    for (int b = w; b < NBUCK; b += 4) {
        int ls = sStart[b], le = sCur[b];
        int gb = sGB[b];
        for (int i = ls + ln; i < le; i += 64)
            pr[gb + (i - ls)] = sSort[i];
    }
}

// Phase B: per-bucket CSR finalize — LDS histogram/scan -> int2 rowptr{start,end}
// + LDS-cursor scatter of src ids into the padded bucket region.
__global__ __launch_bounds__(256) void bucket_csr_kernel(const int* __restrict__ bc,
                                                         const int* __restrict__ pairs,
                                                         int2* __restrict__ rowptr2,
                                                         int* __restrict__ ssrc) {
    int y = blockIdx.y;
    pairs += (size_t)y * (NBUCK * CAP);
    rowptr2 += (size_t)y * NNODE;
    ssrc += (size_t)y * (NBUCK * CAP);

    __shared__ int cnt[512];
    __shared__ int cur[512];
    __shared__ int s1[256];
    int b = blockIdx.x;
    int t = threadIdx.x;
    int node0 = b << BSH;
    int start = b * CAP;
    int end = bc[y * 256 + b];   // final cursor = start + bucket count

    cnt[t] = 0;
    cnt[t + 256] = 0;
    __syncthreads();
    for (int e = start + t; e < end; e += 256)
        atomicAdd(&cnt[pairs[e] >> 17], 1);
    __syncthreads();
    int a0 = cnt[2 * t], a1 = cnt[2 * t + 1];
    s1[t] = a0 + a1;
    __syncthreads();
    for (int off = 1; off < 256; off <<= 1) {
        int a = s1[t];
        int c = (t >= off) ? s1[t - off] : 0;
        __syncthreads();
        s1[t] = a + c;
        __syncthreads();
    }
    int eb = start + s1[t] - (a0 + a1);
    cur[2 * t] = eb;
    cur[2 * t + 1] = eb + a0;
    int n0 = node0 + 2 * t;
    if (n0 + 1 < NNODE) {
        int4 rr = make_int4(eb, eb + a0, eb + a0, eb + a0 + a1);
        *(int4*)(rowptr2 + n0) = rr;
    } else if (n0 < NNODE) {
        rowptr2[n0] = make_int2(eb, eb + a0);
    }
    __syncthreads();
    for (int e = start + t; e < end; e += 256) {
        int p = pairs[e];
        int pos = atomicAdd(&cur[p >> 17], 1);
        ssrc[pos] = p & 0x1FFFF;
    }
}

// ============ gather-mean: wave per dst node, quarter-wave per edge ============
// Uniform main loop (exact 16-edge windows, 4 loads in flight) + predicated
// 8-edge tail windows (2 independent clamped loads/slot, masked accumulate).
__global__ __launch_bounds__(256) void gather_mean_kernel(const __half* __restrict__ x,
                                                          const int2* __restrict__ rowptr2,
                                                          const int* __restrict__ ssrc,
                                                          __half* __restrict__ out, int n) {
    int wid = (blockIdx.x * 256 + threadIdx.x) >> 6;
    int lane = threadIdx.x & 63;
    if (wid >= n) return;
    int qq = lane >> 4;        // edge slot 0..3
    int fo = (lane & 15) << 2; // feature quad base
    int2 se = rowptr2[wid];
    int start = se.x, end = se.y;
    int deg = end - start;
    int nfull = deg >> 4;
    float a0 = 0.f, a1 = 0.f, a2 = 0.f, a3 = 0.f;
    for (int w = 0; w < nfull; ++w) {
        int e = start + (w << 4) + qq;
        int v0 = ssrc[e], v1 = ssrc[e + 4], v2 = ssrc[e + 8], v3 = ssrc[e + 12];
        uint2 r0 = *(const uint2*)(x + ((size_t)v0 << 6) + fo);
        uint2 r1 = *(const uint2*)(x + ((size_t)v1 << 6) + fo);
        uint2 r2 = *(const uint2*)(x + ((size_t)v2 << 6) + fo);
        uint2 r3 = *(const uint2*)(x + ((size_t)v3 << 6) + fo);
        float2 f;
        f = __half22float2(*(__half2*)&r0.x); a0 += f.x; a1 += f.y;
        f = __half22float2(*(__half2*)&r0.y); a2 += f.x; a3 += f.y;
        f = __half22float2(*(__half2*)&r1.x); a0 += f.x; a1 += f.y;
        f = __half22float2(*(__half2*)&r1.y); a2 += f.x; a3 += f.y;
        f = __half22float2(*(__half2*)&r2.x); a0 += f.x; a1 += f.y;
        f = __half22float2(*(__half2*)&r2.y); a2 += f.x; a3 += f.y;
        f = __half22float2(*(__half2*)&r3.x); a0 += f.x; a1 += f.y;
        f = __half22float2(*(__half2*)&r3.y); a2 += f.x; a3 += f.y;
    }
    // predicated tail: window 8, uniform control flow, 2-deep per slot
    for (int e0 = start + (nfull << 4); e0 < end; e0 += 8) {
        int ea = e0 + qq, eb2 = e0 + qq + 4;
        bool pa = ea < end, pb = eb2 < end;
        int ia = pa ? ea : start;
        int ib = pb ? eb2 : start;
        int va = ssrc[ia], vb = ssrc[ib];
        uint2 ra = *(const uint2*)(x + ((size_t)va << 6) + fo);
        uint2 rb = *(const uint2*)(x + ((size_t)vb << 6) + fo);
        float ma = pa ? 1.f : 0.f, mb = pb ? 1.f : 0.f;
        float2 f;
        f = __half22float2(*(__half2*)&ra.x); a0 = fmaf(ma, f.x, a0); a1 = fmaf(ma, f.y, a1);
        f = __half22float2(*(__half2*)&ra.y); a2 = fmaf(ma, f.x, a2); a3 = fmaf(ma, f.y, a3);
        f = __half22float2(*(__half2*)&rb.x); a0 = fmaf(mb, f.x, a0); a1 = fmaf(mb, f.y, a1);
        f = __half22float2(*(__half2*)&rb.y); a2 = fmaf(mb, f.x, a2); a3 = fmaf(mb, f.y, a3);
    }
    a0 += __shfl_xor(a0, 16); a0 += __shfl_xor(a0, 32);
    a1 += __shfl_xor(a1, 16); a1 += __shfl_xor(a1, 32);
    a2 += __shfl_xor(a2, 16); a2 += __shfl_xor(a2, 32);
    a3 += __shfl_xor(a3, 16); a3 += __shfl_xor(a3, 32);
    if (qq == 0) {
        float scale = 1.0f / fmaxf((float)deg, 1.0f);
        uint2 w;
        *(__half2*)&w.x = __floats2half2_rn(a0 * scale, a1 * scale);
        *(__half2*)&w.y = __floats2half2_rn(a2 * scale, a3 * scale);
        *(uint2*)(out + ((size_t)wid << 6) + fo) = w;
    }
}

// ============ weight prep: fp16 W^T (+ summed wr, summed biases) ============
__global__ __launch_bounds__(256) void wprep_kernel(
    const float* __restrict__ writes_wl, const float* __restrict__ cites_wl,
    const float* __restrict__ writes_wr, const float* __restrict__ cites_wr,
    const float* __restrict__ wb_wl, const float* __restrict__ wb_wr,
    const float* __restrict__ winA_w, const float* __restrict__ winP_w,
    const float* __restrict__ lin_w,
    const float* __restrict__ writes_bl, const float* __restrict__ cites_bl,
    __half* __restrict__ wtP0, __half* __restrict__ wtP1, __half* __restrict__ wtA,
    __half* __restrict__ wtPJA, __half* __restrict__ wtPJP, __half* __restrict__ wtLIN,
    float* __restrict__ biasP) {
    int i = blockIdx.x * 256 + threadIdx.x;
    if (i < 24576) {                       // paper combine W^T [64][192] x 2 layers
        int l = i / 12288, j = i % 12288;
        int n = j / 192, k = j % 192;
        float v;
        if (k < 64) v = writes_wl[l * 4096 + k * 64 + n];
        else if (k < 128) v = cites_wl[l * 4096 + (k - 64) * 64 + n];
        else v = writes_wr[l * 4096 + (k - 128) * 64 + n] +
                 cites_wr[l * 4096 + (k - 128) * 64 + n];
        (l ? wtP1 : wtP0)[n * 192 + k] = __float2half(v);
    } else if (i < 32768) {                // author combine W^T [64][128], layer 0
        int j = i - 24576;
        int n = j / 128, k = j % 128;
        float v = (k < 64) ? wb_wl[k * 64 + n] : wb_wr[(k - 64) * 64 + n];
        wtA[n * 128 + k] = __float2half(v);
    } else if (i < 36864) {                // proj author W^T [64][64]
        int j = i - 32768;
        wtPJA[j] = __float2half(winA_w[(j % 64) * 64 + j / 64]);
    } else if (i < 40960) {                // proj paper W^T [64][64]
        int j = i - 36864;
        wtPJP[j] = __float2half(winP_w[(j % 64) * 64 + j / 64]);
    } else if (i < 41984) {                // lin W^T [16][64]
        int j = i - 40960;
        wtLIN[j] = __float2half(lin_w[(j % 64) * 16 + j / 64]);
    } else if (i < 42112) {                // summed paper biases, 2 layers
        int j = i - 41984;
        biasP[j] = writes_bl[j] + cites_bl[j];
    }
}

// ============ MFMA node-GEMMs: wave = 16 nodes, no LDS ============
__device__ inline f16x8 cvt8(const float* p) {
    float4 a = *(const float4*)p, b = *(const float4*)(p + 4);
    f16x8 r;
    r[0] = (_Float16)a.x; r[1] = (_Float16)a.y; r[2] = (_Float16)a.z; r[3] = (_Float16)a.w;
    r[4] = (_Float16)b.x; r[5] = (_Float16)b.y; r[6] = (_Float16)b.z; r[7] = (_Float16)b.w;
    return r;
}

__global__ __launch_bounds__(256) void proj_mfma(const float* __restrict__ xd,
                                                 const float* __restrict__ xc,
                                                 const __half* __restrict__ wt,
                                                 const float* __restrict__ bias,
                                                 __half* __restrict__ out) {
    int wid = (blockIdx.x * 256 + threadIdx.x) >> 6;
    if (wid >= NNODE / 16) return;
    int lane = threadIdx.x & 63;
    int row = lane & 15, kq = lane >> 4;
    int node0 = wid << 4;
    f16x8 af0 = cvt8(xd + (size_t)(node0 + row) * 32 + kq * 8);
    f16x8 af1 = cvt8(xc + (size_t)(node0 + row) * 32 + kq * 8);
#pragma unroll
    for (int nt = 0; nt < 4; ++nt) {
        int col = nt * 16 + row;
        const __half* wp = wt + (size_t)col * 64 + kq * 8;
        f32x4 acc = {0.f, 0.f, 0.f, 0.f};
        acc = __builtin_amdgcn_mfma_f32_16x16x32_f16(af0, *(const f16x8*)(wp), acc, 0, 0, 0);
        acc = __builtin_amdgcn_mfma_f32_16x16x32_f16(af1, *(const f16x8*)(wp + 32), acc, 0, 0, 0);
        float b = bias[col];
#pragma unroll
        for (int r = 0; r < 4; ++r)
            out[((size_t)(node0 + kq * 4 + r) << 6) + col] = __float2half(fmaxf(acc[r] + b, 0.f));
    }
}

template <int NSEG>
__global__ __launch_bounds__(256) void combine_mfma(const __half* __restrict__ a0,
                                                    const __half* __restrict__ a1,
                                                    const __half* __restrict__ a2,
                                                    const __half* __restrict__ wt,
                                                    const float* __restrict__ bias,
                                                    __half* __restrict__ out) {
    int wid = (blockIdx.x * 256 + threadIdx.x) >> 6;
    if (wid >= NNODE / 16) return;
    int lane = threadIdx.x & 63;
    int row = lane & 15, kq = lane >> 4;
    int node0 = wid << 4;
    const int K = NSEG * 64;
    const __half* as[3] = {a0, a1, a2};
    f16x8 af[2 * NSEG];
#pragma unroll
    for (int s = 0; s < NSEG; ++s) {
        const __half* p = as[s] + ((size_t)(node0 + row) << 6) + kq * 8;
        af[2 * s] = *(const f16x8*)(p);
        af[2 * s + 1] = *(const f16x8*)(p + 32);
    }
#pragma unroll
    for (int nt = 0; nt < 4; ++nt) {
        int col = nt * 16 + row;
        const __half* wp = wt + (size_t)col * K + kq * 8;
        f32x4 acc = {0.f, 0.f, 0.f, 0.f};
#pragma unroll
        for (int t = 0; t < 2 * NSEG; ++t)
            acc = __builtin_amdgcn_mfma_f32_16x16x32_f16(af[t], *(const f16x8*)(wp + t * 32), acc, 0, 0, 0);
        float b = bias[col];
#pragma unroll
        for (int r = 0; r < 4; ++r)
            out[((size_t)(node0 + kq * 4 + r) << 6) + col] = __float2half(acc[r] + b);
    }
}

__global__ __launch_bounds__(256) void final_mfma(const __half* __restrict__ y,
                                                  const __half* __restrict__ wt,
                                                  const float* __restrict__ bias,
                                                  float* __restrict__ out) {
    int wid = (blockIdx.x * 256 + threadIdx.x) >> 6;
    if (wid >= NNODE / 16) return;
    int lane = threadIdx.x & 63;
    int row = lane & 15, kq = lane >> 4;
    int node0 = wid << 4;
    const __half* p = y + ((size_t)(node0 + row) << 6) + kq * 8;
    f16x8 af0 = *(const f16x8*)(p);
    f16x8 af1 = *(const f16x8*)(p + 32);
    const __half* wp = wt + (size_t)row * 64 + kq * 8;
    f32x4 acc = {0.f, 0.f, 0.f, 0.f};
    acc = __builtin_amdgcn_mfma_f32_16x16x32_f16(af0, *(const f16x8*)(wp), acc, 0, 0, 0);
    acc = __builtin_amdgcn_mfma_f32_16x16x32_f16(af1, *(const f16x8*)(wp + 32), acc, 0, 0, 0);
    float b = bias[row];
#pragma unroll
    for (int r = 0; r < 4; ++r)
        out[(size_t)(node0 + kq * 4 + r) * 16 + row] = acc[r] + b;
}

extern "C" void kernel_launch(void* const* d_in, const int* in_sizes, int n_in,
                              void* d_out, int out_size, void* d_ws, size_t ws_size,
                              hipStream_t stream) {
    (void)in_sizes; (void)n_in; (void)out_size; (void)ws_size;
    const float* xda = (const float*)d_in[0];
    const float* xca = (const float*)d_in[1];
    const float* xdp = (const float*)d_in[2];
    const float* xcp = (const float*)d_in[3];
    const float* winA_w = (const float*)d_in[4];
    const float* winA_b = (const float*)d_in[5];
    const float* winP_w = (const float*)d_in[6];
    const float* winP_b = (const float*)d_in[7];
    const float* writes_wl = (const float*)d_in[8];
    const float* writes_bl = (const float*)d_in[9];
    const float* writes_wr = (const float*)d_in[10];
    const float* wb_wl = (const float*)d_in[11];
    const float* wb_bl = (const float*)d_in[12];
    const float* wb_wr = (const float*)d_in[13];
    const float* cites_wl = (const float*)d_in[14];
    const float* cites_bl = (const float*)d_in[15];
    const float* cites_wr = (const float*)d_in[16];
    const float* lin_w = (const float*)d_in[17];
    const float* lin_b = (const float*)d_in[18];
    const int* w_src = (const int*)d_in[19];
    const int* w_dst = (const int*)d_in[20];
    const int* b_src = (const int*)d_in[21];
    const int* b_dst = (const int*)d_in[22];
    const int* c_src = (const int*)d_in[23];
    const int* c_dst = (const int*)d_in[24];

    const size_t NF = (size_t)NNODE * 64;
    const size_t BUK = (size_t)NBUCK * CAP;   // padded slots per edge type
    __half* B0 = (__half*)d_ws;      // y_a0 -> L1 mean_writes -> y_p2
    __half* B1 = B0 + NF;            // y_p0 -> L1 mean_cites
    __half* B2 = B1 + NF;            // L0 mean_writes -> y_p1
    __half* B3 = B2 + NF;            // L0 mean_cites
    __half* B4 = B3 + NF;            // L0 mean_wb -> y_a1

    __half* wtP0 = B4 + NF;          // 12288
    __half* wtP1 = wtP0 + 12288;     // 12288
    __half* wtA = wtP1 + 12288;      // 8192
    __half* wtPJA = wtA + 8192;      // 4096
    __half* wtPJP = wtPJA + 4096;    // 4096
    __half* wtLIN = wtPJP + 4096;    // 1024
    float* biasP = (float*)(wtLIN + 1024);  // 128

    int* ip = (int*)(biasP + 128);
    int2* rp2 = (int2*)ip;               // 3 * NNODE int2
    int* bcur = (int*)(rp2 + 3 * NNODE); // 3 * 256
    int* ssrc = bcur + 3 * 256;          // 3 * BUK
    int* pairs = (int*)B2;               // CSR-build-only alias (21.7MB < 38.4MB)

    const int GB = (NNODE * 64) / 256;      // 25000 (wave per node)
    const int MB = (NNODE / 16 + 3) / 4;    // 1563 (wave per 16 nodes)
    const int PB = (NEDGE + PCH - 1) / PCH; // 196

    // ---- weight prep + CSR build ----
    wprep_kernel<<<165, 256, 0, stream>>>(writes_wl, cites_wl, writes_wr, cites_wr,
                                          wb_wl, wb_wr, winA_w, winP_w, lin_w,
                                          writes_bl, cites_bl,
                                          wtP0, wtP1, wtA, wtPJA, wtPJP, wtLIN, biasP);
    initcur_kernel<<<3, 256, 0, stream>>>(bcur);
    partition_kernel<<<dim3(PB, 3), 256, 0, stream>>>(w_src, c_src, b_src,
                                                      w_dst, c_dst, b_dst, bcur, pairs);
    bucket_csr_kernel<<<dim3(NBUCK, 3), 256, 0, stream>>>(bcur, pairs, rp2, ssrc);

    const int2* rp_w = rp2;
    const int2* rp_c = rp2 + NNODE;
    const int2* rp_b = rp2 + 2 * NNODE;
    const int* ss_w = ssrc;
    const int* ss_c = ssrc + BUK;
    const int* ss_b = ssrc + 2 * BUK;

    // ---- input projections ----
    proj_mfma<<<MB, 256, 0, stream>>>(xda, xca, wtPJA, winA_b, B0);
    proj_mfma<<<MB, 256, 0, stream>>>(xdp, xcp, wtPJP, winP_b, B1);

    // ---- layer 0 ----
    gather_mean_kernel<<<GB, 256, 0, stream>>>(B0, rp_w, ss_w, B2, NNODE);
    gather_mean_kernel<<<GB, 256, 0, stream>>>(B1, rp_c, ss_c, B3, NNODE);
    gather_mean_kernel<<<GB, 256, 0, stream>>>(B1, rp_b, ss_b, B4, NNODE);
    combine_mfma<3><<<MB, 256, 0, stream>>>(B2, B3, B1, wtP0, biasP, B2);
    combine_mfma<2><<<MB, 256, 0, stream>>>(B4, B0, nullptr, wtA, wb_bl, B4);

    // ---- layer 1 ---- (author update is dead code in the reference: skipped)
    gather_mean_kernel<<<GB, 256, 0, stream>>>(B4, rp_w, ss_w, B0, NNODE);
    gather_mean_kernel<<<GB, 256, 0, stream>>>(B2, rp_c, ss_c, B1, NNODE);
    combine_mfma<3><<<MB, 256, 0, stream>>>(B0, B1, B2, wtP1, biasP + 64, B0);

    // ---- final projection to OUT=16 ----
    final_mfma<<<MB, 256, 0, stream>>>(B0, wtLIN, lin_b, (float*)d_out);
}

// Round 10
// 364.468 us; speedup vs baseline: 20.0552x; 1.0535x over previous
//
#include <hip/hip_runtime.h>
#include <hip/hip_fp16.h>

#define NNODE 100000
#define NEDGE 1600000
#define NBUCK 196      // ceil(100000/512)
#define BSH 9          // 512 nodes per bucket
#define PCH 8192       // edges per partition block
#define CAP 9216       // fixed bucket capacity (mean 8163 + 11.6 sigma)

typedef _Float16 f16x8 __attribute__((ext_vector_type(8)));
typedef float f32x4 __attribute__((ext_vector_type(4)));

// ============ CSR build (batched over 3 edge types via blockIdx.y) ============

// cursor init: bucket b's region starts at b*CAP
__global__ __launch_bounds__(256) void initcur_kernel(int* __restrict__ bcur) {
    int y = blockIdx.x;
    int b = threadIdx.x;
    if (b < NBUCK) bcur[y * 256 + b] = b * CAP;
}

// Phase A: partition into fixed-capacity dst-bucket streams via per-block LDS
// counting sort; linear sBid flush (coalesced), 512 threads for occupancy.
__global__ __launch_bounds__(512) void partition_kernel(
    const int* __restrict__ s0, const int* __restrict__ s1, const int* __restrict__ s2,
    const int* __restrict__ d0, const int* __restrict__ d1, const int* __restrict__ d2,
    int* __restrict__ bc, int* __restrict__ pairs) {
    int y = blockIdx.y;
    const int* src = (y == 0) ? s0 : (y == 1) ? s1 : s2;
    const int* dst = (y == 0) ? d0 : (y == 1) ? d1 : d2;
    int* bcur = bc + y * 256;
    int* pr = pairs + (size_t)y * (NBUCK * CAP);

    __shared__ int sCur[NBUCK];          // counts -> local cursor
    __shared__ int sDelta[NBUCK];        // globalBase - localStart
    __shared__ int sScan[256];
    __shared__ int sSort[PCH];           // bucket-sorted packed pairs (32 KB)
    __shared__ unsigned char sBid[PCH];  // bucket id per slot (8 KB)
    int t = threadIdx.x;
    for (int i = t; i < NBUCK; i += 512) sCur[i] = 0;
    __syncthreads();
    int c0 = blockIdx.x * PCH;
    int cend = min(c0 + PCH, NEDGE);
    int nblk = cend - c0;
    // pass 1: count
    for (int e = c0 + t; e < cend; e += 512)
        atomicAdd(&sCur[dst[e] >> BSH], 1);
    __syncthreads();
    // scan 196 counts (first 256 threads carry data; all hit barriers)
    int v = (t < NBUCK) ? sCur[t] : 0;
    if (t < 256) sScan[t] = v;
    __syncthreads();
    for (int off = 1; off < 256; off <<= 1) {
        int a = (t < 256) ? sScan[t] : 0;
        int b = (t >= off && t < 256) ? sScan[t - off] : 0;
        __syncthreads();
        if (t < 256) sScan[t] = a + b;
        __syncthreads();
    }
    if (t < NBUCK) {
        int excl = sScan[t] - v;
        sCur[t] = excl;           // local cursor
        int gb = v ? atomicAdd(&bcur[t], v) : 0;
        sDelta[t] = gb - excl;
    }
    __syncthreads();
    // pass 2: place into LDS sorted by bucket
    for (int e = c0 + t; e < cend; e += 512) {
        int d = dst[e];
        int b = d >> BSH;
        int slot = atomicAdd(&sCur[b], 1);
        sSort[slot] = ((d & 511) << 17) | src[e];
        sBid[slot] = (unsigned char)b;
    }
    __syncthreads();
    // flush: consecutive slots -> consecutive global within each run
    for (int i = t; i < nblk; i += 512)
        pr[sDelta[sBid[i]] + i] = sSort[i];
}

// Phase B: per-bucket CSR finalize — 512-thread LDS histogram + direct scan ->
// int2 rowptr{start,end} + LDS-cursor scatter into the padded bucket region.
__global__ __launch_bounds__(512) void bucket_csr_kernel(const int* __restrict__ bc,
                                                         const int* __restrict__ pairs,
                                                         int2* __restrict__ rowptr2,
                                                         int* __restrict__ ssrc) {
    int y = blockIdx.y;
    pairs += (size_t)y * (NBUCK * CAP);
    rowptr2 += (size_t)y * NNODE;
    ssrc += (size_t)y * (NBUCK * CAP);

    __shared__ int cnt[512];
    __shared__ int cur[512];
    __shared__ int s1[512];
    int b = blockIdx.x;
    int t = threadIdx.x;
    int node0 = b << BSH;
    int start = b * CAP;
    int end = bc[y * 256 + b];   // final cursor = start + bucket count

    cnt[t] = 0;
    __syncthreads();
    for (int e = start + t; e < end; e += 512)
        atomicAdd(&cnt[pairs[e] >> 17], 1);
    __syncthreads();
    int v = cnt[t];
    s1[t] = v;
    __syncthreads();
    for (int off = 1; off < 512; off <<= 1) {
        int a = s1[t];
        int c = (t >= off) ? s1[t - off] : 0;
        __syncthreads();
        s1[t] = a + c;
        __syncthreads();
    }
    int eb = start + s1[t] - v;  // exclusive base
    cur[t] = eb;
    if (node0 + t < NNODE) rowptr2[node0 + t] = make_int2(eb, eb + v);
    __syncthreads();
    for (int e = start + t; e < end; e += 512) {
        int p = pairs[e];
        int pos = atomicAdd(&cur[p >> 17], 1);
        ssrc[pos] = p & 0x1FFFF;
    }
}

// ============ gather-mean: wave per dst node, eighth-wave per edge ============
// 8 lanes x 16B (uint4) cover a 128B fp16 row; 8 edge slots/wave, 2-deep main loop.
__global__ __launch_bounds__(256) void gather_mean_kernel(const __half* __restrict__ x,
                                                          const int2* __restrict__ rowptr2,
                                                          const int* __restrict__ ssrc,
                                                          __half* __restrict__ out, int n) {
    int wid = (blockIdx.x * 256 + threadIdx.x) >> 6;
    int lane = threadIdx.x & 63;
    if (wid >= n) return;
    int ee = lane >> 3;        // edge slot 0..7
    int fo = (lane & 7) << 3;  // feature octet base (8 halves = 16B)
    int2 se = rowptr2[wid];
    int start = se.x, end = se.y;
    int deg = end - start;
    int nfull = deg >> 4;
    float a0 = 0.f, a1 = 0.f, a2 = 0.f, a3 = 0.f;
    float a4 = 0.f, a5 = 0.f, a6 = 0.f, a7 = 0.f;
    for (int w = 0; w < nfull; ++w) {
        int e = start + (w << 4) + ee;
        int v0 = ssrc[e], v1 = ssrc[e + 8];
        uint4 r0 = *(const uint4*)(x + ((size_t)v0 << 6) + fo);
        uint4 r1 = *(const uint4*)(x + ((size_t)v1 << 6) + fo);
        float2 f;
        f = __half22float2(*(__half2*)&r0.x); a0 += f.x; a1 += f.y;
        f = __half22float2(*(__half2*)&r0.y); a2 += f.x; a3 += f.y;
        f = __half22float2(*(__half2*)&r0.z); a4 += f.x; a5 += f.y;
        f = __half22float2(*(__half2*)&r0.w); a6 += f.x; a7 += f.y;
        f = __half22float2(*(__half2*)&r1.x); a0 += f.x; a1 += f.y;
        f = __half22float2(*(__half2*)&r1.y); a2 += f.x; a3 += f.y;
        f = __half22float2(*(__half2*)&r1.z); a4 += f.x; a5 += f.y;
        f = __half22float2(*(__half2*)&r1.w); a6 += f.x; a7 += f.y;
    }
    // predicated tail: window 8, uniform control flow
    for (int e0 = start + (nfull << 4); e0 < end; e0 += 8) {
        int ea = e0 + ee;
        bool pa = ea < end;
        int ia = pa ? ea : start;
        int va = ssrc[ia];
        uint4 ra = *(const uint4*)(x + ((size_t)va << 6) + fo);
        float ma = pa ? 1.f : 0.f;
        float2 f;
        f = __half22float2(*(__half2*)&ra.x); a0 = fmaf(ma, f.x, a0); a1 = fmaf(ma, f.y, a1);
        f = __half22float2(*(__half2*)&ra.y); a2 = fmaf(ma, f.x, a2); a3 = fmaf(ma, f.y, a3);
        f = __half22float2(*(__half2*)&ra.z); a4 = fmaf(ma, f.x, a4); a5 = fmaf(ma, f.y, a5);
        f = __half22float2(*(__half2*)&ra.w); a6 = fmaf(ma, f.x, a6); a7 = fmaf(ma, f.y, a7);
    }
    a0 += __shfl_xor(a0, 8); a0 += __shfl_xor(a0, 16); a0 += __shfl_xor(a0, 32);
    a1 += __shfl_xor(a1, 8); a1 += __shfl_xor(a1, 16); a1 += __shfl_xor(a1, 32);
    a2 += __shfl_xor(a2, 8); a2 += __shfl_xor(a2, 16); a2 += __shfl_xor(a2, 32);
    a3 += __shfl_xor(a3, 8); a3 += __shfl_xor(a3, 16); a3 += __shfl_xor(a3, 32);
    a4 += __shfl_xor(a4, 8); a4 += __shfl_xor(a4, 16); a4 += __shfl_xor(a4, 32);
    a5 += __shfl_xor(a5, 8); a5 += __shfl_xor(a5, 16); a5 += __shfl_xor(a5, 32);
    a6 += __shfl_xor(a6, 8); a6 += __shfl_xor(a6, 16); a6 += __shfl_xor(a6, 32);
    a7 += __shfl_xor(a7, 8); a7 += __shfl_xor(a7, 16); a7 += __shfl_xor(a7, 32);
    if (ee == 0) {
        float scale = 1.0f / fmaxf((float)deg, 1.0f);
        uint4 w;
        *(__half2*)&w.x = __floats2half2_rn(a0 * scale, a1 * scale);
        *(__half2*)&w.y = __floats2half2_rn(a2 * scale, a3 * scale);
        *(__half2*)&w.z = __floats2half2_rn(a4 * scale, a5 * scale);
        *(__half2*)&w.w = __floats2half2_rn(a6 * scale, a7 * scale);
        *(uint4*)(out + ((size_t)wid << 6) + fo) = w;
    }
}

// ============ weight prep: fp16 W^T (+ summed wr, summed biases) ============
__global__ __launch_bounds__(256) void wprep_kernel(
    const float* __restrict__ writes_wl, const float* __restrict__ cites_wl,
    const float* __restrict__ writes_wr, const float* __restrict__ cites_wr,
    const float* __restrict__ wb_wl, const float* __restrict__ wb_wr,
    const float* __restrict__ winA_w, const float* __restrict__ winP_w,
    const float* __restrict__ lin_w,
    const float* __restrict__ writes_bl, const float* __restrict__ cites_bl,
    __half* __restrict__ wtP0, __half* __restrict__ wtP1, __half* __restrict__ wtA,
    __half* __restrict__ wtPJA, __half* __restrict__ wtPJP, __half* __restrict__ wtLIN,
    float* __restrict__ biasP) {
    int i = blockIdx.x * 256 + threadIdx.x;
    if (i < 24576) {                       // paper combine W^T [64][192] x 2 layers
        int l = i / 12288, j = i % 12288;
        int n = j / 192, k = j % 192;
        float v;
        if (k < 64) v = writes_wl[l * 4096 + k * 64 + n];
        else if (k < 128) v = cites_wl[l * 4096 + (k - 64) * 64 + n];
        else v = writes_wr[l * 4096 + (k - 128) * 64 + n] +
                 cites_wr[l * 4096 + (k - 128) * 64 + n];
        (l ? wtP1 : wtP0)[n * 192 + k] = __float2half(v);
    } else if (i < 32768) {                // author combine W^T [64][128], layer 0
        int j = i - 24576;
        int n = j / 128, k = j % 128;
        float v = (k < 64) ? wb_wl[k * 64 + n] : wb_wr[(k - 64) * 64 + n];
        wtA[n * 128 + k] = __float2half(v);
    } else if (i < 36864) {                // proj author W^T [64][64]
        int j = i - 32768;
        wtPJA[j] = __float2half(winA_w[(j % 64) * 64 + j / 64]);
    } else if (i < 40960) {                // proj paper W^T [64][64]
        int j = i - 36864;
        wtPJP[j] = __float2half(winP_w[(j % 64) * 64 + j / 64]);
    } else if (i < 41984) {                // lin W^T [16][64]
        int j = i - 40960;
        wtLIN[j] = __float2half(lin_w[(j % 64) * 16 + j / 64]);
    } else if (i < 42112) {                // summed paper biases, 2 layers
        int j = i - 41984;
        biasP[j] = writes_bl[j] + cites_bl[j];
    }
}

// ============ MFMA node-GEMMs: wave = 16 nodes, no LDS ============
__device__ inline f16x8 cvt8(const float* p) {
    float4 a = *(const float4*)p, b = *(const float4*)(p + 4);
    f16x8 r;
    r[0] = (_Float16)a.x; r[1] = (_Float16)a.y; r[2] = (_Float16)a.z; r[3] = (_Float16)a.w;
    r[4] = (_Float16)b.x; r[5] = (_Float16)b.y; r[6] = (_Float16)b.z; r[7] = (_Float16)b.w;
    return r;
}

__global__ __launch_bounds__(256) void proj_mfma(const float* __restrict__ xd,
                                                 const float* __restrict__ xc,
                                                 const __half* __restrict__ wt,
                                                 const float* __restrict__ bias,
                                                 __half* __restrict__ out) {
    int wid = (blockIdx.x * 256 + threadIdx.x) >> 6;
    if (wid >= NNODE / 16) return;
    int lane = threadIdx.x & 63;
    int row = lane & 15, kq = lane >> 4;
    int node0 = wid << 4;
    f16x8 af0 = cvt8(xd + (size_t)(node0 + row) * 32 + kq * 8);
    f16x8 af1 = cvt8(xc + (size_t)(node0 + row) * 32 + kq * 8);
#pragma unroll
    for (int nt = 0; nt < 4; ++nt) {
        int col = nt * 16 + row;
        const __half* wp = wt + (size_t)col * 64 + kq * 8;
        f32x4 acc = {0.f, 0.f, 0.f, 0.f};
        acc = __builtin_amdgcn_mfma_f32_16x16x32_f16(af0, *(const f16x8*)(wp), acc, 0, 0, 0);
        acc = __builtin_amdgcn_mfma_f32_16x16x32_f16(af1, *(const f16x8*)(wp + 32), acc, 0, 0, 0);
        float b = bias[col];
#pragma unroll
        for (int r = 0; r < 4; ++r)
            out[((size_t)(node0 + kq * 4 + r) << 6) + col] = __float2half(fmaxf(acc[r] + b, 0.f));
    }
}

template <int NSEG>
__global__ __launch_bounds__(256) void combine_mfma(const __half* __restrict__ a0,
                                                    const __half* __restrict__ a1,
                                                    const __half* __restrict__ a2,
                                                    const __half* __restrict__ wt,
                                                    const float* __restrict__ bias,
                                                    __half* __restrict__ out) {
    int wid = (blockIdx.x * 256 + threadIdx.x) >> 6;
    if (wid >= NNODE / 16) return;
    int lane = threadIdx.x & 63;
    int row = lane & 15, kq = lane >> 4;
    int node0 = wid << 4;
    const int K = NSEG * 64;
    const __half* as[3] = {a0, a1, a2};
    f16x8 af[2 * NSEG];
#pragma unroll
    for (int s = 0; s < NSEG; ++s) {
        const __half* p = as[s] + ((size_t)(node0 + row) << 6) + kq * 8;
        af[2 * s] = *(const f16x8*)(p);
        af[2 * s + 1] = *(const f16x8*)(p + 32);
    }
#pragma unroll
    for (int nt = 0; nt < 4; ++nt) {
        int col = nt * 16 + row;
        const __half* wp = wt + (size_t)col * K + kq * 8;
        f32x4 acc = {0.f, 0.f, 0.f, 0.f};
#pragma unroll
        for (int t = 0; t < 2 * NSEG; ++t)
            acc = __builtin_amdgcn_mfma_f32_16x16x32_f16(af[t], *(const f16x8*)(wp + t * 32), acc, 0, 0, 0);
        float b = bias[col];
#pragma unroll
        for (int r = 0; r < 4; ++r)
            out[((size_t)(node0 + kq * 4 + r) << 6) + col] = __float2half(acc[r] + b);
    }
}

__global__ __launch_bounds__(256) void final_mfma(const __half* __restrict__ y,
                                                  const __half* __restrict__ wt,
                                                  const float* __restrict__ bias,
                                                  float* __restrict__ out) {
    int wid = (blockIdx.x * 256 + threadIdx.x) >> 6;
    if (wid >= NNODE / 16) return;
    int lane = threadIdx.x & 63;
    int row = lane & 15, kq = lane >> 4;
    int node0 = wid << 4;
    const __half* p = y + ((size_t)(node0 + row) << 6) + kq * 8;
    f16x8 af0 = *(const f16x8*)(p);
    f16x8 af1 = *(const f16x8*)(p + 32);
    const __half* wp = wt + (size_t)row * 64 + kq * 8;
    f32x4 acc = {0.f, 0.f, 0.f, 0.f};
    acc = __builtin_amdgcn_mfma_f32_16x16x32_f16(af0, *(const f16x8*)(wp), acc, 0, 0, 0);
    acc = __builtin_amdgcn_mfma_f32_16x16x32_f16(af1, *(const f16x8*)(wp + 32), acc, 0, 0, 0);
    float b = bias[row];
#pragma unroll
    for (int r = 0; r < 4; ++r)
        out[(size_t)(node0 + kq * 4 + r) * 16 + row] = acc[r] + b;
}

extern "C" void kernel_launch(void* const* d_in, const int* in_sizes, int n_in,
                              void* d_out, int out_size, void* d_ws, size_t ws_size,
                              hipStream_t stream) {
    (void)in_sizes; (void)n_in; (void)out_size; (void)ws_size;
    const float* xda = (const float*)d_in[0];
    const float* xca = (const float*)d_in[1];
    const float* xdp = (const float*)d_in[2];
    const float* xcp = (const float*)d_in[3];
    const float* winA_w = (const float*)d_in[4];
    const float* winA_b = (const float*)d_in[5];
    const float* winP_w = (const float*)d_in[6];
    const float* winP_b = (const float*)d_in[7];
    const float* writes_wl = (const float*)d_in[8];
    const float* writes_bl = (const float*)d_in[9];
    const float* writes_wr = (const float*)d_in[10];
    const float* wb_wl = (const float*)d_in[11];
    const float* wb_bl = (const float*)d_in[12];
    const float* wb_wr = (const float*)d_in[13];
    const float* cites_wl = (const float*)d_in[14];
    const float* cites_bl = (const float*)d_in[15];
    const float* cites_wr = (const float*)d_in[16];
    const float* lin_w = (const float*)d_in[17];
    const float* lin_b = (const float*)d_in[18];
    const int* w_src = (const int*)d_in[19];
    const int* w_dst = (const int*)d_in[20];
    const int* b_src = (const int*)d_in[21];
    const int* b_dst = (const int*)d_in[22];
    const int* c_src = (const int*)d_in[23];
    const int* c_dst = (const int*)d_in[24];

    const size_t NF = (size_t)NNODE * 64;
    const size_t BUK = (size_t)NBUCK * CAP;   // padded slots per edge type
    __half* B0 = (__half*)d_ws;      // y_a0 -> L1 mean_writes -> y_p2
    __half* B1 = B0 + NF;            // y_p0 -> L1 mean_cites
    __half* B2 = B1 + NF;            // L0 mean_writes -> y_p1
    __half* B3 = B2 + NF;            // L0 mean_cites
    __half* B4 = B3 + NF;            // L0 mean_wb -> y_a1

    __half* wtP0 = B4 + NF;          // 12288
    __half* wtP1 = wtP0 + 12288;     // 12288
    __half* wtA = wtP1 + 12288;      // 8192
    __half* wtPJA = wtA + 8192;      // 4096
    __half* wtPJP = wtPJA + 4096;    // 4096
    __half* wtLIN = wtPJP + 4096;    // 1024
    float* biasP = (float*)(wtLIN + 1024);  // 128

    int* ip = (int*)(biasP + 128);
    int2* rp2 = (int2*)ip;               // 3 * NNODE int2
    int* bcur = (int*)(rp2 + 3 * NNODE); // 3 * 256
    int* ssrc = bcur + 3 * 256;          // 3 * BUK
    int* pairs = (int*)B2;               // CSR-build-only alias (21.7MB < 38.4MB)

    const int GB = (NNODE * 64) / 256;      // 25000 (wave per node)
    const int MB = (NNODE / 16 + 3) / 4;    // 1563 (wave per 16 nodes)
    const int PB = (NEDGE + PCH - 1) / PCH; // 196

    // ---- weight prep + CSR build ----
    wprep_kernel<<<165, 256, 0, stream>>>(writes_wl, cites_wl, writes_wr, cites_wr,
                                          wb_wl, wb_wr, winA_w, winP_w, lin_w,
                                          writes_bl, cites_bl,
                                          wtP0, wtP1, wtA, wtPJA, wtPJP, wtLIN, biasP);
    initcur_kernel<<<3, 256, 0, stream>>>(bcur);
    partition_kernel<<<dim3(PB, 3), 512, 0, stream>>>(w_src, c_src, b_src,
                                                      w_dst, c_dst, b_dst, bcur, pairs);
    bucket_csr_kernel<<<dim3(NBUCK, 3), 512, 0, stream>>>(bcur, pairs, rp2, ssrc);

    const int2* rp_w = rp2;
    const int2* rp_c = rp2 + NNODE;
    const int2* rp_b = rp2 + 2 * NNODE;
    const int* ss_w = ssrc;
    const int* ss_c = ssrc + BUK;
    const int* ss_b = ssrc + 2 * BUK;

    // ---- input projections ----
    proj_mfma<<<MB, 256, 0, stream>>>(xda, xca, wtPJA, winA_b, B0);
    proj_mfma<<<MB, 256, 0, stream>>>(xdp, xcp, wtPJP, winP_b, B1);

    // ---- layer 0 ----
    gather_mean_kernel<<<GB, 256, 0, stream>>>(B0, rp_w, ss_w, B2, NNODE);
    gather_mean_kernel<<<GB, 256, 0, stream>>>(B1, rp_c, ss_c, B3, NNODE);
    gather_mean_kernel<<<GB, 256, 0, stream>>>(B1, rp_b, ss_b, B4, NNODE);
    combine_mfma<3><<<MB, 256, 0, stream>>>(B2, B3, B1, wtP0, biasP, B2);
    combine_mfma<2><<<MB, 256, 0, stream>>>(B4, B0, nullptr, wtA, wb_bl, B4);

    // ---- layer 1 ---- (author update is dead code in the reference: skipped)
    gather_mean_kernel<<<GB, 256, 0, stream>>>(B4, rp_w, ss_w, B0, NNODE);
    gather_mean_kernel<<<GB, 256, 0, stream>>>(B2, rp_c, ss_c, B1, NNODE);
    combine_mfma<3><<<MB, 256, 0, stream>>>(B0, B1, B2, wtP1, biasP + 64, B0);

    // ---- final projection to OUT=16 ----
    final_mfma<<<MB, 256, 0, stream>>>(B0, wtLIN, lin_b, (float*)d_out);
}

// Round 11
// 336.840 us; speedup vs baseline: 21.7001x; 1.0820x over previous
//
#include <hip/hip_runtime.h>
#include <hip/hip_fp16.h>

#define NNODE 100000
#define NEDGE 1600000
#define NBUCK 196      // ceil(100000/512)
#define BSH 9          // 512 nodes per bucket
#define PCH 8192       // edges per partition block
#define CAP 9216       // fixed bucket capacity (mean 8163 + 11.6 sigma)

typedef _Float16 f16x8 __attribute__((ext_vector_type(8)));
typedef float f32x4 __attribute__((ext_vector_type(4)));

// ============ CSR build (batched over 3 edge types via blockIdx.y) ============

// cursor init: bucket b's region starts at b*CAP
__global__ __launch_bounds__(256) void initcur_kernel(int* __restrict__ bcur) {
    int y = blockIdx.x;
    int b = threadIdx.x;
    if (b < NBUCK) bcur[y * 256 + b] = b * CAP;
}

// Phase A: partition into fixed-capacity dst-bucket streams via per-block LDS
// counting sort; linear sBid flush (coalesced), 512 threads for occupancy.
__global__ __launch_bounds__(512) void partition_kernel(
    const int* __restrict__ s0, const int* __restrict__ s1, const int* __restrict__ s2,
    const int* __restrict__ d0, const int* __restrict__ d1, const int* __restrict__ d2,
    int* __restrict__ bc, int* __restrict__ pairs) {
    int y = blockIdx.y;
    const int* src = (y == 0) ? s0 : (y == 1) ? s1 : s2;
    const int* dst = (y == 0) ? d0 : (y == 1) ? d1 : d2;
    int* bcur = bc + y * 256;
    int* pr = pairs + (size_t)y * (NBUCK * CAP);

    __shared__ int sCur[NBUCK];          // counts -> local cursor
    __shared__ int sDelta[NBUCK];        // globalBase - localStart
    __shared__ int sScan[256];
    __shared__ int sSort[PCH];           // bucket-sorted packed pairs (32 KB)
    __shared__ unsigned char sBid[PCH];  // bucket id per slot (8 KB)
    int t = threadIdx.x;
    for (int i = t; i < NBUCK; i += 512) sCur[i] = 0;
    __syncthreads();
    int c0 = blockIdx.x * PCH;
    int cend = min(c0 + PCH, NEDGE);
    int nblk = cend - c0;
    // pass 1: count
    for (int e = c0 + t; e < cend; e += 512)
        atomicAdd(&sCur[dst[e] >> BSH], 1);
    __syncthreads();
    // scan 196 counts (first 256 threads carry data; all hit barriers)
    int v = (t < NBUCK) ? sCur[t] : 0;
    if (t < 256) sScan[t] = v;
    __syncthreads();
    for (int off = 1; off < 256; off <<= 1) {
        int a = (t < 256) ? sScan[t] : 0;
        int b = (t >= off && t < 256) ? sScan[t - off] : 0;
        __syncthreads();
        if (t < 256) sScan[t] = a + b;
        __syncthreads();
    }
    if (t < NBUCK) {
        int excl = sScan[t] - v;
        sCur[t] = excl;           // local cursor
        int gb = v ? atomicAdd(&bcur[t], v) : 0;
        sDelta[t] = gb - excl;
    }
    __syncthreads();
    // pass 2: place into LDS sorted by bucket
    for (int e = c0 + t; e < cend; e += 512) {
        int d = dst[e];
        int b = d >> BSH;
        int slot = atomicAdd(&sCur[b], 1);
        sSort[slot] = ((d & 511) << 17) | src[e];
        sBid[slot] = (unsigned char)b;
    }
    __syncthreads();
    // flush: consecutive slots -> consecutive global within each run
    for (int i = t; i < nblk; i += 512)
        pr[sDelta[sBid[i]] + i] = sSort[i];
}

// Phase B: per-bucket CSR finalize — fully in LDS: load+histogram, scan,
// LDS->LDS cursor scatter, then LINEAR coalesced flush (kills write amp).
__global__ __launch_bounds__(512) void bucket_csr_kernel(const int* __restrict__ bc,
                                                         const int* __restrict__ pairs,
                                                         int2* __restrict__ rowptr2,
                                                         int* __restrict__ ssrc) {
    int y = blockIdx.y;
    pairs += (size_t)y * (NBUCK * CAP);
    rowptr2 += (size_t)y * NNODE;
    ssrc += (size_t)y * (NBUCK * CAP);

    __shared__ int sIn[CAP];    // 36 KB
    __shared__ int sOut[CAP];   // 36 KB
    __shared__ int cnt[512];
    __shared__ int cur[512];
    __shared__ int s1[512];
    int b = blockIdx.x;
    int t = threadIdx.x;
    int node0 = b << BSH;
    int start = b * CAP;
    int end = bc[y * 256 + b];   // final cursor = start + bucket count
    int m = end - start;

    cnt[t] = 0;
    __syncthreads();
    for (int i = t; i < m; i += 512) {
        int p = pairs[start + i];
        sIn[i] = p;
        atomicAdd(&cnt[p >> 17], 1);
    }
    __syncthreads();
    int v = cnt[t];
    s1[t] = v;
    __syncthreads();
    for (int off = 1; off < 512; off <<= 1) {
        int a = s1[t];
        int c = (t >= off) ? s1[t - off] : 0;
        __syncthreads();
        s1[t] = a + c;
        __syncthreads();
    }
    int eb = s1[t] - v;  // local exclusive base
    cur[t] = eb;
    if (node0 + t < NNODE) rowptr2[node0 + t] = make_int2(start + eb, start + eb + v);
    __syncthreads();
    for (int i = t; i < m; i += 512) {
        int p = sIn[i];
        int pos = atomicAdd(&cur[p >> 17], 1);
        sOut[pos] = p & 0x1FFFF;
    }
    __syncthreads();
    for (int i = t; i < m; i += 512)
        ssrc[start + i] = sOut[i];
}

// ============ gather-mean: wave per dst node, eighth-wave per edge ============
// 8 lanes x 16B (uint4) per 128B fp16 row; packed fp16 accumulation (v_pk_add_f16).
__global__ __launch_bounds__(256) void gather_mean_kernel(const __half* __restrict__ x,
                                                          const int2* __restrict__ rowptr2,
                                                          const int* __restrict__ ssrc,
                                                          __half* __restrict__ out, int n) {
    int wid = (blockIdx.x * 256 + threadIdx.x) >> 6;
    int lane = threadIdx.x & 63;
    if (wid >= n) return;
    int ee = lane >> 3;        // edge slot 0..7
    int fo = (lane & 7) << 3;  // feature octet base (8 halves = 16B)
    int2 se = rowptr2[wid];
    int start = se.x, end = se.y;
    int deg = end - start;
    int nfull = deg >> 4;
    __half2 h0 = __float2half2_rn(0.f), h1 = h0, h2 = h0, h3 = h0;
    for (int w = 0; w < nfull; ++w) {
        int e = start + (w << 4) + ee;
        int v0 = ssrc[e], v1 = ssrc[e + 8];
        uint4 r0 = *(const uint4*)(x + ((size_t)v0 << 6) + fo);
        uint4 r1 = *(const uint4*)(x + ((size_t)v1 << 6) + fo);
        h0 = __hadd2(h0, *(__half2*)&r0.x);
        h1 = __hadd2(h1, *(__half2*)&r0.y);
        h2 = __hadd2(h2, *(__half2*)&r0.z);
        h3 = __hadd2(h3, *(__half2*)&r0.w);
        h0 = __hadd2(h0, *(__half2*)&r1.x);
        h1 = __hadd2(h1, *(__half2*)&r1.y);
        h2 = __hadd2(h2, *(__half2*)&r1.z);
        h3 = __hadd2(h3, *(__half2*)&r1.w);
    }
    // predicated tail: window 8, uniform control flow
    __half2 one = __float2half2_rn(1.f), zero = __float2half2_rn(0.f);
    for (int e0 = start + (nfull << 4); e0 < end; e0 += 8) {
        int ea = e0 + ee;
        bool pa = ea < end;
        int ia = pa ? ea : start;
        int va = ssrc[ia];
        uint4 ra = *(const uint4*)(x + ((size_t)va << 6) + fo);
        __half2 hm = pa ? one : zero;
        h0 = __hfma2(hm, *(__half2*)&ra.x, h0);
        h1 = __hfma2(hm, *(__half2*)&ra.y, h1);
        h2 = __hfma2(hm, *(__half2*)&ra.z, h2);
        h3 = __hfma2(hm, *(__half2*)&ra.w, h3);
    }
    // reduce across the 8 edge slots in packed fp16
#define RED8(hh) { \
        int u_ = *(int*)&hh; int r_; \
        r_ = __shfl_xor(u_, 8);  hh = __hadd2(hh, *(__half2*)&r_); u_ = *(int*)&hh; \
        r_ = __shfl_xor(u_, 16); hh = __hadd2(hh, *(__half2*)&r_); u_ = *(int*)&hh; \
        r_ = __shfl_xor(u_, 32); hh = __hadd2(hh, *(__half2*)&r_); }
    RED8(h0) RED8(h1) RED8(h2) RED8(h3)
#undef RED8
    if (ee == 0) {
        float scale = 1.0f / fmaxf((float)deg, 1.0f);
        float2 f0 = __half22float2(h0), f1 = __half22float2(h1);
        float2 f2 = __half22float2(h2), f3 = __half22float2(h3);
        uint4 w;
        *(__half2*)&w.x = __floats2half2_rn(f0.x * scale, f0.y * scale);
        *(__half2*)&w.y = __floats2half2_rn(f1.x * scale, f1.y * scale);
        *(__half2*)&w.z = __floats2half2_rn(f2.x * scale, f2.y * scale);
        *(__half2*)&w.w = __floats2half2_rn(f3.x * scale, f3.y * scale);
        *(uint4*)(out + ((size_t)wid << 6) + fo) = w;
    }
}

// ============ weight prep: fp16 W^T (+ summed wr, summed biases) ============
__global__ __launch_bounds__(256) void wprep_kernel(
    const float* __restrict__ writes_wl, const float* __restrict__ cites_wl,
    const float* __restrict__ writes_wr, const float* __restrict__ cites_wr,
    const float* __restrict__ wb_wl, const float* __restrict__ wb_wr,
    const float* __restrict__ winA_w, const float* __restrict__ winP_w,
    const float* __restrict__ lin_w,
    const float* __restrict__ writes_bl, const float* __restrict__ cites_bl,
    __half* __restrict__ wtP0, __half* __restrict__ wtP1, __half* __restrict__ wtA,
    __half* __restrict__ wtPJA, __half* __restrict__ wtPJP, __half* __restrict__ wtLIN,
    float* __restrict__ biasP) {
    int i = blockIdx.x * 256 + threadIdx.x;
    if (i < 24576) {                       // paper combine W^T [64][192] x 2 layers
        int l = i / 12288, j = i % 12288;
        int n = j / 192, k = j % 192;
        float v;
        if (k < 64) v = writes_wl[l * 4096 + k * 64 + n];
        else if (k < 128) v = cites_wl[l * 4096 + (k - 64) * 64 + n];
        else v = writes_wr[l * 4096 + (k - 128) * 64 + n] +
                 cites_wr[l * 4096 + (k - 128) * 64 + n];
        (l ? wtP1 : wtP0)[n * 192 + k] = __float2half(v);
    } else if (i < 32768) {                // author combine W^T [64][128], layer 0
        int j = i - 24576;
        int n = j / 128, k = j % 128;
        float v = (k < 64) ? wb_wl[k * 64 + n] : wb_wr[(k - 64) * 64 + n];
        wtA[n * 128 + k] = __float2half(v);
    } else if (i < 36864) {                // proj author W^T [64][64]
        int j = i - 32768;
        wtPJA[j] = __float2half(winA_w[(j % 64) * 64 + j / 64]);
    } else if (i < 40960) {                // proj paper W^T [64][64]
        int j = i - 36864;
        wtPJP[j] = __float2half(winP_w[(j % 64) * 64 + j / 64]);
    } else if (i < 41984) {                // lin W^T [16][64]
        int j = i - 40960;
        wtLIN[j] = __float2half(lin_w[(j % 64) * 16 + j / 64]);
    } else if (i < 42112) {                // summed paper biases, 2 layers
        int j = i - 41984;
        biasP[j] = writes_bl[j] + cites_bl[j];
    }
}

// ============ MFMA node-GEMMs: wave = 16 nodes, no LDS ============
__device__ inline f16x8 cvt8(const float* p) {
    float4 a = *(const float4*)p, b = *(const float4*)(p + 4);
    f16x8 r;
    r[0] = (_Float16)a.x; r[1] = (_Float16)a.y; r[2] = (_Float16)a.z; r[3] = (_Float16)a.w;
    r[4] = (_Float16)b.x; r[5] = (_Float16)b.y; r[6] = (_Float16)b.z; r[7] = (_Float16)b.w;
    return r;
}

__global__ __launch_bounds__(256) void proj_mfma(const float* __restrict__ xd,
                                                 const float* __restrict__ xc,
                                                 const __half* __restrict__ wt,
                                                 const float* __restrict__ bias,
                                                 __half* __restrict__ out) {
    int wid = (blockIdx.x * 256 + threadIdx.x) >> 6;
    if (wid >= NNODE / 16) return;
    int lane = threadIdx.x & 63;
    int row = lane & 15, kq = lane >> 4;
    int node0 = wid << 4;
    f16x8 af0 = cvt8(xd + (size_t)(node0 + row) * 32 + kq * 8);
    f16x8 af1 = cvt8(xc + (size_t)(node0 + row) * 32 + kq * 8);
#pragma unroll
    for (int nt = 0; nt < 4; ++nt) {
        int col = nt * 16 + row;
        const __half* wp = wt + (size_t)col * 64 + kq * 8;
        f32x4 acc = {0.f, 0.f, 0.f, 0.f};
        acc = __builtin_amdgcn_mfma_f32_16x16x32_f16(af0, *(const f16x8*)(wp), acc, 0, 0, 0);
        acc = __builtin_amdgcn_mfma_f32_16x16x32_f16(af1, *(const f16x8*)(wp + 32), acc, 0, 0, 0);
        float b = bias[col];
#pragma unroll
        for (int r = 0; r < 4; ++r)
            out[((size_t)(node0 + kq * 4 + r) << 6) + col] = __float2half(fmaxf(acc[r] + b, 0.f));
    }
}

template <int NSEG>
__global__ __launch_bounds__(256) void combine_mfma(const __half* __restrict__ a0,
                                                    const __half* __restrict__ a1,
                                                    const __half* __restrict__ a2,
                                                    const __half* __restrict__ wt,
                                                    const float* __restrict__ bias,
                                                    __half* __restrict__ out) {
    int wid = (blockIdx.x * 256 + threadIdx.x) >> 6;
    if (wid >= NNODE / 16) return;
    int lane = threadIdx.x & 63;
    int row = lane & 15, kq = lane >> 4;
    int node0 = wid << 4;
    const int K = NSEG * 64;
    const __half* as[3] = {a0, a1, a2};
    f16x8 af[2 * NSEG];
#pragma unroll
    for (int s = 0; s < NSEG; ++s) {
        const __half* p = as[s] + ((size_t)(node0 + row) << 6) + kq * 8;
        af[2 * s] = *(const f16x8*)(p);
        af[2 * s + 1] = *(const f16x8*)(p + 32);
    }
#pragma unroll
    for (int nt = 0; nt < 4; ++nt) {
        int col = nt * 16 + row;
        const __half* wp = wt + (size_t)col * K + kq * 8;
        f32x4 acc = {0.f, 0.f, 0.f, 0.f};
#pragma unroll
        for (int t = 0; t < 2 * NSEG; ++t)
            acc = __builtin_amdgcn_mfma_f32_16x16x32_f16(af[t], *(const f16x8*)(wp + t * 32), acc, 0, 0, 0);
        float b = bias[col];
#pragma unroll
        for (int r = 0; r < 4; ++r)
            out[((size_t)(node0 + kq * 4 + r) << 6) + col] = __float2half(acc[r] + b);
    }
}

__global__ __launch_bounds__(256) void final_mfma(const __half* __restrict__ y,
                                                  const __half* __restrict__ wt,
                                                  const float* __restrict__ bias,
                                                  float* __restrict__ out) {
    int wid = (blockIdx.x * 256 + threadIdx.x) >> 6;
    if (wid >= NNODE / 16) return;
    int lane = threadIdx.x & 63;
    int row = lane & 15, kq = lane >> 4;
    int node0 = wid << 4;
    const __half* p = y + ((size_t)(node0 + row) << 6) + kq * 8;
    f16x8 af0 = *(const f16x8*)(p);
    f16x8 af1 = *(const f16x8*)(p + 32);
    const __half* wp = wt + (size_t)row * 64 + kq * 8;
    f32x4 acc = {0.f, 0.f, 0.f, 0.f};
    acc = __builtin_amdgcn_mfma_f32_16x16x32_f16(af0, *(const f16x8*)(wp), acc, 0, 0, 0);
    acc = __builtin_amdgcn_mfma_f32_16x16x32_f16(af1, *(const f16x8*)(wp + 32), acc, 0, 0, 0);
    float b = bias[row];
#pragma unroll
    for (int r = 0; r < 4; ++r)
        out[(size_t)(node0 + kq * 4 + r) * 16 + row] = acc[r] + b;
}

extern "C" void kernel_launch(void* const* d_in, const int* in_sizes, int n_in,
                              void* d_out, int out_size, void* d_ws, size_t ws_size,
                              hipStream_t stream) {
    (void)in_sizes; (void)n_in; (void)out_size; (void)ws_size;
    const float* xda = (const float*)d_in[0];
    const float* xca = (const float*)d_in[1];
    const float* xdp = (const float*)d_in[2];
    const float* xcp = (const float*)d_in[3];
    const float* winA_w = (const float*)d_in[4];
    const float* winA_b = (const float*)d_in[5];
    const float* winP_w = (const float*)d_in[6];
    const float* winP_b = (const float*)d_in[7];
    const float* writes_wl = (const float*)d_in[8];
    const float* writes_bl = (const float*)d_in[9];
    const float* writes_wr = (const float*)d_in[10];
    const float* wb_wl = (const float*)d_in[11];
    const float* wb_bl = (const float*)d_in[12];
    const float* wb_wr = (const float*)d_in[13];
    const float* cites_wl = (const float*)d_in[14];
    const float* cites_bl = (const float*)d_in[15];
    const float* cites_wr = (const float*)d_in[16];
    const float* lin_w = (const float*)d_in[17];
    const float* lin_b = (const float*)d_in[18];
    const int* w_src = (const int*)d_in[19];
    const int* w_dst = (const int*)d_in[20];
    const int* b_src = (const int*)d_in[21];
    const int* b_dst = (const int*)d_in[22];
    const int* c_src = (const int*)d_in[23];
    const int* c_dst = (const int*)d_in[24];

    const size_t NF = (size_t)NNODE * 64;
    const size_t BUK = (size_t)NBUCK * CAP;   // padded slots per edge type
    __half* B0 = (__half*)d_ws;      // y_a0 -> L1 mean_writes -> y_p2
    __half* B1 = B0 + NF;            // y_p0 -> L1 mean_cites
    __half* B2 = B1 + NF;            // L0 mean_writes -> y_p1
    __half* B3 = B2 + NF;            // L0 mean_cites
    __half* B4 = B3 + NF;            // L0 mean_wb -> y_a1

    __half* wtP0 = B4 + NF;          // 12288
    __half* wtP1 = wtP0 + 12288;     // 12288
    __half* wtA = wtP1 + 12288;      // 8192
    __half* wtPJA = wtA + 8192;      // 4096
    __half* wtPJP = wtPJA + 4096;    // 4096
    __half* wtLIN = wtPJP + 4096;    // 1024
    float* biasP = (float*)(wtLIN + 1024);  // 128

    int* ip = (int*)(biasP + 128);
    int2* rp2 = (int2*)ip;               // 3 * NNODE int2
    int* bcur = (int*)(rp2 + 3 * NNODE); // 3 * 256
    int* ssrc = bcur + 3 * 256;          // 3 * BUK
    int* pairs = (int*)B2;               // CSR-build-only alias (21.7MB < 38.4MB)

    const int GB = (NNODE * 64) / 256;      // 25000 (wave per node)
    const int MB = (NNODE / 16 + 3) / 4;    // 1563 (wave per 16 nodes)
    const int PB = (NEDGE + PCH - 1) / PCH; // 196

    // ---- weight prep + CSR build ----
    wprep_kernel<<<165, 256, 0, stream>>>(writes_wl, cites_wl, writes_wr, cites_wr,
                                          wb_wl, wb_wr, winA_w, winP_w, lin_w,
                                          writes_bl, cites_bl,
                                          wtP0, wtP1, wtA, wtPJA, wtPJP, wtLIN, biasP);
    initcur_kernel<<<3, 256, 0, stream>>>(bcur);
    partition_kernel<<<dim3(PB, 3), 512, 0, stream>>>(w_src, c_src, b_src,
                                                      w_dst, c_dst, b_dst, bcur, pairs);
    bucket_csr_kernel<<<dim3(NBUCK, 3), 512, 0, stream>>>(bcur, pairs, rp2, ssrc);

    const int2* rp_w = rp2;
    const int2* rp_c = rp2 + NNODE;
    const int2* rp_b = rp2 + 2 * NNODE;
    const int* ss_w = ssrc;
    const int* ss_c = ssrc + BUK;
    const int* ss_b = ssrc + 2 * BUK;

    // ---- input projections ----
    proj_mfma<<<MB, 256, 0, stream>>>(xda, xca, wtPJA, winA_b, B0);
    proj_mfma<<<MB, 256, 0, stream>>>(xdp, xcp, wtPJP, winP_b, B1);

    // ---- layer 0 ----
    gather_mean_kernel<<<GB, 256, 0, stream>>>(B0, rp_w, ss_w, B2, NNODE);
    gather_mean_kernel<<<GB, 256, 0, stream>>>(B1, rp_c, ss_c, B3, NNODE);
    gather_mean_kernel<<<GB, 256, 0, stream>>>(B1, rp_b, ss_b, B4, NNODE);
    combine_mfma<3><<<MB, 256, 0, stream>>>(B2, B3, B1, wtP0, biasP, B2);
    combine_mfma<2><<<MB, 256, 0, stream>>>(B4, B0, nullptr, wtA, wb_bl, B4);

    // ---- layer 1 ---- (author update is dead code in the reference: skipped)
    gather_mean_kernel<<<GB, 256, 0, stream>>>(B4, rp_w, ss_w, B0, NNODE);
    gather_mean_kernel<<<GB, 256, 0, stream>>>(B2, rp_c, ss_c, B1, NNODE);
    combine_mfma<3><<<MB, 256, 0, stream>>>(B0, B1, B2, wtP1, biasP + 64, B0);

    // ---- final projection to OUT=16 ----
    final_mfma<<<MB, 256, 0, stream>>>(B0, wtLIN, lin_b, (float*)d_out);
}

// Round 12
// 314.928 us; speedup vs baseline: 23.2099x; 1.0696x over previous
//
#include <hip/hip_runtime.h>
#include <hip/hip_fp16.h>

#define NNODE 100000
#define NEDGE 1600000
#define NBUCK 196      // ceil(100000/512)
#define BSH 9          // 512 nodes per bucket
#define PCH 8192       // edges per partition block
#define CAP 9216       // fixed bucket capacity (mean 8163 + 11.6 sigma)

typedef _Float16 f16x8 __attribute__((ext_vector_type(8)));
typedef float f32x4 __attribute__((ext_vector_type(4)));

// ============ CSR build (batched over 3 edge types via blockIdx.y) ============

// Phase A: partition into fixed-capacity dst-bucket streams via per-block LDS
// counting sort; linear sBid flush (coalesced), 512 threads for occupancy.
__global__ __launch_bounds__(512) void partition_kernel(
    const int* __restrict__ s0, const int* __restrict__ s1, const int* __restrict__ s2,
    const int* __restrict__ d0, const int* __restrict__ d1, const int* __restrict__ d2,
    int* __restrict__ bc, int* __restrict__ pairs) {
    int y = blockIdx.y;
    const int* src = (y == 0) ? s0 : (y == 1) ? s1 : s2;
    const int* dst = (y == 0) ? d0 : (y == 1) ? d1 : d2;
    int* bcur = bc + y * 256;
    int* pr = pairs + (size_t)y * (NBUCK * CAP);

    __shared__ int sCur[NBUCK];          // counts -> local cursor
    __shared__ int sDelta[NBUCK];        // globalBase - localStart
    __shared__ int sScan[256];
    __shared__ int sSort[PCH];           // bucket-sorted packed pairs (32 KB)
    __shared__ unsigned char sBid[PCH];  // bucket id per slot (8 KB)
    int t = threadIdx.x;
    for (int i = t; i < NBUCK; i += 512) sCur[i] = 0;
    __syncthreads();
    int c0 = blockIdx.x * PCH;
    int cend = min(c0 + PCH, NEDGE);
    int nblk = cend - c0;
    // pass 1: count
    for (int e = c0 + t; e < cend; e += 512)
        atomicAdd(&sCur[dst[e] >> BSH], 1);
    __syncthreads();
    // scan 196 counts (first 256 threads carry data; all hit barriers)
    int v = (t < NBUCK) ? sCur[t] : 0;
    if (t < 256) sScan[t] = v;
    __syncthreads();
    for (int off = 1; off < 256; off <<= 1) {
        int a = (t < 256) ? sScan[t] : 0;
        int b = (t >= off && t < 256) ? sScan[t - off] : 0;
        __syncthreads();
        if (t < 256) sScan[t] = a + b;
        __syncthreads();
    }
    if (t < NBUCK) {
        int excl = sScan[t] - v;
        sCur[t] = excl;           // local cursor
        int gb = v ? atomicAdd(&bcur[t], v) : 0;
        sDelta[t] = gb - excl;
    }
    __syncthreads();
    // pass 2: place into LDS sorted by bucket
    for (int e = c0 + t; e < cend; e += 512) {
        int d = dst[e];
        int b = d >> BSH;
        int slot = atomicAdd(&sCur[b], 1);
        sSort[slot] = ((d & 511) << 17) | src[e];
        sBid[slot] = (unsigned char)b;
    }
    __syncthreads();
    // flush: consecutive slots -> consecutive global within each run
    for (int i = t; i < nblk; i += 512)
        pr[sDelta[sBid[i]] + i] = sSort[i];
}

// Phase B: per-bucket CSR finalize — fully in LDS: load+histogram, scan,
// LDS->LDS cursor scatter, then LINEAR coalesced flush (kills write amp).
__global__ __launch_bounds__(512) void bucket_csr_kernel(const int* __restrict__ bc,
                                                         const int* __restrict__ pairs,
                                                         int2* __restrict__ rowptr2,
                                                         int* __restrict__ ssrc) {
    int y = blockIdx.y;
    pairs += (size_t)y * (NBUCK * CAP);
    rowptr2 += (size_t)y * NNODE;
    ssrc += (size_t)y * (NBUCK * CAP);

    __shared__ int sIn[CAP];    // 36 KB
    __shared__ int sOut[CAP];   // 36 KB
    __shared__ int cnt[512];
    __shared__ int cur[512];
    __shared__ int s1[512];
    int b = blockIdx.x;
    int t = threadIdx.x;
    int node0 = b << BSH;
    int start = b * CAP;
    int end = bc[y * 256 + b];   // final cursor = start + bucket count
    int m = end - start;

    cnt[t] = 0;
    __syncthreads();
    for (int i = t; i < m; i += 512) {
        int p = pairs[start + i];
        sIn[i] = p;
        atomicAdd(&cnt[p >> 17], 1);
    }
    __syncthreads();
    int v = cnt[t];
    s1[t] = v;
    __syncthreads();
    for (int off = 1; off < 512; off <<= 1) {
        int a = s1[t];
        int c = (t >= off) ? s1[t - off] : 0;
        __syncthreads();
        s1[t] = a + c;
        __syncthreads();
    }
    int eb = s1[t] - v;  // local exclusive base
    cur[t] = eb;
    if (node0 + t < NNODE) rowptr2[node0 + t] = make_int2(start + eb, start + eb + v);
    __syncthreads();
    for (int i = t; i < m; i += 512) {
        int p = sIn[i];
        int pos = atomicAdd(&cur[p >> 17], 1);
        sOut[pos] = p & 0x1FFFF;
    }
    __syncthreads();
    for (int i = t; i < m; i += 512)
        ssrc[start + i] = sOut[i];
}

// ============ gather-mean (batched over up to 3 passes via blockIdx.y) ============
// Wave per dst node, eighth-wave per edge; 8 lanes x 16B per 128B fp16 row;
// packed fp16 accumulation (v_pk_add_f16).
__device__ __forceinline__ void gather_body(const __half* __restrict__ x,
                                            const int2* __restrict__ rowptr2,
                                            const int* __restrict__ ssrc,
                                            __half* __restrict__ out) {
    int wid = (blockIdx.x * 256 + threadIdx.x) >> 6;
    int lane = threadIdx.x & 63;
    if (wid >= NNODE) return;
    int ee = lane >> 3;        // edge slot 0..7
    int fo = (lane & 7) << 3;  // feature octet base (8 halves = 16B)
    int2 se = rowptr2[wid];
    int start = se.x, end = se.y;
    int deg = end - start;
    int nfull = deg >> 4;
    __half2 h0 = __float2half2_rn(0.f), h1 = h0, h2 = h0, h3 = h0;
    for (int w = 0; w < nfull; ++w) {
        int e = start + (w << 4) + ee;
        int v0 = ssrc[e], v1 = ssrc[e + 8];
        uint4 r0 = *(const uint4*)(x + ((size_t)v0 << 6) + fo);
        uint4 r1 = *(const uint4*)(x + ((size_t)v1 << 6) + fo);
        h0 = __hadd2(h0, *(__half2*)&r0.x);
        h1 = __hadd2(h1, *(__half2*)&r0.y);
        h2 = __hadd2(h2, *(__half2*)&r0.z);
        h3 = __hadd2(h3, *(__half2*)&r0.w);
        h0 = __hadd2(h0, *(__half2*)&r1.x);
        h1 = __hadd2(h1, *(__half2*)&r1.y);
        h2 = __hadd2(h2, *(__half2*)&r1.z);
        h3 = __hadd2(h3, *(__half2*)&r1.w);
    }
    // predicated tail: window 8, uniform control flow
    __half2 one = __float2half2_rn(1.f), zero = __float2half2_rn(0.f);
    for (int e0 = start + (nfull << 4); e0 < end; e0 += 8) {
        int ea = e0 + ee;
        bool pa = ea < end;
        int ia = pa ? ea : start;
        int va = ssrc[ia];
        uint4 ra = *(const uint4*)(x + ((size_t)va << 6) + fo);
        __half2 hm = pa ? one : zero;
        h0 = __hfma2(hm, *(__half2*)&ra.x, h0);
        h1 = __hfma2(hm, *(__half2*)&ra.y, h1);
        h2 = __hfma2(hm, *(__half2*)&ra.z, h2);
        h3 = __hfma2(hm, *(__half2*)&ra.w, h3);
    }
#define RED8(hh) { \
        int u_ = *(int*)&hh; int r_; \
        r_ = __shfl_xor(u_, 8);  hh = __hadd2(hh, *(__half2*)&r_); u_ = *(int*)&hh; \
        r_ = __shfl_xor(u_, 16); hh = __hadd2(hh, *(__half2*)&r_); u_ = *(int*)&hh; \
        r_ = __shfl_xor(u_, 32); hh = __hadd2(hh, *(__half2*)&r_); }
    RED8(h0) RED8(h1) RED8(h2) RED8(h3)
#undef RED8
    if (ee == 0) {
        float scale = 1.0f / fmaxf((float)deg, 1.0f);
        float2 f0 = __half22float2(h0), f1 = __half22float2(h1);
        float2 f2 = __half22float2(h2), f3 = __half22float2(h3);
        uint4 w;
        *(__half2*)&w.x = __floats2half2_rn(f0.x * scale, f0.y * scale);
        *(__half2*)&w.y = __floats2half2_rn(f1.x * scale, f1.y * scale);
        *(__half2*)&w.z = __floats2half2_rn(f2.x * scale, f2.y * scale);
        *(__half2*)&w.w = __floats2half2_rn(f3.x * scale, f3.y * scale);
        *(uint4*)(out + ((size_t)wid << 6) + fo) = w;
    }
}

__global__ __launch_bounds__(256) void gather3_kernel(
    const __half* __restrict__ x0, const __half* __restrict__ x1, const __half* __restrict__ x2,
    const int2* __restrict__ rp0, const int2* __restrict__ rp1, const int2* __restrict__ rp2,
    const int* __restrict__ ss0, const int* __restrict__ ss1, const int* __restrict__ ss2,
    __half* __restrict__ o0, __half* __restrict__ o1, __half* __restrict__ o2) {
    int y = blockIdx.y;
    if (y == 0) gather_body(x0, rp0, ss0, o0);
    else if (y == 1) gather_body(x1, rp1, ss1, o1);
    else gather_body(x2, rp2, ss2, o2);
}

__global__ __launch_bounds__(256) void gather2_kernel(
    const __half* __restrict__ x0, const __half* __restrict__ x1,
    const int2* __restrict__ rp0, const int2* __restrict__ rp1,
    const int* __restrict__ ss0, const int* __restrict__ ss1,
    __half* __restrict__ o0, __half* __restrict__ o1) {
    int y = blockIdx.y;
    if (y == 0) gather_body(x0, rp0, ss0, o0);
    else gather_body(x1, rp1, ss1, o1);
}

// ============ weight prep: fp16 W^T (+ summed wr/biases) + cursor init ============
__global__ __launch_bounds__(256) void wprep_kernel(
    const float* __restrict__ writes_wl, const float* __restrict__ cites_wl,
    const float* __restrict__ writes_wr, const float* __restrict__ cites_wr,
    const float* __restrict__ wb_wl, const float* __restrict__ wb_wr,
    const float* __restrict__ winA_w, const float* __restrict__ winP_w,
    const float* __restrict__ lin_w,
    const float* __restrict__ writes_bl, const float* __restrict__ cites_bl,
    __half* __restrict__ wtP0, __half* __restrict__ wtP1, __half* __restrict__ wtA,
    __half* __restrict__ wtPJA, __half* __restrict__ wtPJP, __half* __restrict__ wtLIN,
    float* __restrict__ biasP, int* __restrict__ bcur) {
    int i = blockIdx.x * 256 + threadIdx.x;
    if (i < 24576) {                       // paper combine W^T [64][192] x 2 layers
        int l = i / 12288, j = i % 12288;
        int n = j / 192, k = j % 192;
        float v;
        if (k < 64) v = writes_wl[l * 4096 + k * 64 + n];
        else if (k < 128) v = cites_wl[l * 4096 + (k - 64) * 64 + n];
        else v = writes_wr[l * 4096 + (k - 128) * 64 + n] +
                 cites_wr[l * 4096 + (k - 128) * 64 + n];
        (l ? wtP1 : wtP0)[n * 192 + k] = __float2half(v);
    } else if (i < 32768) {                // author combine W^T [64][128], layer 0
        int j = i - 24576;
        int n = j / 128, k = j % 128;
        float v = (k < 64) ? wb_wl[k * 64 + n] : wb_wr[(k - 64) * 64 + n];
        wtA[n * 128 + k] = __float2half(v);
    } else if (i < 36864) {                // proj author W^T [64][64]
        int j = i - 32768;
        wtPJA[j] = __float2half(winA_w[(j % 64) * 64 + j / 64]);
    } else if (i < 40960) {                // proj paper W^T [64][64]
        int j = i - 36864;
        wtPJP[j] = __float2half(winP_w[(j % 64) * 64 + j / 64]);
    } else if (i < 41984) {                // lin W^T [16][64]
        int j = i - 40960;
        wtLIN[j] = __float2half(lin_w[(j % 64) * 16 + j / 64]);
    } else if (i < 42112) {                // summed paper biases, 2 layers
        int j = i - 41984;
        biasP[j] = writes_bl[j] + cites_bl[j];
    } else if (i < 42880) {                // partition cursors: bucket b starts at b*CAP
        int j = i - 42112;
        bcur[j] = (j & 255) * CAP;
    }
}

// ============ MFMA node-GEMMs: wave = 16 nodes, no LDS ============
__device__ inline f16x8 cvt8(const float* p) {
    float4 a = *(const float4*)p, b = *(const float4*)(p + 4);
    f16x8 r;
    r[0] = (_Float16)a.x; r[1] = (_Float16)a.y; r[2] = (_Float16)a.z; r[3] = (_Float16)a.w;
    r[4] = (_Float16)b.x; r[5] = (_Float16)b.y; r[6] = (_Float16)b.z; r[7] = (_Float16)b.w;
    return r;
}

// batched projection: y=0 authors, y=1 papers
__global__ __launch_bounds__(256) void proj_mfma(const float* __restrict__ xd0,
                                                 const float* __restrict__ xc0,
                                                 const float* __restrict__ xd1,
                                                 const float* __restrict__ xc1,
                                                 const __half* __restrict__ wt0,
                                                 const __half* __restrict__ wt1,
                                                 const float* __restrict__ b0,
                                                 const float* __restrict__ b1,
                                                 __half* __restrict__ o0,
                                                 __half* __restrict__ o1) {
    int yb = blockIdx.y;
    const float* xd = yb ? xd1 : xd0;
    const float* xc = yb ? xc1 : xc0;
    const __half* wt = yb ? wt1 : wt0;
    const float* bias = yb ? b1 : b0;
    __half* out = yb ? o1 : o0;
    int wid = (blockIdx.x * 256 + threadIdx.x) >> 6;
    if (wid >= NNODE / 16) return;
    int lane = threadIdx.x & 63;
    int row = lane & 15, kq = lane >> 4;
    int node0 = wid << 4;
    f16x8 af0 = cvt8(xd + (size_t)(node0 + row) * 32 + kq * 8);
    f16x8 af1 = cvt8(xc + (size_t)(node0 + row) * 32 + kq * 8);
#pragma unroll
    for (int nt = 0; nt < 4; ++nt) {
        int col = nt * 16 + row;
        const __half* wp = wt + (size_t)col * 64 + kq * 8;
        f32x4 acc = {0.f, 0.f, 0.f, 0.f};
        acc = __builtin_amdgcn_mfma_f32_16x16x32_f16(af0, *(const f16x8*)(wp), acc, 0, 0, 0);
        acc = __builtin_amdgcn_mfma_f32_16x16x32_f16(af1, *(const f16x8*)(wp + 32), acc, 0, 0, 0);
        float b = bias[col];
#pragma unroll
        for (int r = 0; r < 4; ++r)
            out[((size_t)(node0 + kq * 4 + r) << 6) + col] = __float2half(fmaxf(acc[r] + b, 0.f));
    }
}

template <int NSEG>
__device__ __forceinline__ void combine_body(const __half* __restrict__ a0,
                                             const __half* __restrict__ a1,
                                             const __half* __restrict__ a2,
                                             const __half* __restrict__ wt,
                                             const float* __restrict__ bias,
                                             __half* __restrict__ out) {
    int wid = (blockIdx.x * 256 + threadIdx.x) >> 6;
    if (wid >= NNODE / 16) return;
    int lane = threadIdx.x & 63;
    int row = lane & 15, kq = lane >> 4;
    int node0 = wid << 4;
    const int K = NSEG * 64;
    const __half* as[3] = {a0, a1, a2};
    f16x8 af[2 * NSEG];
#pragma unroll
    for (int s = 0; s < NSEG; ++s) {
        const __half* p = as[s] + ((size_t)(node0 + row) << 6) + kq * 8;
        af[2 * s] = *(const f16x8*)(p);
        af[2 * s + 1] = *(const f16x8*)(p + 32);
    }
#pragma unroll
    for (int nt = 0; nt < 4; ++nt) {
        int col = nt * 16 + row;
        const __half* wp = wt + (size_t)col * K + kq * 8;
        f32x4 acc = {0.f, 0.f, 0.f, 0.f};
#pragma unroll
        for (int t = 0; t < 2 * NSEG; ++t)
            acc = __builtin_amdgcn_mfma_f32_16x16x32_f16(af[t], *(const f16x8*)(wp + t * 32), acc, 0, 0, 0);
        float b = bias[col];
#pragma unroll
        for (int r = 0; r < 4; ++r)
            out[((size_t)(node0 + kq * 4 + r) << 6) + col] = __float2half(acc[r] + b);
    }
}

// L0 dual combine: y=0 papers (3-seg), y=1 authors (2-seg)
__global__ __launch_bounds__(256) void combine_dual(
    const __half* __restrict__ pm0, const __half* __restrict__ pm1, const __half* __restrict__ py,
    const __half* __restrict__ am0, const __half* __restrict__ ay,
    const __half* __restrict__ wtP, const __half* __restrict__ wtA,
    const float* __restrict__ bP, const float* __restrict__ bA,
    __half* __restrict__ oP, __half* __restrict__ oA) {
    if (blockIdx.y == 0) combine_body<3>(pm0, pm1, py, wtP, bP, oP);
    else combine_body<2>(am0, ay, nullptr, wtA, bA, oA);
}

__global__ __launch_bounds__(256) void combine3_kernel(const __half* __restrict__ a0,
                                                       const __half* __restrict__ a1,
                                                       const __half* __restrict__ a2,
                                                       const __half* __restrict__ wt,
                                                       const float* __restrict__ bias,
                                                       __half* __restrict__ out) {
    combine_body<3>(a0, a1, a2, wt, bias, out);
}

__global__ __launch_bounds__(256) void final_mfma(const __half* __restrict__ y,
                                                  const __half* __restrict__ wt,
                                                  const float* __restrict__ bias,
                                                  float* __restrict__ out) {
    int wid = (blockIdx.x * 256 + threadIdx.x) >> 6;
    if (wid >= NNODE / 16) return;
    int lane = threadIdx.x & 63;
    int row = lane & 15, kq = lane >> 4;
    int node0 = wid << 4;
    const __half* p = y + ((size_t)(node0 + row) << 6) + kq * 8;
    f16x8 af0 = *(const f16x8*)(p);
    f16x8 af1 = *(const f16x8*)(p + 32);
    const __half* wp = wt + (size_t)row * 64 + kq * 8;
    f32x4 acc = {0.f, 0.f, 0.f, 0.f};
    acc = __builtin_amdgcn_mfma_f32_16x16x32_f16(af0, *(const f16x8*)(wp), acc, 0, 0, 0);
    acc = __builtin_amdgcn_mfma_f32_16x16x32_f16(af1, *(const f16x8*)(wp + 32), acc, 0, 0, 0);
    float b = bias[row];
#pragma unroll
    for (int r = 0; r < 4; ++r)
        out[(size_t)(node0 + kq * 4 + r) * 16 + row] = acc[r] + b;
}

extern "C" void kernel_launch(void* const* d_in, const int* in_sizes, int n_in,
                              void* d_out, int out_size, void* d_ws, size_t ws_size,
                              hipStream_t stream) {
    (void)in_sizes; (void)n_in; (void)out_size; (void)ws_size;
    const float* xda = (const float*)d_in[0];
    const float* xca = (const float*)d_in[1];
    const float* xdp = (const float*)d_in[2];
    const float* xcp = (const float*)d_in[3];
    const float* winA_w = (const float*)d_in[4];
    const float* winA_b = (const float*)d_in[5];
    const float* winP_w = (const float*)d_in[6];
    const float* winP_b = (const float*)d_in[7];
    const float* writes_wl = (const float*)d_in[8];
    const float* writes_bl = (const float*)d_in[9];
    const float* writes_wr = (const float*)d_in[10];
    const float* wb_wl = (const float*)d_in[11];
    const float* wb_bl = (const float*)d_in[12];
    const float* wb_wr = (const float*)d_in[13];
    const float* cites_wl = (const float*)d_in[14];
    const float* cites_bl = (const float*)d_in[15];
    const float* cites_wr = (const float*)d_in[16];
    const float* lin_w = (const float*)d_in[17];
    const float* lin_b = (const float*)d_in[18];
    const int* w_src = (const int*)d_in[19];
    const int* w_dst = (const int*)d_in[20];
    const int* b_src = (const int*)d_in[21];
    const int* b_dst = (const int*)d_in[22];
    const int* c_src = (const int*)d_in[23];
    const int* c_dst = (const int*)d_in[24];

    const size_t NF = (size_t)NNODE * 64;
    const size_t BUK = (size_t)NBUCK * CAP;   // padded slots per edge type
    __half* B0 = (__half*)d_ws;      // y_a0 -> L1 mean_writes -> y_p2
    __half* B1 = B0 + NF;            // y_p0 -> L1 mean_cites
    __half* B2 = B1 + NF;            // L0 mean_writes -> y_p1
    __half* B3 = B2 + NF;            // L0 mean_cites
    __half* B4 = B3 + NF;            // L0 mean_wb -> y_a1

    __half* wtP0 = B4 + NF;          // 12288
    __half* wtP1 = wtP0 + 12288;     // 12288
    __half* wtA = wtP1 + 12288;      // 8192
    __half* wtPJA = wtA + 8192;      // 4096
    __half* wtPJP = wtPJA + 4096;    // 4096
    __half* wtLIN = wtPJP + 4096;    // 1024
    float* biasP = (float*)(wtLIN + 1024);  // 128

    int* ip = (int*)(biasP + 128);
    int2* rp2 = (int2*)ip;               // 3 * NNODE int2
    int* bcur = (int*)(rp2 + 3 * NNODE); // 3 * 256
    int* ssrc = bcur + 3 * 256;          // 3 * BUK
    int* pairs = (int*)B2;               // CSR-build-only alias (21.7MB < 38.4MB)

    const int GB = (NNODE * 64) / 256;      // 25000 (wave per node)
    const int MB = (NNODE / 16 + 3) / 4;    // 1563 (wave per 16 nodes)
    const int PB = (NEDGE + PCH - 1) / PCH; // 196

    // ---- weight prep (+cursor init) + CSR build ----
    wprep_kernel<<<168, 256, 0, stream>>>(writes_wl, cites_wl, writes_wr, cites_wr,
                                          wb_wl, wb_wr, winA_w, winP_w, lin_w,
                                          writes_bl, cites_bl,
                                          wtP0, wtP1, wtA, wtPJA, wtPJP, wtLIN, biasP, bcur);
    partition_kernel<<<dim3(PB, 3), 512, 0, stream>>>(w_src, c_src, b_src,
                                                      w_dst, c_dst, b_dst, bcur, pairs);
    bucket_csr_kernel<<<dim3(NBUCK, 3), 512, 0, stream>>>(bcur, pairs, rp2, ssrc);

    const int2* rp_w = rp2;
    const int2* rp_c = rp2 + NNODE;
    const int2* rp_b = rp2 + 2 * NNODE;
    const int* ss_w = ssrc;
    const int* ss_c = ssrc + BUK;
    const int* ss_b = ssrc + 2 * BUK;

    // ---- input projections (batched) ----
    proj_mfma<<<dim3(MB, 2), 256, 0, stream>>>(xda, xca, xdp, xcp,
                                               wtPJA, wtPJP, winA_b, winP_b, B0, B1);

    // ---- layer 0: 3 gathers in one dispatch (cites+wb share table B1) ----
    gather3_kernel<<<dim3(GB, 3), 256, 0, stream>>>(B0, B1, B1,
                                                    rp_w, rp_c, rp_b,
                                                    ss_w, ss_c, ss_b,
                                                    B2, B3, B4);
    combine_dual<<<dim3(MB, 2), 256, 0, stream>>>(B2, B3, B1, B4, B0,
                                                  wtP0, wtA, biasP, wb_bl, B2, B4);

    // ---- layer 1 (author update is dead code in the reference: skipped) ----
    gather2_kernel<<<dim3(GB, 2), 256, 0, stream>>>(B4, B2,
                                                    rp_w, rp_c,
                                                    ss_w, ss_c,
                                                    B0, B1);
    combine3_kernel<<<MB, 256, 0, stream>>>(B0, B1, B2, wtP1, biasP + 64, B0);

    // ---- final projection to OUT=16 ----
    final_mfma<<<MB, 256, 0, stream>>>(B0, wtLIN, lin_b, (float*)d_out);
}

// Round 13
// 309.641 us; speedup vs baseline: 23.6063x; 1.0171x over previous
//
#include <hip/hip_runtime.h>
#include <hip/hip_fp16.h>

#define NNODE 100000
#define NEDGE 1600000
#define NBUCK 196      // ceil(100000/512)
#define BSH 9          // 512 nodes per bucket
#define PCH 8192       // edges per partition block
#define CAP 9216       // fixed bucket capacity (mean 8163 + 11.6 sigma)

typedef _Float16 f16x8 __attribute__((ext_vector_type(8)));
typedef float f32x4 __attribute__((ext_vector_type(4)));

// ============ CSR build (batched over 3 edge types via blockIdx.y) ============

// Phase A: partition into fixed-capacity dst-bucket streams via per-block LDS
// counting sort; 4x-replicated count histogram (fewer LDS-atomic conflicts),
// linear sBid flush (coalesced), 512 threads.
__global__ __launch_bounds__(512) void partition_kernel(
    const int* __restrict__ s0, const int* __restrict__ s1, const int* __restrict__ s2,
    const int* __restrict__ d0, const int* __restrict__ d1, const int* __restrict__ d2,
    int* __restrict__ bc, int* __restrict__ pairs) {
    int y = blockIdx.y;
    const int* src = (y == 0) ? s0 : (y == 1) ? s1 : s2;
    const int* dst = (y == 0) ? d0 : (y == 1) ? d1 : d2;
    int* bcur = bc + y * 256;
    int* pr = pairs + (size_t)y * (NBUCK * CAP);

    __shared__ int sCnt4[4][NBUCK];      // replicated count histogram
    __shared__ int sCur[NBUCK];          // local cursor
    __shared__ int sDelta[NBUCK];        // globalBase - localStart
    __shared__ int sScan[256];
    __shared__ int sSort[PCH];           // bucket-sorted packed pairs (32 KB)
    __shared__ unsigned char sBid[PCH];  // bucket id per slot (8 KB)
    int t = threadIdx.x;
    for (int i = t; i < 4 * NBUCK; i += 512) sCnt4[0][i] = 0;
    __syncthreads();
    int c0 = blockIdx.x * PCH;
    int cend = min(c0 + PCH, NEDGE);
    int nblk = cend - c0;
    // pass 1: count (4 replicated copies; group = 2 waves)
    int* myCnt = sCnt4[(t >> 7) & 3];
    for (int e = c0 + t; e < cend; e += 512)
        atomicAdd(&myCnt[dst[e] >> BSH], 1);
    __syncthreads();
    // merge + scan 196 counts (first 256 threads carry data; all hit barriers)
    int v = 0;
    if (t < NBUCK) v = sCnt4[0][t] + sCnt4[1][t] + sCnt4[2][t] + sCnt4[3][t];
    if (t < 256) sScan[t] = v;
    __syncthreads();
    for (int off = 1; off < 256; off <<= 1) {
        int a = (t < 256) ? sScan[t] : 0;
        int b = (t >= off && t < 256) ? sScan[t - off] : 0;
        __syncthreads();
        if (t < 256) sScan[t] = a + b;
        __syncthreads();
    }
    if (t < NBUCK) {
        int excl = sScan[t] - v;
        sCur[t] = excl;           // local cursor
        int gb = v ? atomicAdd(&bcur[t], v) : 0;
        sDelta[t] = gb - excl;
    }
    __syncthreads();
    // pass 2: place into LDS sorted by bucket
    for (int e = c0 + t; e < cend; e += 512) {
        int d = dst[e];
        int b = d >> BSH;
        int slot = atomicAdd(&sCur[b], 1);
        sSort[slot] = ((d & 511) << 17) | src[e];
        sBid[slot] = (unsigned char)b;
    }
    __syncthreads();
    // flush: consecutive slots -> consecutive global within each run
    for (int i = t; i < nblk; i += 512)
        pr[sDelta[sBid[i]] + i] = sSort[i];
}

// Phase B: per-bucket CSR finalize — fully in LDS: load+histogram, scan,
// LDS->LDS cursor scatter, then LINEAR coalesced flush (kills write amp).
__global__ __launch_bounds__(512) void bucket_csr_kernel(const int* __restrict__ bc,
                                                         const int* __restrict__ pairs,
                                                         int2* __restrict__ rowptr2,
                                                         int* __restrict__ ssrc) {
    int y = blockIdx.y;
    pairs += (size_t)y * (NBUCK * CAP);
    rowptr2 += (size_t)y * NNODE;
    ssrc += (size_t)y * (NBUCK * CAP);

    __shared__ int sIn[CAP];    // 36 KB
    __shared__ int sOut[CAP];   // 36 KB
    __shared__ int cnt[512];
    __shared__ int cur[512];
    __shared__ int s1[512];
    int b = blockIdx.x;
    int t = threadIdx.x;
    int node0 = b << BSH;
    int start = b * CAP;
    int end = bc[y * 256 + b];   // final cursor = start + bucket count
    int m = end - start;

    cnt[t] = 0;
    __syncthreads();
    for (int i = t; i < m; i += 512) {
        int p = pairs[start + i];
        sIn[i] = p;
        atomicAdd(&cnt[p >> 17], 1);
    }
    __syncthreads();
    int v = cnt[t];
    s1[t] = v;
    __syncthreads();
    for (int off = 1; off < 512; off <<= 1) {
        int a = s1[t];
        int c = (t >= off) ? s1[t - off] : 0;
        __syncthreads();
        s1[t] = a + c;
        __syncthreads();
    }
    int eb = s1[t] - v;  // local exclusive base
    cur[t] = eb;
    if (node0 + t < NNODE) rowptr2[node0 + t] = make_int2(start + eb, start + eb + v);
    __syncthreads();
    for (int i = t; i < m; i += 512) {
        int p = sIn[i];
        int pos = atomicAdd(&cur[p >> 17], 1);
        sOut[pos] = p & 0x1FFFF;
    }
    __syncthreads();
    for (int i = t; i < m; i += 512)
        ssrc[start + i] = sOut[i];
}

// ============ gather-mean (batched over up to 3 passes via blockIdx.y) ============
// Wave per dst node, eighth-wave per edge; 8 lanes x 16B per 128B fp16 row;
// packed fp16 accumulation; 32-bit offsets (saddr+voffset addressing).
__device__ __forceinline__ void gather_body(const __half* __restrict__ x,
                                            const int2* __restrict__ rowptr2,
                                            const int* __restrict__ ssrc,
                                            __half* __restrict__ out) {
    int wid = (blockIdx.x * 256 + threadIdx.x) >> 6;
    int lane = threadIdx.x & 63;
    if (wid >= NNODE) return;
    int ee = lane >> 3;        // edge slot 0..7
    unsigned fo = (lane & 7) << 3;  // feature octet base (8 halves = 16B)
    int2 se = rowptr2[wid];
    int start = se.x, end = se.y;
    int deg = end - start;
    int nfull = deg >> 4;
    __half2 h0 = __float2half2_rn(0.f), h1 = h0, h2 = h0, h3 = h0;
    for (int w = 0; w < nfull; ++w) {
        int e = start + (w << 4) + ee;
        unsigned v0 = (unsigned)ssrc[e], v1 = (unsigned)ssrc[e + 8];
        uint4 r0 = *(const uint4*)(x + ((v0 << 6) + fo));
        uint4 r1 = *(const uint4*)(x + ((v1 << 6) + fo));
        h0 = __hadd2(h0, *(__half2*)&r0.x);
        h1 = __hadd2(h1, *(__half2*)&r0.y);
        h2 = __hadd2(h2, *(__half2*)&r0.z);
        h3 = __hadd2(h3, *(__half2*)&r0.w);
        h0 = __hadd2(h0, *(__half2*)&r1.x);
        h1 = __hadd2(h1, *(__half2*)&r1.y);
        h2 = __hadd2(h2, *(__half2*)&r1.z);
        h3 = __hadd2(h3, *(__half2*)&r1.w);
    }
    // predicated tail: window 8, uniform control flow
    __half2 one = __float2half2_rn(1.f), zero = __float2half2_rn(0.f);
    for (int e0 = start + (nfull << 4); e0 < end; e0 += 8) {
        int ea = e0 + ee;
        bool pa = ea < end;
        int ia = pa ? ea : start;
        unsigned va = (unsigned)ssrc[ia];
        uint4 ra = *(const uint4*)(x + ((va << 6) + fo));
        __half2 hm = pa ? one : zero;
        h0 = __hfma2(hm, *(__half2*)&ra.x, h0);
        h1 = __hfma2(hm, *(__half2*)&ra.y, h1);
        h2 = __hfma2(hm, *(__half2*)&ra.z, h2);
        h3 = __hfma2(hm, *(__half2*)&ra.w, h3);
    }
#define RED8(hh) { \
        int u_ = *(int*)&hh; int r_; \
        r_ = __shfl_xor(u_, 8);  hh = __hadd2(hh, *(__half2*)&r_); u_ = *(int*)&hh; \
        r_ = __shfl_xor(u_, 16); hh = __hadd2(hh, *(__half2*)&r_); u_ = *(int*)&hh; \
        r_ = __shfl_xor(u_, 32); hh = __hadd2(hh, *(__half2*)&r_); }
    RED8(h0) RED8(h1) RED8(h2) RED8(h3)
#undef RED8
    if (ee == 0) {
        float scale = 1.0f / fmaxf((float)deg, 1.0f);
        float2 f0 = __half22float2(h0), f1 = __half22float2(h1);
        float2 f2 = __half22float2(h2), f3 = __half22float2(h3);
        uint4 w;
        *(__half2*)&w.x = __floats2half2_rn(f0.x * scale, f0.y * scale);
        *(__half2*)&w.y = __floats2half2_rn(f1.x * scale, f1.y * scale);
        *(__half2*)&w.z = __floats2half2_rn(f2.x * scale, f2.y * scale);
        *(__half2*)&w.w = __floats2half2_rn(f3.x * scale, f3.y * scale);
        *(uint4*)(out + (((unsigned)wid << 6) + fo)) = w;
    }
}

__global__ __launch_bounds__(256) void gather3_kernel(
    const __half* __restrict__ x0, const __half* __restrict__ x1, const __half* __restrict__ x2,
    const int2* __restrict__ rp0, const int2* __restrict__ rp1, const int2* __restrict__ rp2,
    const int* __restrict__ ss0, const int* __restrict__ ss1, const int* __restrict__ ss2,
    __half* __restrict__ o0, __half* __restrict__ o1, __half* __restrict__ o2) {
    int y = blockIdx.y;
    if (y == 0) gather_body(x0, rp0, ss0, o0);
    else if (y == 1) gather_body(x1, rp1, ss1, o1);
    else gather_body(x2, rp2, ss2, o2);
}

__global__ __launch_bounds__(256) void gather2_kernel(
    const __half* __restrict__ x0, const __half* __restrict__ x1,
    const int2* __restrict__ rp0, const int2* __restrict__ rp1,
    const int* __restrict__ ss0, const int* __restrict__ ss1,
    __half* __restrict__ o0, __half* __restrict__ o1) {
    int y = blockIdx.y;
    if (y == 0) gather_body(x0, rp0, ss0, o0);
    else gather_body(x1, rp1, ss1, o1);
}

// ============ weight prep: fp16 W^T (+ summed wr/biases) + cursor init ============
__global__ __launch_bounds__(256) void wprep_kernel(
    const float* __restrict__ writes_wl, const float* __restrict__ cites_wl,
    const float* __restrict__ writes_wr, const float* __restrict__ cites_wr,
    const float* __restrict__ wb_wl, const float* __restrict__ wb_wr,
    const float* __restrict__ winA_w, const float* __restrict__ winP_w,
    const float* __restrict__ lin_w,
    const float* __restrict__ writes_bl, const float* __restrict__ cites_bl,
    __half* __restrict__ wtP0, __half* __restrict__ wtP1, __half* __restrict__ wtA,
    __half* __restrict__ wtPJA, __half* __restrict__ wtPJP, __half* __restrict__ wtLIN,
    float* __restrict__ biasP, int* __restrict__ bcur) {
    int i = blockIdx.x * 256 + threadIdx.x;
    if (i < 24576) {                       // paper combine W^T [64][192] x 2 layers
        int l = i / 12288, j = i % 12288;
        int n = j / 192, k = j % 192;
        float v;
        if (k < 64) v = writes_wl[l * 4096 + k * 64 + n];
        else if (k < 128) v = cites_wl[l * 4096 + (k - 64) * 64 + n];
        else v = writes_wr[l * 4096 + (k - 128) * 64 + n] +
                 cites_wr[l * 4096 + (k - 128) * 64 + n];
        (l ? wtP1 : wtP0)[n * 192 + k] = __float2half(v);
    } else if (i < 32768) {                // author combine W^T [64][128], layer 0
        int j = i - 24576;
        int n = j / 128, k = j % 128;
        float v = (k < 64) ? wb_wl[k * 64 + n] : wb_wr[(k - 64) * 64 + n];
        wtA[n * 128 + k] = __float2half(v);
    } else if (i < 36864) {                // proj author W^T [64][64]
        int j = i - 32768;
        wtPJA[j] = __float2half(winA_w[(j % 64) * 64 + j / 64]);
    } else if (i < 40960) {                // proj paper W^T [64][64]
        int j = i - 36864;
        wtPJP[j] = __float2half(winP_w[(j % 64) * 64 + j / 64]);
    } else if (i < 41984) {                // lin W^T [16][64]
        int j = i - 40960;
        wtLIN[j] = __float2half(lin_w[(j % 64) * 16 + j / 64]);
    } else if (i < 42112) {                // summed paper biases, 2 layers
        int j = i - 41984;
        biasP[j] = writes_bl[j] + cites_bl[j];
    } else if (i < 42880) {                // partition cursors: bucket b starts at b*CAP
        int j = i - 42112;
        bcur[j] = (j & 255) * CAP;
    }
}

// ============ MFMA node-GEMMs: wave = 16 nodes, no LDS ============
__device__ inline f16x8 cvt8(const float* p) {
    float4 a = *(const float4*)p, b = *(const float4*)(p + 4);
    f16x8 r;
    r[0] = (_Float16)a.x; r[1] = (_Float16)a.y; r[2] = (_Float16)a.z; r[3] = (_Float16)a.w;
    r[4] = (_Float16)b.x; r[5] = (_Float16)b.y; r[6] = (_Float16)b.z; r[7] = (_Float16)b.w;
    return r;
}

// batched projection: y=0 authors, y=1 papers
__global__ __launch_bounds__(256) void proj_mfma(const float* __restrict__ xd0,
                                                 const float* __restrict__ xc0,
                                                 const float* __restrict__ xd1,
                                                 const float* __restrict__ xc1,
                                                 const __half* __restrict__ wt0,
                                                 const __half* __restrict__ wt1,
                                                 const float* __restrict__ b0,
                                                 const float* __restrict__ b1,
                                                 __half* __restrict__ o0,
                                                 __half* __restrict__ o1) {
    int yb = blockIdx.y;
    const float* xd = yb ? xd1 : xd0;
    const float* xc = yb ? xc1 : xc0;
    const __half* wt = yb ? wt1 : wt0;
    const float* bias = yb ? b1 : b0;
    __half* out = yb ? o1 : o0;
    int wid = (blockIdx.x * 256 + threadIdx.x) >> 6;
    if (wid >= NNODE / 16) return;
    int lane = threadIdx.x & 63;
    int row = lane & 15, kq = lane >> 4;
    int node0 = wid << 4;
    f16x8 af0 = cvt8(xd + (size_t)(node0 + row) * 32 + kq * 8);
    f16x8 af1 = cvt8(xc + (size_t)(node0 + row) * 32 + kq * 8);
#pragma unroll
    for (int nt = 0; nt < 4; ++nt) {
        int col = nt * 16 + row;
        const __half* wp = wt + (size_t)col * 64 + kq * 8;
        f32x4 acc = {0.f, 0.f, 0.f, 0.f};
        acc = __builtin_amdgcn_mfma_f32_16x16x32_f16(af0, *(const f16x8*)(wp), acc, 0, 0, 0);
        acc = __builtin_amdgcn_mfma_f32_16x16x32_f16(af1, *(const f16x8*)(wp + 32), acc, 0, 0, 0);
        float b = bias[col];
#pragma unroll
        for (int r = 0; r < 4; ++r)
            out[((size_t)(node0 + kq * 4 + r) << 6) + col] = __float2half(fmaxf(acc[r] + b, 0.f));
    }
}

template <int NSEG>
__device__ __forceinline__ void combine_body(const __half* __restrict__ a0,
                                             const __half* __restrict__ a1,
                                             const __half* __restrict__ a2,
                                             const __half* __restrict__ wt,
                                             const float* __restrict__ bias,
                                             __half* __restrict__ out) {
    int wid = (blockIdx.x * 256 + threadIdx.x) >> 6;
    if (wid >= NNODE / 16) return;
    int lane = threadIdx.x & 63;
    int row = lane & 15, kq = lane >> 4;
    int node0 = wid << 4;
    const int K = NSEG * 64;
    const __half* as[3] = {a0, a1, a2};
    f16x8 af[2 * NSEG];
#pragma unroll
    for (int s = 0; s < NSEG; ++s) {
        const __half* p = as[s] + ((size_t)(node0 + row) << 6) + kq * 8;
        af[2 * s] = *(const f16x8*)(p);
        af[2 * s + 1] = *(const f16x8*)(p + 32);
    }
#pragma unroll
    for (int nt = 0; nt < 4; ++nt) {
        int col = nt * 16 + row;
        const __half* wp = wt + (size_t)col * K + kq * 8;
        f32x4 acc = {0.f, 0.f, 0.f, 0.f};
#pragma unroll
        for (int t = 0; t < 2 * NSEG; ++t)
            acc = __builtin_amdgcn_mfma_f32_16x16x32_f16(af[t], *(const f16x8*)(wp + t * 32), acc, 0, 0, 0);
        float b = bias[col];
#pragma unroll
        for (int r = 0; r < 4; ++r)
            out[((size_t)(node0 + kq * 4 + r) << 6) + col] = __float2half(acc[r] + b);
    }
}

// L0 dual combine: y=0 papers (3-seg), y=1 authors (2-seg)
__global__ __launch_bounds__(256) void combine_dual(
    const __half* __restrict__ pm0, const __half* __restrict__ pm1, const __half* __restrict__ py,
    const __half* __restrict__ am0, const __half* __restrict__ ay,
    const __half* __restrict__ wtP, const __half* __restrict__ wtA,
    const float* __restrict__ bP, const float* __restrict__ bA,
    __half* __restrict__ oP, __half* __restrict__ oA) {
    if (blockIdx.y == 0) combine_body<3>(pm0, pm1, py, wtP, bP, oP);
    else combine_body<2>(am0, ay, nullptr, wtA, bA, oA);
}

// L1 combine fused with final projection: y_p2 tile staged in per-wave LDS,
// re-read as A-fragments, 2 MFMAs with lin W^T -> d_out fp32 directly.
__global__ __launch_bounds__(256) void combine3_final_kernel(
    const __half* __restrict__ a0, const __half* __restrict__ a1, const __half* __restrict__ a2,
    const __half* __restrict__ wt, const float* __restrict__ bias,
    const __half* __restrict__ wtLIN, const float* __restrict__ linb,
    float* __restrict__ out) {
    __shared__ __half sTile[4][16][64];   // per-wave y_p2 tile (8 KB)
    int wid = (blockIdx.x * 256 + threadIdx.x) >> 6;
    if (wid >= NNODE / 16) return;
    int wv = (threadIdx.x >> 6) & 3;
    int lane = threadIdx.x & 63;
    int row = lane & 15, kq = lane >> 4;
    int node0 = wid << 4;
    const __half* as[3] = {a0, a1, a2};
    f16x8 af[6];
#pragma unroll
    for (int s = 0; s < 3; ++s) {
        const __half* p = as[s] + ((size_t)(node0 + row) << 6) + kq * 8;
        af[2 * s] = *(const f16x8*)(p);
        af[2 * s + 1] = *(const f16x8*)(p + 32);
    }
#pragma unroll
    for (int nt = 0; nt < 4; ++nt) {
        int col = nt * 16 + row;
        const __half* wp = wt + (size_t)col * 192 + kq * 8;
        f32x4 acc = {0.f, 0.f, 0.f, 0.f};
#pragma unroll
        for (int t = 0; t < 6; ++t)
            acc = __builtin_amdgcn_mfma_f32_16x16x32_f16(af[t], *(const f16x8*)(wp + t * 32), acc, 0, 0, 0);
        float b = bias[col];
#pragma unroll
        for (int r = 0; r < 4; ++r)
            sTile[wv][kq * 4 + r][col] = __float2half(acc[r] + b);
    }
    // re-read own tile as A-fragments (wave-local LDS dependency)
    f16x8 y0 = *(const f16x8*)(&sTile[wv][row][kq * 8]);
    f16x8 y1 = *(const f16x8*)(&sTile[wv][row][kq * 8 + 32]);
    const __half* wl = wtLIN + (size_t)row * 64 + kq * 8;
    f32x4 acc = {0.f, 0.f, 0.f, 0.f};
    acc = __builtin_amdgcn_mfma_f32_16x16x32_f16(y0, *(const f16x8*)(wl), acc, 0, 0, 0);
    acc = __builtin_amdgcn_mfma_f32_16x16x32_f16(y1, *(const f16x8*)(wl + 32), acc, 0, 0, 0);
    float b = linb[row];
#pragma unroll
    for (int r = 0; r < 4; ++r)
        out[(size_t)(node0 + kq * 4 + r) * 16 + row] = acc[r] + b;
}

extern "C" void kernel_launch(void* const* d_in, const int* in_sizes, int n_in,
                              void* d_out, int out_size, void* d_ws, size_t ws_size,
                              hipStream_t stream) {
    (void)in_sizes; (void)n_in; (void)out_size; (void)ws_size;
    const float* xda = (const float*)d_in[0];
    const float* xca = (const float*)d_in[1];
    const float* xdp = (const float*)d_in[2];
    const float* xcp = (const float*)d_in[3];
    const float* winA_w = (const float*)d_in[4];
    const float* winA_b = (const float*)d_in[5];
    const float* winP_w = (const float*)d_in[6];
    const float* winP_b = (const float*)d_in[7];
    const float* writes_wl = (const float*)d_in[8];
    const float* writes_bl = (const float*)d_in[9];
    const float* writes_wr = (const float*)d_in[10];
    const float* wb_wl = (const float*)d_in[11];
    const float* wb_bl = (const float*)d_in[12];
    const float* wb_wr = (const float*)d_in[13];
    const float* cites_wl = (const float*)d_in[14];
    const float* cites_bl = (const float*)d_in[15];
    const float* cites_wr = (const float*)d_in[16];
    const float* lin_w = (const float*)d_in[17];
    const float* lin_b = (const float*)d_in[18];
    const int* w_src = (const int*)d_in[19];
    const int* w_dst = (const int*)d_in[20];
    const int* b_src = (const int*)d_in[21];
    const int* b_dst = (const int*)d_in[22];
    const int* c_src = (const int*)d_in[23];
    const int* c_dst = (const int*)d_in[24];

    const size_t NF = (size_t)NNODE * 64;
    const size_t BUK = (size_t)NBUCK * CAP;   // padded slots per edge type
    __half* B0 = (__half*)d_ws;      // y_a0 -> L1 mean_writes -> y_p2
    __half* B1 = B0 + NF;            // y_p0 -> L1 mean_cites
    __half* B2 = B1 + NF;            // L0 mean_writes -> y_p1
    __half* B3 = B2 + NF;            // L0 mean_cites
    __half* B4 = B3 + NF;            // L0 mean_wb -> y_a1

    __half* wtP0 = B4 + NF;          // 12288
    __half* wtP1 = wtP0 + 12288;     // 12288
    __half* wtA = wtP1 + 12288;      // 8192
    __half* wtPJA = wtA + 8192;      // 4096
    __half* wtPJP = wtPJA + 4096;    // 4096
    __half* wtLIN = wtPJP + 4096;    // 1024
    float* biasP = (float*)(wtLIN + 1024);  // 128

    int* ip = (int*)(biasP + 128);
    int2* rp2 = (int2*)ip;               // 3 * NNODE int2
    int* bcur = (int*)(rp2 + 3 * NNODE); // 3 * 256
    int* ssrc = bcur + 3 * 256;          // 3 * BUK
    int* pairs = (int*)B2;               // CSR-build-only alias (21.7MB < 38.4MB)

    const int GB = (NNODE * 64) / 256;      // 25000 (wave per node)
    const int MB = (NNODE / 16 + 3) / 4;    // 1563 (wave per 16 nodes)
    const int PB = (NEDGE + PCH - 1) / PCH; // 196

    // ---- weight prep (+cursor init) + CSR build ----
    wprep_kernel<<<168, 256, 0, stream>>>(writes_wl, cites_wl, writes_wr, cites_wr,
                                          wb_wl, wb_wr, winA_w, winP_w, lin_w,
                                          writes_bl, cites_bl,
                                          wtP0, wtP1, wtA, wtPJA, wtPJP, wtLIN, biasP, bcur);
    partition_kernel<<<dim3(PB, 3), 512, 0, stream>>>(w_src, c_src, b_src,
                                                      w_dst, c_dst, b_dst, bcur, pairs);
    bucket_csr_kernel<<<dim3(NBUCK, 3), 512, 0, stream>>>(bcur, pairs, rp2, ssrc);

    const int2* rp_w = rp2;
    const int2* rp_c = rp2 + NNODE;
    const int2* rp_b = rp2 + 2 * NNODE;
    const int* ss_w = ssrc;
    const int* ss_c = ssrc + BUK;
    const int* ss_b = ssrc + 2 * BUK;

    // ---- input projections (batched) ----
    proj_mfma<<<dim3(MB, 2), 256, 0, stream>>>(xda, xca, xdp, xcp,
                                               wtPJA, wtPJP, winA_b, winP_b, B0, B1);

    // ---- layer 0: 3 gathers in one dispatch (cites+wb share table B1) ----
    gather3_kernel<<<dim3(GB, 3), 256, 0, stream>>>(B0, B1, B1,
                                                    rp_w, rp_c, rp_b,
                                                    ss_w, ss_c, ss_b,
                                                    B2, B3, B4);
    combine_dual<<<dim3(MB, 2), 256, 0, stream>>>(B2, B3, B1, B4, B0,
                                                  wtP0, wtA, biasP, wb_bl, B2, B4);

    // ---- layer 1 (author update is dead code in the reference: skipped) ----
    gather2_kernel<<<dim3(GB, 2), 256, 0, stream>>>(B4, B2,
                                                    rp_w, rp_c,
                                                    ss_w, ss_c,
                                                    B0, B1);
    // L1 combine + final projection fused -> d_out
    combine3_final_kernel<<<MB, 256, 0, stream>>>(B0, B1, B2, wtP1, biasP + 64,
                                                  wtLIN, lin_b, (float*)d_out);
}

// Round 14
// 288.721 us; speedup vs baseline: 25.3166x; 1.0725x over previous
//
#include <hip/hip_runtime.h>
#include <hip/hip_fp16.h>

#define NNODE 100000
#define NEDGE 1600000
#define NBUCK 196      // ceil(100000/512)
#define BSH 9          // 512 nodes per bucket
#define PCH 8192       // edges per partition block
#define CAP 9216       // fixed bucket capacity (mean 8163 + 11.6 sigma)

typedef _Float16 f16x8 __attribute__((ext_vector_type(8)));
typedef float f32x4 __attribute__((ext_vector_type(4)));

// ============ CSR build (batched over 3 edge types via blockIdx.y) ============

// Phase A: partition into fixed-capacity dst-bucket streams via per-block LDS
// counting sort; 4x-replicated count histogram, linear sBid flush, 512 threads.
__global__ __launch_bounds__(512) void partition_kernel(
    const int* __restrict__ s0, const int* __restrict__ s1, const int* __restrict__ s2,
    const int* __restrict__ d0, const int* __restrict__ d1, const int* __restrict__ d2,
    int* __restrict__ bc, int* __restrict__ pairs) {
    int y = blockIdx.y;
    const int* src = (y == 0) ? s0 : (y == 1) ? s1 : s2;
    const int* dst = (y == 0) ? d0 : (y == 1) ? d1 : d2;
    int* bcur = bc + y * 256;
    int* pr = pairs + (size_t)y * (NBUCK * CAP);

    __shared__ int sCnt4[4][NBUCK];      // replicated count histogram
    __shared__ int sCur[NBUCK];          // local cursor
    __shared__ int sDelta[NBUCK];        // globalBase - localStart
    __shared__ int sScan[256];
    __shared__ int sSort[PCH];           // bucket-sorted packed pairs (32 KB)
    __shared__ unsigned char sBid[PCH];  // bucket id per slot (8 KB)
    int t = threadIdx.x;
    for (int i = t; i < 4 * NBUCK; i += 512) sCnt4[0][i] = 0;
    __syncthreads();
    int c0 = blockIdx.x * PCH;
    int cend = min(c0 + PCH, NEDGE);
    int nblk = cend - c0;
    // pass 1: count (4 replicated copies; group = 2 waves)
    int* myCnt = sCnt4[(t >> 7) & 3];
    for (int e = c0 + t; e < cend; e += 512)
        atomicAdd(&myCnt[dst[e] >> BSH], 1);
    __syncthreads();
    // merge + scan 196 counts
    int v = 0;
    if (t < NBUCK) v = sCnt4[0][t] + sCnt4[1][t] + sCnt4[2][t] + sCnt4[3][t];
    if (t < 256) sScan[t] = v;
    __syncthreads();
    for (int off = 1; off < 256; off <<= 1) {
        int a = (t < 256) ? sScan[t] : 0;
        int b = (t >= off && t < 256) ? sScan[t - off] : 0;
        __syncthreads();
        if (t < 256) sScan[t] = a + b;
        __syncthreads();
    }
    if (t < NBUCK) {
        int excl = sScan[t] - v;
        sCur[t] = excl;           // local cursor
        int gb = v ? atomicAdd(&bcur[t], v) : 0;
        sDelta[t] = gb - excl;
    }
    __syncthreads();
    // pass 2: place into LDS sorted by bucket
    for (int e = c0 + t; e < cend; e += 512) {
        int d = dst[e];
        int b = d >> BSH;
        int slot = atomicAdd(&sCur[b], 1);
        sSort[slot] = ((d & 511) << 17) | src[e];
        sBid[slot] = (unsigned char)b;
    }
    __syncthreads();
    // flush: consecutive slots -> consecutive global within each run
    for (int i = t; i < nblk; i += 512)
        pr[sDelta[sBid[i]] + i] = sSort[i];
}

// Phase B: per-bucket CSR finalize — fully in LDS: load+histogram, scan,
// LDS->LDS cursor scatter, then LINEAR coalesced flush.
__global__ __launch_bounds__(512) void bucket_csr_kernel(const int* __restrict__ bc,
                                                         const int* __restrict__ pairs,
                                                         int2* __restrict__ rowptr2,
                                                         int* __restrict__ ssrc) {
    int y = blockIdx.y;
    pairs += (size_t)y * (NBUCK * CAP);
    rowptr2 += (size_t)y * NNODE;
    ssrc += (size_t)y * (NBUCK * CAP);

    __shared__ int sIn[CAP];    // 36 KB
    __shared__ int sOut[CAP];   // 36 KB
    __shared__ int cnt[512];
    __shared__ int cur[512];
    __shared__ int s1[512];
    int b = blockIdx.x;
    int t = threadIdx.x;
    int node0 = b << BSH;
    int start = b * CAP;
    int end = bc[y * 256 + b];   // final cursor = start + bucket count
    int m = end - start;

    cnt[t] = 0;
    __syncthreads();
    for (int i = t; i < m; i += 512) {
        int p = pairs[start + i];
        sIn[i] = p;
        atomicAdd(&cnt[p >> 17], 1);
    }
    __syncthreads();
    int v = cnt[t];
    s1[t] = v;
    __syncthreads();
    for (int off = 1; off < 512; off <<= 1) {
        int a = s1[t];
        int c = (t >= off) ? s1[t - off] : 0;
        __syncthreads();
        s1[t] = a + c;
        __syncthreads();
    }
    int eb = s1[t] - v;  // local exclusive base
    cur[t] = eb;
    if (node0 + t < NNODE) rowptr2[node0 + t] = make_int2(start + eb, start + eb + v);
    __syncthreads();
    for (int i = t; i < m; i += 512) {
        int p = sIn[i];
        int pos = atomicAdd(&cur[p >> 17], 1);
        sOut[pos] = p & 0x1FFFF;
    }
    __syncthreads();
    for (int i = t; i < m; i += 512)
        ssrc[start + i] = sOut[i];
}

// ============ gather-mean (batched over up to 3 passes via blockIdx.y) ============
// Wave per dst node, eighth-wave per edge; lane-resident ssrc + shuffle broadcast
// (no redundant index loads); 32-edge superwindows, 4 row loads in flight,
// fully mask-predicated; packed fp16 accumulation.
__device__ __forceinline__ void gather_body(const __half* __restrict__ x,
                                            const int2* __restrict__ rowptr2,
                                            const int* __restrict__ ssrc,
                                            __half* __restrict__ out) {
    int wid = (blockIdx.x * 256 + threadIdx.x) >> 6;
    int lane = threadIdx.x & 63;
    if (wid >= NNODE) return;
    int ee = lane >> 3;             // edge slot 0..7
    unsigned fo = (lane & 7) << 3;  // feature octet base (8 halves = 16B)
    int2 se = rowptr2[wid];
    int start = se.x;
    int deg = se.y - se.x;
    __half2 h0 = __float2half2_rn(0.f), h1 = h0, h2 = h0, h3 = h0;
    __half2 one = __float2half2_rn(1.f), zero = __float2half2_rn(0.f);
    for (int base = 0; base < deg; base += 64) {
        int rem = min(deg - base, 64);
        int sv = (lane < rem) ? ssrc[start + base + lane] : 0;
        int nsw = (rem + 31) >> 5;   // 32-edge superwindows
        for (int w = 0; w < nsw; ++w) {
            int i0 = (w << 5) + ee;
            int i1 = i0 + 8, i2 = i0 + 16, i3 = i0 + 24;
            unsigned v0 = (unsigned)__shfl(sv, i0);
            unsigned v1 = (unsigned)__shfl(sv, i1);
            unsigned v2 = (unsigned)__shfl(sv, i2);
            unsigned v3 = (unsigned)__shfl(sv, i3);
            __half2 m0 = (i0 < rem) ? one : zero;
            __half2 m1 = (i1 < rem) ? one : zero;
            __half2 m2 = (i2 < rem) ? one : zero;
            __half2 m3 = (i3 < rem) ? one : zero;
            uint4 r0 = *(const uint4*)(x + ((v0 << 6) + fo));
            uint4 r1 = *(const uint4*)(x + ((v1 << 6) + fo));
            uint4 r2 = *(const uint4*)(x + ((v2 << 6) + fo));
            uint4 r3 = *(const uint4*)(x + ((v3 << 6) + fo));
            h0 = __hfma2(m0, *(__half2*)&r0.x, h0);
            h1 = __hfma2(m0, *(__half2*)&r0.y, h1);
            h2 = __hfma2(m0, *(__half2*)&r0.z, h2);
            h3 = __hfma2(m0, *(__half2*)&r0.w, h3);
            h0 = __hfma2(m1, *(__half2*)&r1.x, h0);
            h1 = __hfma2(m1, *(__half2*)&r1.y, h1);
            h2 = __hfma2(m1, *(__half2*)&r1.z, h2);
            h3 = __hfma2(m1, *(__half2*)&r1.w, h3);
            h0 = __hfma2(m2, *(__half2*)&r2.x, h0);
            h1 = __hfma2(m2, *(__half2*)&r2.y, h1);
            h2 = __hfma2(m2, *(__half2*)&r2.z, h2);
            h3 = __hfma2(m2, *(__half2*)&r2.w, h3);
            h0 = __hfma2(m3, *(__half2*)&r3.x, h0);
            h1 = __hfma2(m3, *(__half2*)&r3.y, h1);
            h2 = __hfma2(m3, *(__half2*)&r3.z, h2);
            h3 = __hfma2(m3, *(__half2*)&r3.w, h3);
        }
    }
#define RED8(hh) { \
        int u_ = *(int*)&hh; int r_; \
        r_ = __shfl_xor(u_, 8);  hh = __hadd2(hh, *(__half2*)&r_); u_ = *(int*)&hh; \
        r_ = __shfl_xor(u_, 16); hh = __hadd2(hh, *(__half2*)&r_); u_ = *(int*)&hh; \
        r_ = __shfl_xor(u_, 32); hh = __hadd2(hh, *(__half2*)&r_); }
    RED8(h0) RED8(h1) RED8(h2) RED8(h3)
#undef RED8
    if (ee == 0) {
        float scale = 1.0f / fmaxf((float)deg, 1.0f);
        float2 f0 = __half22float2(h0), f1 = __half22float2(h1);
        float2 f2 = __half22float2(h2), f3 = __half22float2(h3);
        uint4 w;
        *(__half2*)&w.x = __floats2half2_rn(f0.x * scale, f0.y * scale);
        *(__half2*)&w.y = __floats2half2_rn(f1.x * scale, f1.y * scale);
        *(__half2*)&w.z = __floats2half2_rn(f2.x * scale, f2.y * scale);
        *(__half2*)&w.w = __floats2half2_rn(f3.x * scale, f3.y * scale);
        *(uint4*)(out + (((unsigned)wid << 6) + fo)) = w;
    }
}

__global__ __launch_bounds__(256) void gather3_kernel(
    const __half* __restrict__ x0, const __half* __restrict__ x1, const __half* __restrict__ x2,
    const int2* __restrict__ rp0, const int2* __restrict__ rp1, const int2* __restrict__ rp2,
    const int* __restrict__ ss0, const int* __restrict__ ss1, const int* __restrict__ ss2,
    __half* __restrict__ o0, __half* __restrict__ o1, __half* __restrict__ o2) {
    int y = blockIdx.y;
    if (y == 0) gather_body(x0, rp0, ss0, o0);
    else if (y == 1) gather_body(x1, rp1, ss1, o1);
    else gather_body(x2, rp2, ss2, o2);
}

__global__ __launch_bounds__(256) void gather2_kernel(
    const __half* __restrict__ x0, const __half* __restrict__ x1,
    const int2* __restrict__ rp0, const int2* __restrict__ rp1,
    const int* __restrict__ ss0, const int* __restrict__ ss1,
    __half* __restrict__ o0, __half* __restrict__ o1) {
    int y = blockIdx.y;
    if (y == 0) gather_body(x0, rp0, ss0, o0);
    else gather_body(x1, rp1, ss1, o1);
}

// ============ weight prep: fp16 W^T (+ summed wr/biases) + cursor init ============
__global__ __launch_bounds__(256) void wprep_kernel(
    const float* __restrict__ writes_wl, const float* __restrict__ cites_wl,
    const float* __restrict__ writes_wr, const float* __restrict__ cites_wr,
    const float* __restrict__ wb_wl, const float* __restrict__ wb_wr,
    const float* __restrict__ winA_w, const float* __restrict__ winP_w,
    const float* __restrict__ lin_w,
    const float* __restrict__ writes_bl, const float* __restrict__ cites_bl,
    __half* __restrict__ wtP0, __half* __restrict__ wtP1, __half* __restrict__ wtA,
    __half* __restrict__ wtPJA, __half* __restrict__ wtPJP, __half* __restrict__ wtLIN,
    float* __restrict__ biasP, int* __restrict__ bcur) {
    int i = blockIdx.x * 256 + threadIdx.x;
    if (i < 24576) {                       // paper combine W^T [64][192] x 2 layers
        int l = i / 12288, j = i % 12288;
        int n = j / 192, k = j % 192;
        float v;
        if (k < 64) v = writes_wl[l * 4096 + k * 64 + n];
        else if (k < 128) v = cites_wl[l * 4096 + (k - 64) * 64 + n];
        else v = writes_wr[l * 4096 + (k - 128) * 64 + n] +
                 cites_wr[l * 4096 + (k - 128) * 64 + n];
        (l ? wtP1 : wtP0)[n * 192 + k] = __float2half(v);
    } else if (i < 32768) {                // author combine W^T [64][128], layer 0
        int j = i - 24576;
        int n = j / 128, k = j % 128;
        float v = (k < 64) ? wb_wl[k * 64 + n] : wb_wr[(k - 64) * 64 + n];
        wtA[n * 128 + k] = __float2half(v);
    } else if (i < 36864) {                // proj author W^T [64][64]
        int j = i - 32768;
        wtPJA[j] = __float2half(winA_w[(j % 64) * 64 + j / 64]);
    } else if (i < 40960) {                // proj paper W^T [64][64]
        int j = i - 36864;
        wtPJP[j] = __float2half(winP_w[(j % 64) * 64 + j / 64]);
    } else if (i < 41984) {                // lin W^T [16][64]
        int j = i - 40960;
        wtLIN[j] = __float2half(lin_w[(j % 64) * 16 + j / 64]);
    } else if (i < 42112) {                // summed paper biases, 2 layers
        int j = i - 41984;
        biasP[j] = writes_bl[j] + cites_bl[j];
    } else if (i < 42880) {                // partition cursors: bucket b starts at b*CAP
        int j = i - 42112;
        bcur[j] = (j & 255) * CAP;
    }
}

// ============ MFMA node-GEMMs: wave = 16 nodes, no LDS ============
__device__ inline f16x8 cvt8(const float* p) {
    float4 a = *(const float4*)p, b = *(const float4*)(p + 4);
    f16x8 r;
    r[0] = (_Float16)a.x; r[1] = (_Float16)a.y; r[2] = (_Float16)a.z; r[3] = (_Float16)a.w;
    r[4] = (_Float16)b.x; r[5] = (_Float16)b.y; r[6] = (_Float16)b.z; r[7] = (_Float16)b.w;
    return r;
}

// batched projection: y=0 authors, y=1 papers
__global__ __launch_bounds__(256) void proj_mfma(const float* __restrict__ xd0,
                                                 const float* __restrict__ xc0,
                                                 const float* __restrict__ xd1,
                                                 const float* __restrict__ xc1,
                                                 const __half* __restrict__ wt0,
                                                 const __half* __restrict__ wt1,
                                                 const float* __restrict__ b0,
                                                 const float* __restrict__ b1,
                                                 __half* __restrict__ o0,
                                                 __half* __restrict__ o1) {
    int yb = blockIdx.y;
    const float* xd = yb ? xd1 : xd0;
    const float* xc = yb ? xc1 : xc0;
    const __half* wt = yb ? wt1 : wt0;
    const float* bias = yb ? b1 : b0;
    __half* out = yb ? o1 : o0;
    int wid = (blockIdx.x * 256 + threadIdx.x) >> 6;
    if (wid >= NNODE / 16) return;
    int lane = threadIdx.x & 63;
    int row = lane & 15, kq = lane >> 4;
    int node0 = wid << 4;
    f16x8 af0 = cvt8(xd + (size_t)(node0 + row) * 32 + kq * 8);
    f16x8 af1 = cvt8(xc + (size_t)(node0 + row) * 32 + kq * 8);
#pragma unroll
    for (int nt = 0; nt < 4; ++nt) {
        int col = nt * 16 + row;
        const __half* wp = wt + (size_t)col * 64 + kq * 8;
        f32x4 acc = {0.f, 0.f, 0.f, 0.f};
        acc = __builtin_amdgcn_mfma_f32_16x16x32_f16(af0, *(const f16x8*)(wp), acc, 0, 0, 0);
        acc = __builtin_amdgcn_mfma_f32_16x16x32_f16(af1, *(const f16x8*)(wp + 32), acc, 0, 0, 0);
        float b = bias[col];
#pragma unroll
        for (int r = 0; r < 4; ++r)
            out[((size_t)(node0 + kq * 4 + r) << 6) + col] = __float2half(fmaxf(acc[r] + b, 0.f));
    }
}

template <int NSEG>
__device__ __forceinline__ void combine_body(const __half* __restrict__ a0,
                                             const __half* __restrict__ a1,
                                             const __half* __restrict__ a2,
                                             const __half* __restrict__ wt,
                                             const float* __restrict__ bias,
                                             __half* __restrict__ out) {
    int wid = (blockIdx.x * 256 + threadIdx.x) >> 6;
    if (wid >= NNODE / 16) return;
    int lane = threadIdx.x & 63;
    int row = lane & 15, kq = lane >> 4;
    int node0 = wid << 4;
    const int K = NSEG * 64;
    const __half* as[3] = {a0, a1, a2};
    f16x8 af[2 * NSEG];
#pragma unroll
    for (int s = 0; s < NSEG; ++s) {
        const __half* p = as[s] + ((size_t)(node0 + row) << 6) + kq * 8;
        af[2 * s] = *(const f16x8*)(p);
        af[2 * s + 1] = *(const f16x8*)(p + 32);
    }
#pragma unroll
    for (int nt = 0; nt < 4; ++nt) {
        int col = nt * 16 + row;
        const __half* wp = wt + (size_t)col * K + kq * 8;
        f32x4 acc = {0.f, 0.f, 0.f, 0.f};
#pragma unroll
        for (int t = 0; t < 2 * NSEG; ++t)
            acc = __builtin_amdgcn_mfma_f32_16x16x32_f16(af[t], *(const f16x8*)(wp + t * 32), acc, 0, 0, 0);
        float b = bias[col];
#pragma unroll
        for (int r = 0; r < 4; ++r)
            out[((size_t)(node0 + kq * 4 + r) << 6) + col] = __float2half(acc[r] + b);
    }
}

// L0 dual combine: y=0 papers (3-seg), y=1 authors (2-seg)
__global__ __launch_bounds__(256) void combine_dual(
    const __half* __restrict__ pm0, const __half* __restrict__ pm1, const __half* __restrict__ py,
    const __half* __restrict__ am0, const __half* __restrict__ ay,
    const __half* __restrict__ wtP, const __half* __restrict__ wtA,
    const float* __restrict__ bP, const float* __restrict__ bA,
    __half* __restrict__ oP, __half* __restrict__ oA) {
    if (blockIdx.y == 0) combine_body<3>(pm0, pm1, py, wtP, bP, oP);
    else combine_body<2>(am0, ay, nullptr, wtA, bA, oA);
}

// L1 combine fused with final projection: y_p2 tile staged in per-wave LDS,
// re-read as A-fragments, 2 MFMAs with lin W^T -> d_out fp32 directly.
__global__ __launch_bounds__(256) void combine3_final_kernel(
    const __half* __restrict__ a0, const __half* __restrict__ a1, const __half* __restrict__ a2,
    const __half* __restrict__ wt, const float* __restrict__ bias,
    const __half* __restrict__ wtLIN, const float* __restrict__ linb,
    float* __restrict__ out) {
    __shared__ __half sTile[4][16][64];   // per-wave y_p2 tile (8 KB)
    int wid = (blockIdx.x * 256 + threadIdx.x) >> 6;
    if (wid >= NNODE / 16) return;
    int wv = (threadIdx.x >> 6) & 3;
    int lane = threadIdx.x & 63;
    int row = lane & 15, kq = lane >> 4;
    int node0 = wid << 4;
    const __half* as[3] = {a0, a1, a2};
    f16x8 af[6];
#pragma unroll
    for (int s = 0; s < 3; ++s) {
        const __half* p = as[s] + ((size_t)(node0 + row) << 6) + kq * 8;
        af[2 * s] = *(const f16x8*)(p);
        af[2 * s + 1] = *(const f16x8*)(p + 32);
    }
#pragma unroll
    for (int nt = 0; nt < 4; ++nt) {
        int col = nt * 16 + row;
        const __half* wp = wt + (size_t)col * 192 + kq * 8;
        f32x4 acc = {0.f, 0.f, 0.f, 0.f};
#pragma unroll
        for (int t = 0; t < 6; ++t)
            acc = __builtin_amdgcn_mfma_f32_16x16x32_f16(af[t], *(const f16x8*)(wp + t * 32), acc, 0, 0, 0);
        float b = bias[col];
#pragma unroll
        for (int r = 0; r < 4; ++r)
            sTile[wv][kq * 4 + r][col] = __float2half(acc[r] + b);
    }
    // re-read own tile as A-fragments (wave-local LDS dependency)
    f16x8 y0 = *(const f16x8*)(&sTile[wv][row][kq * 8]);
    f16x8 y1 = *(const f16x8*)(&sTile[wv][row][kq * 8 + 32]);
    const __half* wl = wtLIN + (size_t)row * 64 + kq * 8;
    f32x4 acc = {0.f, 0.f, 0.f, 0.f};
    acc = __builtin_amdgcn_mfma_f32_16x16x32_f16(y0, *(const f16x8*)(wl), acc, 0, 0, 0);
    acc = __builtin_amdgcn_mfma_f32_16x16x32_f16(y1, *(const f16x8*)(wl + 32), acc, 0, 0, 0);
    float b = linb[row];
#pragma unroll
    for (int r = 0; r < 4; ++r)
        out[(size_t)(node0 + kq * 4 + r) * 16 + row] = acc[r] + b;
}

extern "C" void kernel_launch(void* const* d_in, const int* in_sizes, int n_in,
                              void* d_out, int out_size, void* d_ws, size_t ws_size,
                              hipStream_t stream) {
    (void)in_sizes; (void)n_in; (void)out_size; (void)ws_size;
    const float* xda = (const float*)d_in[0];
    const float* xca = (const float*)d_in[1];
    const float* xdp = (const float*)d_in[2];
    const float* xcp = (const float*)d_in[3];
    const float* winA_w = (const float*)d_in[4];
    const float* winA_b = (const float*)d_in[5];
    const float* winP_w = (const float*)d_in[6];
    const float* winP_b = (const float*)d_in[7];
    const float* writes_wl = (const float*)d_in[8];
    const float* writes_bl = (const float*)d_in[9];
    const float* writes_wr = (const float*)d_in[10];
    const float* wb_wl = (const float*)d_in[11];
    const float* wb_bl = (const float*)d_in[12];
    const float* wb_wr = (const float*)d_in[13];
    const float* cites_wl = (const float*)d_in[14];
    const float* cites_bl = (const float*)d_in[15];
    const float* cites_wr = (const float*)d_in[16];
    const float* lin_w = (const float*)d_in[17];
    const float* lin_b = (const float*)d_in[18];
    const int* w_src = (const int*)d_in[19];
    const int* w_dst = (const int*)d_in[20];
    const int* b_src = (const int*)d_in[21];
    const int* b_dst = (const int*)d_in[22];
    const int* c_src = (const int*)d_in[23];
    const int* c_dst = (const int*)d_in[24];

    const size_t NF = (size_t)NNODE * 64;
    const size_t BUK = (size_t)NBUCK * CAP;   // padded slots per edge type
    __half* B0 = (__half*)d_ws;      // y_a0 -> L1 mean_writes -> y_p2
    __half* B1 = B0 + NF;            // y_p0 -> L1 mean_cites
    __half* B2 = B1 + NF;            // L0 mean_writes -> y_p1
    __half* B3 = B2 + NF;            // L0 mean_cites
    __half* B4 = B3 + NF;            // L0 mean_wb -> y_a1

    __half* wtP0 = B4 + NF;          // 12288
    __half* wtP1 = wtP0 + 12288;     // 12288
    __half* wtA = wtP1 + 12288;      // 8192
    __half* wtPJA = wtA + 8192;      // 4096
    __half* wtPJP = wtPJA + 4096;    // 4096
    __half* wtLIN = wtPJP + 4096;    // 1024
    float* biasP = (float*)(wtLIN + 1024);  // 128

    int* ip = (int*)(biasP + 128);
    int2* rp2 = (int2*)ip;               // 3 * NNODE int2
    int* bcur = (int*)(rp2 + 3 * NNODE); // 3 * 256
    int* ssrc = bcur + 3 * 256;          // 3 * BUK
    int* pairs = (int*)B2;               // CSR-build-only alias (21.7MB < 38.4MB)

    const int GB = (NNODE * 64) / 256;      // 25000 (wave per node)
    const int MB = (NNODE / 16 + 3) / 4;    // 1563 (wave per 16 nodes)
    const int PB = (NEDGE + PCH - 1) / PCH; // 196

    // ---- weight prep (+cursor init) + CSR build ----
    wprep_kernel<<<168, 256, 0, stream>>>(writes_wl, cites_wl, writes_wr, cites_wr,
                                          wb_wl, wb_wr, winA_w, winP_w, lin_w,
                                          writes_bl, cites_bl,
                                          wtP0, wtP1, wtA, wtPJA, wtPJP, wtLIN, biasP, bcur);
    partition_kernel<<<dim3(PB, 3), 512, 0, stream>>>(w_src, c_src, b_src,
                                                      w_dst, c_dst, b_dst, bcur, pairs);
    bucket_csr_kernel<<<dim3(NBUCK, 3), 512, 0, stream>>>(bcur, pairs, rp2, ssrc);

    const int2* rp_w = rp2;
    const int2* rp_c = rp2 + NNODE;
    const int2* rp_b = rp2 + 2 * NNODE;
    const int* ss_w = ssrc;
    const int* ss_c = ssrc + BUK;
    const int* ss_b = ssrc + 2 * BUK;

    // ---- input projections (batched) ----
    proj_mfma<<<dim3(MB, 2), 256, 0, stream>>>(xda, xca, xdp, xcp,
                                               wtPJA, wtPJP, winA_b, winP_b, B0, B1);

    // ---- layer 0: 3 gathers in one dispatch (cites+wb share table B1) ----
    gather3_kernel<<<dim3(GB, 3), 256, 0, stream>>>(B0, B1, B1,
                                                    rp_w, rp_c, rp_b,
                                                    ss_w, ss_c, ss_b,
                                                    B2, B3, B4);
    combine_dual<<<dim3(MB, 2), 256, 0, stream>>>(B2, B3, B1, B4, B0,
                                                  wtP0, wtA, biasP, wb_bl, B2, B4);

    // ---- layer 1 (author update is dead code in the reference: skipped) ----
    gather2_kernel<<<dim3(GB, 2), 256, 0, stream>>>(B4, B2,
                                                    rp_w, rp_c,
                                                    ss_w, ss_c,
                                                    B0, B1);
    // L1 combine + final projection fused -> d_out
    combine3_final_kernel<<<MB, 256, 0, stream>>>(B0, B1, B2, wtP1, biasP + 64,
                                                  wtLIN, lin_b, (float*)d_out);
}